// Round 3
// baseline (333.554 us; speedup 1.0000x reference)
//
#include <hip/hip_runtime.h>
#include <math.h>

// B=64, M=128, J=512, T=513 (padded to TPAD=544), E=256, H=16, D=16; out (64, 65664) fp32.

#define LDT 68    // 64-row A-tile LDS leading dim (fp32 gemms)
#define LDB 132   // 128-col B-tile LDS leading dim (fp32 gemms)
#define LDL 40    // logits LDS leading dim (shorts): stride 80 B kills bank conflicts
#define TPAD 544  // 17 * 32; rows 513..543 are zero pads (exp(0)=1 -> subtract 31 from l)

typedef __attribute__((ext_vector_type(8))) short bf16x8;   // 8 bf16 = 4 VGPR
typedef __attribute__((ext_vector_type(4))) float f32x4;    // MFMA acc
typedef __attribute__((ext_vector_type(4))) unsigned short u16x4;

static __device__ inline unsigned short f2bf(float x) {     // RNE fp32->bf16
  unsigned u = __float_as_uint(x);
  return (unsigned short)((u + 0x7fffu + ((u >> 16) & 1u)) >> 16);
}
static __device__ inline float bf2f(unsigned short h) {
  return __uint_as_float(((unsigned)h) << 16);
}
static __device__ inline unsigned pk(unsigned short a, unsigned short b) {
  return (unsigned)a | ((unsigned)b << 16);
}

// global -> LDS direct DMA, 16B per lane; ldst must be wave-uniform (HW adds lane*16)
#define GLD16(gsrc, ldst) \
  __builtin_amdgcn_global_load_lds((const __attribute__((address_space(1))) void*)(gsrc), \
                                   (__attribute__((address_space(3))) void*)(ldst), 16, 0, 0)

// ---------------------------------------------------------------------------
// One-time W split+transpose: Wt[col][k] (bf16 hi/lo), col 0..255 = Wk cols,
// 256..511 = Wv cols. Block 0 also zeroes the 2KB zero-page used for pad rows.
// ---------------------------------------------------------------------------
__global__ void prep_wt(const float* __restrict__ Wk, const float* __restrict__ Wv,
                        unsigned short* __restrict__ Wth, unsigned short* __restrict__ Wtl,
                        float* __restrict__ zpage)
{
  const int c = blockIdx.x, k = threadIdx.x;
  if (c == 0) { zpage[k] = 0.f; zpage[k + 256] = 0.f; }
  const float x = (c < 256) ? Wk[k * 256 + c] : Wv[k * 256 + (c - 256)];
  const unsigned short h = f2bf(x);
  Wth[c * 256 + k] = h;
  Wtl[c * 256 + k] = f2bf(x - bf2f(h));
}

// ---------------------------------------------------------------------------
// KV projection: C(34816 x 512) = vjobs_padded(34816 x 256) @ [Wk|Wv].
// 128x128 tile, 256 thr = 4 waves (2x2, each 64x64 via 4x4 16x16x32 tiles).
// T3-minimum 2-phase pipeline: double-buffered LDS (2 x 32KB), per K-step
//   { STAGE(next -> buf^1) ; ds_read frags + MFMA on buf ; __syncthreads }
// -> one barrier/step, stage latency hidden under compute (vs R1's serial
// stage->drain->compute which exposed full HBM latency each step).
// Staging via global_load_lds (16B/lane) into chunk-major LDS (conflict-free):
//   A fp32 [kc 0..7][row 0..127] x 16B (16 KB)  waves 0,1
//   Bh bf16 [fq 0..3][col 0..127] x 16B ( 8 KB)  wave 2
//   Bl bf16                            ( 8 KB)  wave 3
// A split in-reg at frag read: trunc-hi + RNE-lo (recon err 2^-17).
// C = Ah*Bh + Ah*Bl + Al*Bh. Outputs: K bf16 hi/lo planes [34816][256];
// V TRANSPOSED bf16 hi/lo planes [b][256 cols][544 t] for attn's PV loads.
// ---------------------------------------------------------------------------
__global__ __launch_bounds__(256) void gemm_kv_mfma(
    const float* __restrict__ jobs, const float* __restrict__ skip,
    const float* __restrict__ zpage,
    const unsigned short* __restrict__ Wth, const unsigned short* __restrict__ Wtl,
    unsigned short* __restrict__ Kh, unsigned short* __restrict__ Kl,
    unsigned short* __restrict__ Vth, unsigned short* __restrict__ Vtl)
{
  __shared__ __align__(128) char smem[65536];  // 2 buffers: A:0..16K | Bh:16K..24K | Bl:24K..32K
  const int tid = threadIdx.x;
  const int bx = blockIdx.x, by = blockIdx.y;
  const int w = __builtin_amdgcn_readfirstlane(tid >> 6);
  const int lane = tid & 63;
  const int wr = (w >> 1) << 6, wc = (w & 1) << 6;
  const int fm = lane & 15, fq = lane >> 4;

  // per-lane staging source pointers (2 per wave: row halves / col halves)
  const char* src0;
  const char* src1;
  if (w < 2) {
    const int rg0 = by * 128 + lane;
    const int rg1 = rg0 + 64;
    {
      const int bb = rg0 / TPAD, tt = rg0 - bb * TPAD;
      src0 = (const char*)((tt == 0) ? skip : (tt >= 513 ? zpage
             : (jobs + ((size_t)(bb * 512 + tt - 1) << 8))));
    }
    {
      const int bb = rg1 / TPAD, tt = rg1 - bb * TPAD;
      src1 = (const char*)((tt == 0) ? skip : (tt >= 513 ? zpage
             : (jobs + ((size_t)(bb * 512 + tt - 1) << 8))));
    }
  } else {
    const unsigned short* Wt = (w == 2) ? Wth : Wtl;
    src0 = (const char*)(Wt + ((size_t)(bx * 128 + lane) << 8));
    src1 = (const char*)(Wt + ((size_t)(bx * 128 + 64 + lane) << 8));
  }

  // stage K-step ks into buffer buf (8 x global_load_lds per wave)
  auto STAGE = [&](int ks, char* buf) {
    if (w < 2) {
      #pragma unroll
      for (int j = 0; j < 8; ++j) {
        const int c = w * 8 + j;                 // chunkset: kc=c>>1, rowhalf=c&1
        GLD16(((c & 1) ? src1 : src0) + ks * 128 + (c >> 1) * 16,
              buf + c * 1024);
      }
    } else {
      char* base = buf + ((w == 2) ? 16384 : 24576);
      #pragma unroll
      for (int j = 0; j < 8; ++j)                // fq=j>>1, colhalf=j&1
        GLD16(((j & 1) ? src1 : src0) + ks * 64 + (j >> 1) * 16,
              base + j * 1024);
    }
  };

  f32x4 acc[4][4] = {};

  STAGE(0, smem);
  __syncthreads();                               // buf0 ready

  for (int ks = 0; ks < 8; ++ks) {
    char* cur = smem + ((ks & 1) << 15);
    char* nxt = smem + (((ks & 1) ^ 1) << 15);
    if (ks < 7) STAGE(ks + 1, nxt);              // issue next-step loads FIRST

    // ---- A frags: fp32 -> trunc-hi + RNE-lo split, packed via v_perm ----
    bf16x8 afh[4], afl[4];
    #pragma unroll
    for (int i = 0; i < 4; ++i) {
      const int row = wr + i * 16 + fm;
      const float4 x0 = *(const float4*)(cur + (fq * 2) * 2048 + row * 16);
      const float4 x1 = *(const float4*)(cur + (fq * 2 + 1) * 2048 + row * 16);
      const float xv[8] = {x0.x,x0.y,x0.z,x0.w, x1.x,x1.y,x1.z,x1.w};
      #pragma unroll
      for (int jp = 0; jp < 4; ++jp) {
        const unsigned u0 = __float_as_uint(xv[2*jp]);
        const unsigned u1 = __float_as_uint(xv[2*jp+1]);
        ((unsigned*)&afh[i])[jp] = __builtin_amdgcn_perm(u1, u0, 0x07060302u);
        const float r0 = xv[2*jp]   - __uint_as_float(u0 & 0xffff0000u);
        const float r1 = xv[2*jp+1] - __uint_as_float(u1 & 0xffff0000u);
        unsigned t0_ = __float_as_uint(r0); t0_ += 0x7fffu + ((t0_ >> 16) & 1u);
        unsigned t1_ = __float_as_uint(r1); t1_ += 0x7fffu + ((t1_ >> 16) & 1u);
        ((unsigned*)&afl[i])[jp] = __builtin_amdgcn_perm(t1_, t0_, 0x07060302u);
      }
    }
    bf16x8 bfh[4], bfl[4];
    #pragma unroll
    for (int i = 0; i < 4; ++i) {
      const int col = wc + i * 16 + fm;
      bfh[i] = *(const bf16x8*)(cur + 16384 + fq * 2048 + col * 16);
      bfl[i] = *(const bf16x8*)(cur + 24576 + fq * 2048 + col * 16);
    }
    #pragma unroll
    for (int mi = 0; mi < 4; ++mi)
      #pragma unroll
      for (int ni = 0; ni < 4; ++ni) {
        acc[mi][ni] = __builtin_amdgcn_mfma_f32_16x16x32_bf16(afh[mi], bfl[ni], acc[mi][ni], 0, 0, 0);
        acc[mi][ni] = __builtin_amdgcn_mfma_f32_16x16x32_bf16(afl[mi], bfh[ni], acc[mi][ni], 0, 0, 0);
        acc[mi][ni] = __builtin_amdgcn_mfma_f32_16x16x32_bf16(afh[mi], bfh[ni], acc[mi][ni], 0, 0, 0);
      }

    __syncthreads();  // drains vmcnt (stage of nxt done) + all reads of cur done
  }

  // ---- epilogue: RNE hi/lo bf16 planes ----
  const int cb = ((bx & 1) << 7) + wc;
  if (bx < 2) {
    // K planes, row-major [34816][256]
    #pragma unroll
    for (int mi = 0; mi < 4; ++mi) {
      #pragma unroll
      for (int r = 0; r < 4; ++r) {
        const int row = by * 128 + wr + mi * 16 + fq * 4 + r;
        const size_t rb = (size_t)row << 8;
        #pragma unroll
        for (int ni = 0; ni < 4; ++ni) {
          const int cc = cb + ni * 16 + fm;
          const float x = acc[mi][ni][r];
          const unsigned short hh = f2bf(x);
          Kh[rb + cc] = hh;
          Kl[rb + cc] = f2bf(x - bf2f(hh));
        }
      }
    }
  } else {
    // V transposed planes [b][256][544]; 4 consecutive t per frag reg quad
    #pragma unroll
    for (int mi = 0; mi < 4; ++mi) {
      const int row0 = by * 128 + wr + mi * 16 + fq * 4;   // 4-aligned, same b
      const int bb = row0 / TPAD;
      const int tt0 = row0 - bb * TPAD;
      #pragma unroll
      for (int ni = 0; ni < 4; ++ni) {
        const int cc = cb + ni * 16 + fm;
        const size_t vb = ((size_t)(bb * 256 + cc)) * TPAD + tt0;
        u16x4 vh, vl;
        #pragma unroll
        for (int r = 0; r < 4; ++r) {
          const float x = acc[mi][ni][r];
          const unsigned short hh = f2bf(x);
          vh[r] = hh;
          vl[r] = f2bf(x - bf2f(hh));
        }
        *(u16x4*)(Vth + vb) = vh;
        *(u16x4*)(Vtl + vb) = vl;
      }
    }
  }
}

// ---------------------------------------------------------------------------
// Wide tiled fp32 GEMM (Q and Wc projections): C[rows x 256] = A @ W (+bias)
// ---------------------------------------------------------------------------
template<int MODE>
__global__ __launch_bounds__(256) void gemm_wide(
    const float* __restrict__ A, const float* __restrict__ jobs,
    const float* __restrict__ skip, const float* __restrict__ W1,
    const float* __restrict__ bias, float* __restrict__ C1)
{
  __shared__ float As[16 * LDT];
  __shared__ float Bs[16 * LDB];
  const int tid = threadIdx.x;
  const int bx = blockIdx.x, by = blockIdx.y;

  const float* W = W1; float* C = C1; const int col0 = bx * 128;

  const int a_row = tid >> 2;
  const int a_k4  = (tid & 3) << 2;
  const int row = by * 64 + a_row;
  const float* arow;
  if (MODE == 0) {
    arow = A + ((size_t)row << 8);
  } else {
    const int bb = row / 513;
    const int t  = row - bb * 513;
    arow = (t == 0) ? skip : (jobs + ((size_t)(bb * 512 + t - 1) << 8));
  }

  const int b_k  = tid >> 4;
  const int b_c8 = (tid & 15) << 3;

  const int tr = tid >> 4, tc = tid & 15;
  float acc[4][8] = {};

  for (int k0 = 0; k0 < 256; k0 += 16) {
    const float4 av  = *(const float4*)(arow + k0 + a_k4);
    const float4 bv0 = *(const float4*)(W + ((size_t)(k0 + b_k) << 8) + col0 + b_c8);
    const float4 bv1 = *(const float4*)(W + ((size_t)(k0 + b_k) << 8) + col0 + b_c8 + 4);
    __syncthreads();
    As[(a_k4 + 0) * LDT + a_row] = av.x;
    As[(a_k4 + 1) * LDT + a_row] = av.y;
    As[(a_k4 + 2) * LDT + a_row] = av.z;
    As[(a_k4 + 3) * LDT + a_row] = av.w;
    *(float4*)&Bs[b_k * LDB + b_c8]     = bv0;
    *(float4*)&Bs[b_k * LDB + b_c8 + 4] = bv1;
    __syncthreads();
    #pragma unroll
    for (int k = 0; k < 16; ++k) {
      const float4 a  = *(const float4*)&As[k * LDT + (tr << 2)];
      const float4 b0 = *(const float4*)&Bs[k * LDB + (tc << 3)];
      const float4 b1 = *(const float4*)&Bs[k * LDB + (tc << 3) + 4];
      const float aa[4] = {a.x, a.y, a.z, a.w};
      #pragma unroll
      for (int i = 0; i < 4; ++i) {
        acc[i][0] = fmaf(aa[i], b0.x, acc[i][0]);
        acc[i][1] = fmaf(aa[i], b0.y, acc[i][1]);
        acc[i][2] = fmaf(aa[i], b0.z, acc[i][2]);
        acc[i][3] = fmaf(aa[i], b0.w, acc[i][3]);
        acc[i][4] = fmaf(aa[i], b1.x, acc[i][4]);
        acc[i][5] = fmaf(aa[i], b1.y, acc[i][5]);
        acc[i][6] = fmaf(aa[i], b1.z, acc[i][6]);
        acc[i][7] = fmaf(aa[i], b1.w, acc[i][7]);
      }
    }
  }

  const int oc = col0 + (tc << 3);
  float4 bsa = make_float4(0.f,0.f,0.f,0.f), bsb = make_float4(0.f,0.f,0.f,0.f);
  if (bias) { bsa = *(const float4*)(bias + oc); bsb = *(const float4*)(bias + oc + 4); }
  #pragma unroll
  for (int i = 0; i < 4; ++i) {
    float* crow = C + ((size_t)(by * 64 + (tr << 2) + i) << 8) + oc;
    float4 o0, o1;
    o0.x = acc[i][0]+bsa.x; o0.y = acc[i][1]+bsa.y; o0.z = acc[i][2]+bsa.z; o0.w = acc[i][3]+bsa.w;
    o1.x = acc[i][4]+bsb.x; o1.y = acc[i][5]+bsb.y; o1.z = acc[i][6]+bsb.z; o1.w = acc[i][7]+bsb.w;
    *(float4*)crow = o0; *(float4*)(crow + 4) = o1;
  }
}

// ---------------------------------------------------------------------------
// MFMA attention v8: one block per (h, b), 256 thr = 4 waves (m-half x t-half).
// K/V read as pre-split bf16 planes: each lane loads ONE 16B ushort8 per
// frag (hi plane for lane groups 0,1; lo plane for 2,3) -> half the bytes of
// the fp32 version and zero split VALU in the loop. V comes from transposed
// planes (contiguous t). P split: trunc-hi + RNE-lo via v_perm.
// Pads t=513..543 are zero -> exp=1 exactly: subtract 31 from l.
// ---------------------------------------------------------------------------
__global__ __launch_bounds__(256, 4) void attn_mfma(
    const float* __restrict__ Q,
    const unsigned short* __restrict__ Kh, const unsigned short* __restrict__ Kl,
    const unsigned short* __restrict__ Vth, const unsigned short* __restrict__ Vtl,
    float* __restrict__ OC)
{
  const int h = blockIdx.x, b = blockIdx.y;
  const int tid = threadIdx.x;
  const int lane = tid & 63;
  const int w = __builtin_amdgcn_readfirstlane(tid >> 6);
  const int g = lane >> 4, fm = lane & 15;
  const int mh = (w & 2) << 5;              // 0 or 64
  const int th = w & 1;                     // t-half
  const int send = th ? 17 : 9;             // steps [0,9) | [9,17)
  int s = th ? 9 : 0;

  __shared__ float red[2 * 64 * 21];        // 10.5 KB, stride-21 (conflict-free)

  const int col = h * 16;
  const int dbase = (g & 1) << 3;           // d 0..7 | 8..15 per group parity

  // ---- Q B-frags (persistent, RNE): Bq1 = [Qh|Qh], Bq2 = [Ql|0] ----
  bf16x8 Bq1[4], Bq2[4];
  #pragma unroll
  for (int mt = 0; mt < 4; ++mt) {
    const float* qp = Q + ((size_t)(b * 128 + mh + mt * 16 + fm) << 8) + col + dbase;
    const float4 q0 = *(const float4*)qp;
    const float4 q1 = *(const float4*)(qp + 4);
    const float qv[8] = {q0.x,q0.y,q0.z,q0.w, q1.x,q1.y,q1.z,q1.w};
    #pragma unroll
    for (int j = 0; j < 8; ++j) {
      const float x = qv[j] * 0.25f;        // fold 1/sqrt(QKV)
      const unsigned short hh = f2bf(x);
      Bq1[mt][j] = (short)hh;
      Bq2[mt][j] = (short)((g < 2) ? f2bf(x - bf2f(hh)) : (unsigned short)0);
    }
  }

  f32x4 oT[4] = {};
  float lsum[4] = {0.f, 0.f, 0.f, 0.f};

  // per-lane plane pointers (hoisted)
  const int rA = ((fm & 12) << 1) + (fm & 3);   // permuted K row within step
  const unsigned short* kpl = ((g < 2) ? Kh : Kl)
      + ((((size_t)b * TPAD) + rA) << 8) + col + dbase;
  const unsigned short* vhp = Vth + ((size_t)(b * 256 + col + fm)) * TPAD + (g << 3);
  const unsigned short* vlp = Vtl + ((size_t)(b * 256 + col + fm)) * TPAD + (g << 3);

  for (; s < send; ++s) {
    const int t0 = s << 5;
    const bf16x8 KA = *(const bf16x8*)(kpl + ((size_t)t0 << 8));
    const bf16x8 KB = *(const bf16x8*)(kpl + ((size_t)(t0 + 4) << 8));
    const bf16x8 Vh = *(const bf16x8*)(vhp + t0);
    const bf16x8 Vl = *(const bf16x8*)(vlp + t0);

    #pragma unroll
    for (int mt = 0; mt < 4; ++mt) {
      f32x4 sA = {}, sB = {};
      sA = __builtin_amdgcn_mfma_f32_16x16x32_bf16(KA, Bq1[mt], sA, 0, 0, 0);
      sA = __builtin_amdgcn_mfma_f32_16x16x32_bf16(KA, Bq2[mt], sA, 0, 0, 0);
      sB = __builtin_amdgcn_mfma_f32_16x16x32_bf16(KB, Bq1[mt], sB, 0, 0, 0);
      sB = __builtin_amdgcn_mfma_f32_16x16x32_bf16(KB, Bq2[mt], sB, 0, 0, 0);
      // lane holds P[t0+8g+r][m] (tileA r=0..3) and P[t0+8g+4+r][m] (tileB)
      float p[8];
      p[0] = __expf(sA[0]); p[1] = __expf(sA[1]); p[2] = __expf(sA[2]); p[3] = __expf(sA[3]);
      p[4] = __expf(sB[0]); p[5] = __expf(sB[1]); p[6] = __expf(sB[2]); p[7] = __expf(sB[3]);
      lsum[mt] += ((p[0] + p[1]) + (p[2] + p[3])) + ((p[4] + p[5]) + (p[6] + p[7]));
      bf16x8 Ph, Pl;
      #pragma unroll
      for (int jp = 0; jp < 4; ++jp) {
        const unsigned u0 = __float_as_uint(p[2*jp]);
        const unsigned u1 = __float_as_uint(p[2*jp+1]);
        ((unsigned*)&Ph)[jp] = __builtin_amdgcn_perm(u1, u0, 0x07060302u);
        const float r0 = p[2*jp]   - __uint_as_float(u0 & 0xffff0000u);
        const float r1 = p[2*jp+1] - __uint_as_float(u1 & 0xffff0000u);
        unsigned t0_ = __float_as_uint(r0); t0_ += 0x7fffu + ((t0_ >> 16) & 1u);
        unsigned t1_ = __float_as_uint(r1); t1_ += 0x7fffu + ((t1_ >> 16) & 1u);
        ((unsigned*)&Pl)[jp] = __builtin_amdgcn_perm(t1_, t0_, 0x07060302u);
      }
      oT[mt] = __builtin_amdgcn_mfma_f32_16x16x32_bf16(Vh, Ph, oT[mt], 0, 0, 0);
      oT[mt] = __builtin_amdgcn_mfma_f32_16x16x32_bf16(Vh, Pl, oT[mt], 0, 0, 0);
      oT[mt] = __builtin_amdgcn_mfma_f32_16x16x32_bf16(Vl, Ph, oT[mt], 0, 0, 0);
    }
  }

  // ---- pair reduce (t-half 1 -> t-half 0), then normalize + write ----
  float* slot = red + ((w >> 1) * 1344);
  const int base = lane * 21;
  if (th) {
    #pragma unroll
    for (int mt = 0; mt < 4; ++mt) {
      slot[base + 4 * mt + 0] = oT[mt][0];
      slot[base + 4 * mt + 1] = oT[mt][1];
      slot[base + 4 * mt + 2] = oT[mt][2];
      slot[base + 4 * mt + 3] = oT[mt][3];
      slot[base + 16 + mt]    = lsum[mt];
    }
  }
  __syncthreads();
  if (!th) {
    #pragma unroll
    for (int mt = 0; mt < 4; ++mt) {
      oT[mt][0] += slot[base + 4 * mt + 0];
      oT[mt][1] += slot[base + 4 * mt + 1];
      oT[mt][2] += slot[base + 4 * mt + 2];
      oT[mt][3] += slot[base + 4 * mt + 3];
      float v = lsum[mt] + slot[base + 16 + mt];
      v += __shfl_xor(v, 16);
      v += __shfl_xor(v, 32);
      const float inv = 1.f / (v - 31.f);     // remove 31 pad rows (exp(0)=1)
      float4 o;
      o.x = oT[mt][0] * inv; o.y = oT[mt][1] * inv;
      o.z = oT[mt][2] * inv; o.w = oT[mt][3] * inv;
      // oT reg r = out[m][d = 4g + r]
      *(float4*)(OC + ((size_t)(b * 128 + mh + mt * 16 + fm) << 8) + col + (g << 2)) = o;
    }
  }
}

// ---------------------------------------------------------------------------
// Logits via split-bf16 MFMA: C(128 x 513) per b = MH(128 x 256) @ vjobs(b)^T.
// LDS stride padded to 40 shorts (80 B) -> write/read bank conflicts gone.
// Fused epilogue: e = exp(10*tanh(x/16)+mask-10), write out, deterministic
// per-block partial -> partials[b*5 + bx]. grid (5 t-tiles, 64 b).
// ---------------------------------------------------------------------------
__global__ __launch_bounds__(256) void logits_mfma(
    const float* __restrict__ MH, const float* __restrict__ jobs,
    const float* __restrict__ skip, const float* __restrict__ mask,
    float* __restrict__ out, float* __restrict__ partials)
{
  __shared__ short Ah[128 * LDL], Al[128 * LDL];   // MH  [m][k] bf16 hi/lo
  __shared__ short Bh[128 * LDL], Bl[128 * LDL];   // jobs[t][k] bf16 hi/lo
  __shared__ float red[4];
  const int tid = threadIdx.x;
  const int bx = blockIdx.x;       // t-tile 0..4
  const int b  = blockIdx.y;

  const int r16 = tid >> 1;
  const int h16 = (tid & 1) << 4;
  const float* arow = MH + ((size_t)(b * 128 + r16) << 8);
  int tg = bx * 128 + r16; if (tg > 512) tg = 512;
  const float* brow = (tg == 0) ? skip : (jobs + ((size_t)(b * 512 + tg - 1) << 8));

  const int w = tid >> 6, lane = tid & 63;
  const int wr = (w >> 1) << 6, wc = (w & 1) << 6;
  const int fm = lane & 15, fq = lane >> 4;

  f32x4 acc[4][4] = {};

  for (int kk = 0; kk < 256; kk += 32) {
    const float4 a0 = *(const float4*)(arow + kk + h16);
    const float4 a1 = *(const float4*)(arow + kk + h16 + 4);
    const float4 a2 = *(const float4*)(arow + kk + h16 + 8);
    const float4 a3 = *(const float4*)(arow + kk + h16 + 12);
    const float4 b0 = *(const float4*)(brow + kk + h16);
    const float4 b1 = *(const float4*)(brow + kk + h16 + 4);
    const float4 b2 = *(const float4*)(brow + kk + h16 + 8);
    const float4 b3 = *(const float4*)(brow + kk + h16 + 12);

    unsigned short ha[16], la[16], hb[16], lb[16];
    const float av[16] = {a0.x,a0.y,a0.z,a0.w, a1.x,a1.y,a1.z,a1.w,
                          a2.x,a2.y,a2.z,a2.w, a3.x,a3.y,a3.z,a3.w};
    const float bv[16] = {b0.x,b0.y,b0.z,b0.w, b1.x,b1.y,b1.z,b1.w,
                          b2.x,b2.y,b2.z,b2.w, b3.x,b3.y,b3.z,b3.w};
    #pragma unroll
    for (int i = 0; i < 16; ++i) {
      ha[i] = f2bf(av[i]); la[i] = f2bf(av[i] - bf2f(ha[i]));
      hb[i] = f2bf(bv[i]); lb[i] = f2bf(bv[i] - bf2f(hb[i]));
    }

    __syncthreads();
    const int so = r16 * LDL + h16;
    ((int4*)&Ah[so])[0] = make_int4(pk(ha[0],ha[1]), pk(ha[2],ha[3]), pk(ha[4],ha[5]), pk(ha[6],ha[7]));
    ((int4*)&Ah[so])[1] = make_int4(pk(ha[8],ha[9]), pk(ha[10],ha[11]), pk(ha[12],ha[13]), pk(ha[14],ha[15]));
    ((int4*)&Al[so])[0] = make_int4(pk(la[0],la[1]), pk(la[2],la[3]), pk(la[4],la[5]), pk(la[6],la[7]));
    ((int4*)&Al[so])[1] = make_int4(pk(la[8],la[9]), pk(la[10],la[11]), pk(la[12],la[13]), pk(la[14],la[15]));
    ((int4*)&Bh[so])[0] = make_int4(pk(hb[0],hb[1]), pk(hb[2],hb[3]), pk(hb[4],hb[5]), pk(hb[6],hb[7]));
    ((int4*)&Bh[so])[1] = make_int4(pk(hb[8],hb[9]), pk(hb[10],hb[11]), pk(hb[12],hb[13]), pk(hb[14],hb[15]));
    ((int4*)&Bl[so])[0] = make_int4(pk(lb[0],lb[1]), pk(lb[2],lb[3]), pk(lb[4],lb[5]), pk(lb[6],lb[7]));
    ((int4*)&Bl[so])[1] = make_int4(pk(lb[8],lb[9]), pk(lb[10],lb[11]), pk(lb[12],lb[13]), pk(lb[14],lb[15]));
    __syncthreads();

    bf16x8 afh[4], afl[4], bfh[4], bfl[4];
    #pragma unroll
    for (int i = 0; i < 4; ++i) {
      const int ai = (wr + i * 16 + fm) * LDL + fq * 8;
      const int bi = (wc + i * 16 + fm) * LDL + fq * 8;
      afh[i] = *(const bf16x8*)&Ah[ai];
      afl[i] = *(const bf16x8*)&Al[ai];
      bfh[i] = *(const bf16x8*)&Bh[bi];
      bfl[i] = *(const bf16x8*)&Bl[bi];
    }
    #pragma unroll
    for (int mi = 0; mi < 4; ++mi)
      #pragma unroll
      for (int ni = 0; ni < 4; ++ni) {
        acc[mi][ni] = __builtin_amdgcn_mfma_f32_16x16x32_bf16(afh[mi], bfl[ni], acc[mi][ni], 0, 0, 0);
        acc[mi][ni] = __builtin_amdgcn_mfma_f32_16x16x32_bf16(afl[mi], bfh[ni], acc[mi][ni], 0, 0, 0);
        acc[mi][ni] = __builtin_amdgcn_mfma_f32_16x16x32_bf16(afh[mi], bfh[ni], acc[mi][ni], 0, 0, 0);
      }
  }

  // epilogue: lg = 10*tanh(acc/16) + mask; e = exp(lg-10); sum
  float lsum = 0.f;
  #pragma unroll
  for (int mi = 0; mi < 4; ++mi) {
    #pragma unroll
    for (int r = 0; r < 4; ++r) {
      const int m = wr + mi * 16 + fq * 4 + r;
      #pragma unroll
      for (int ni = 0; ni < 4; ++ni) {
        const int t = bx * 128 + wc + ni * 16 + fm;
        if (t < 513) {
          const float lg = 10.f * tanhf(acc[mi][ni][r] * 0.0625f)
                         + mask[((size_t)(b * 128 + m)) * 513 + t];
          const float e = __expf(lg - 10.f);
          out[(size_t)b * 65664 + (size_t)m * 513 + t] = e;
          lsum += e;
        }
      }
    }
  }
  #pragma unroll
  for (int off = 32; off; off >>= 1) lsum += __shfl_xor(lsum, off);
  if (lane == 0) red[w] = lsum;
  __syncthreads();
  if (tid == 0)
    partials[b * 5 + bx] = (red[0] + red[1]) + (red[2] + red[3]);
}

// Reduce 5 partials per batch -> 1/sum.
__global__ void sm_inv(const float* __restrict__ partials, float* __restrict__ invb)
{
  const int b = threadIdx.x;
  if (b < 64) {
    float s = 0.f;
    #pragma unroll
    for (int i = 0; i < 5; ++i) s += partials[b * 5 + i];
    invb[b] = 1.f / s;
  }
}

__global__ __launch_bounds__(256) void sm_norm(float* __restrict__ out,
                                               const float* __restrict__ invb)
{
  const int i4 = blockIdx.x * 256 + threadIdx.x;
  if (i4 < 1050624) {
    const int b = i4 / 16416;
    float4 v = ((float4*)out)[i4];
    const float s = invb[b];
    v.x *= s; v.y *= s; v.z *= s; v.w *= s;
    ((float4*)out)[i4] = v;
  }
}

// ---------------------------------------------------------------------------
extern "C" void kernel_launch(void* const* d_in, const int* in_sizes, int n_in,
                              void* d_out, int out_size, void* d_ws, size_t ws_size,
                              hipStream_t stream)
{
  const float* machine = (const float*)d_in[0];
  const float* jobs    = (const float*)d_in[1];
  const float* mask    = (const float*)d_in[2];
  const float* Wq      = (const float*)d_in[3];
  const float* Wk      = (const float*)d_in[4];
  const float* Wv      = (const float*)d_in[5];
  const float* Wc      = (const float*)d_in[6];
  const float* bc      = (const float*)d_in[7];
  const float* skip    = (const float*)d_in[8];

  // Workspace (floats). Peak 20,054,528 f ~ 80.2 MB.
  //   [0,        2097152)  Qw fp32; overwritten in-place by attn_mfma as OC
  //   [2097152, 11010048)  Kh|Kl bf16 planes [34816][256]; reused: partials/invb
  //   [11010048,19922944)  Vth|Vtl bf16 planes [64][256][544]; reused: MH
  //   [19922944,20054016)  Wth/Wtl (bf16) -> dead after kv gemm
  //   [20054016,20054528)  zpage (512 f zeros for pad-row staging)
  float* ws       = (float*)d_ws;
  float* Qw       = ws;
  unsigned short* KhP = (unsigned short*)(ws + 2097152);
  unsigned short* KlP = KhP + 8912896;
  unsigned short* VthP = (unsigned short*)(ws + 11010048);
  unsigned short* VtlP = VthP + 8912896;
  unsigned short* Wth = (unsigned short*)(ws + 19922944);
  unsigned short* Wtl = Wth + 131072;
  float* zpage    = ws + 20054016;
  float* MH       = ws + 11010048;     // overlays Vt planes (dead after attn)
  float* partials = ws + 2097152;      // overlays K planes (dead after attn)
  float* invb     = partials + 320;
  float* OC       = Qw;                // attn writes its own (h,b) slice only
  float* out      = (float*)d_out;

  // Q = machine @ Wq3 (fp32)
  gemm_wide<0><<<dim3(2, 128), 256, 0, stream>>>(
      machine, nullptr, nullptr, Wq, nullptr, Qw);
  // W split/transpose (+ zero page), then K|V projection (2-phase pipelined MFMA)
  prep_wt<<<512, 256, 0, stream>>>(Wk, Wv, Wth, Wtl, zpage);
  gemm_kv_mfma<<<dim3(4, 272), 256, 0, stream>>>(
      jobs, skip, zpage, Wth, Wtl, KhP, KlP, VthP, VtlP);
  // MFMA attention on pre-split K/V planes
  attn_mfma<<<dim3(16, 64), 256, 0, stream>>>(Qw, KhP, KlP, VthP, VtlP, OC);
  // mh = out_concat @ Wc + bc (fp32)
  gemm_wide<0><<<dim3(2, 128), 256, 0, stream>>>(
      OC, nullptr, nullptr, Wc, bc, MH);
  // logits via split-bf16 MFMA + fused exp epilogue + partials
  logits_mfma<<<dim3(5, 64), 256, 0, stream>>>(MH, jobs, skip, mask, out, partials);
  sm_inv<<<1, 64, 0, stream>>>(partials, invb);
  sm_norm<<<4104, 256, 0, stream>>>(out, invb);
}

// Round 4
// 317.214 us; speedup vs baseline: 1.0515x; 1.0515x over previous
//
#include <hip/hip_runtime.h>
#include <math.h>

// B=64, M=128, J=512, T=513 (padded to TPAD=544), E=256, H=16, D=16; out (64, 65664) fp32.

#define LDT 68    // 64-row A-tile LDS leading dim (fp32 gemms)
#define LDB 132   // 128-col B-tile LDS leading dim (fp32 gemms)
#define LDL 40    // logits LDS leading dim (shorts): stride 80 B kills bank conflicts
#define TPAD 544  // 17 * 32; rows 513..543 are zero pads (exp(0)=1 -> subtract 31 from l)
#define NROWS 34816  // 64 * TPAD

typedef __attribute__((ext_vector_type(8))) short bf16x8;   // 8 bf16 = 4 VGPR
typedef __attribute__((ext_vector_type(8))) unsigned short u16x8;
typedef __attribute__((ext_vector_type(4))) float f32x4;    // MFMA acc
typedef __attribute__((ext_vector_type(4))) unsigned short u16x4;

static __device__ inline unsigned short f2bf(float x) {     // RNE fp32->bf16
  unsigned u = __float_as_uint(x);
  return (unsigned short)((u + 0x7fffu + ((u >> 16) & 1u)) >> 16);
}
static __device__ inline float bf2f(unsigned short h) {
  return __uint_as_float(((unsigned)h) << 16);
}
static __device__ inline unsigned pk(unsigned short a, unsigned short b) {
  return (unsigned)a | ((unsigned)b << 16);
}

// global -> LDS direct DMA, 16B per lane; ldst wave-uniform (HW adds lane*16),
// gsrc is per-lane (must include + lane*16 for contiguous runs).
#define GLD16(gsrc, ldst) \
  __builtin_amdgcn_global_load_lds((const __attribute__((address_space(1))) void*)(gsrc), \
                                   (__attribute__((address_space(3))) void*)(ldst), 16, 0, 0)

// ---------------------------------------------------------------------------
// W split+transpose -> CHUNK-MAJOR planes: Wh/Wl[chunk 0..31][512 cols][8 bf16].
// col 0..255 = Wk cols, 256..511 = Wv cols. One block per col.
// ---------------------------------------------------------------------------
__global__ void prep_wt(const float* __restrict__ Wk, const float* __restrict__ Wv,
                        unsigned short* __restrict__ Wh, unsigned short* __restrict__ Wl)
{
  __shared__ unsigned short sh[256], sl[256];
  const int c = blockIdx.x, k = threadIdx.x;
  const float x = (c < 256) ? Wk[k * 256 + c] : Wv[k * 256 + (c - 256)];
  const unsigned short h = f2bf(x);
  sh[k] = h; sl[k] = f2bf(x - bf2f(h));
  __syncthreads();
  if (k < 32)
    *(u16x8*)(Wh + ((size_t)k * 512 + c) * 8) = *(const u16x8*)&sh[k * 8];
  else if (k < 64)
    *(u16x8*)(Wl + ((size_t)(k - 32) * 512 + c) * 8) = *(const u16x8*)&sl[(k - 32) * 8];
}

// ---------------------------------------------------------------------------
// jobs_padded split -> CHUNK-MAJOR planes: Jh/Jl[chunk 0..31][34816 rows][8 bf16].
// Row r = (b, t): t=0 skip, 1..512 jobs, >=513 zero pads. Writes are
// lane-contiguous 1KB runs. grid 544 x 256 (wave w owns chunks w*8..w*8+8).
// ---------------------------------------------------------------------------
__global__ __launch_bounds__(256) void prep_jobs(
    const float* __restrict__ jobs, const float* __restrict__ skip,
    unsigned short* __restrict__ Jh, unsigned short* __restrict__ Jl)
{
  const int w = threadIdx.x >> 6, lane = threadIdx.x & 63;
  const int r = blockIdx.x * 64 + lane;          // 0..34815
  const int bb = r / TPAD, tt = r - bb * TPAD;
  const bool padr = (tt >= 513);
  const float* src = (tt == 0) ? skip : (jobs + ((size_t)(bb * 512 + tt - 1) << 8));
  #pragma unroll
  for (int i = 0; i < 8; ++i) {
    const int cc = w * 8 + i;                    // chunk 0..31
    u16x8 h8 = {}, l8 = {};
    if (!padr) {
      const float4 a = *(const float4*)(src + cc * 8);
      const float4 b = *(const float4*)(src + cc * 8 + 4);
      const float v[8] = {a.x,a.y,a.z,a.w, b.x,b.y,b.z,b.w};
      #pragma unroll
      for (int j = 0; j < 8; ++j) {
        const unsigned short hh = f2bf(v[j]);
        h8[j] = hh;
        l8[j] = f2bf(v[j] - bf2f(hh));
      }
    }
    const size_t o = ((size_t)cc * NROWS + r) * 8;
    *(u16x8*)(Jh + o) = h8;
    *(u16x8*)(Jl + o) = l8;
  }
}

// ---------------------------------------------------------------------------
// KV projection: C(34816 x 512) = vjobs_padded @ [Wk|Wv], pure pre-split bf16.
// 128x128 tile, 4 waves (2x2 of 64x64). 2-phase double-buffered LDS (2x32KB).
// Per K-step: wave w stages its plane {Ah,Al,Bh,Bl} with 8 global_load_lds,
// each a CONTIGUOUS 1KB run (64 lanes x 16B, one chunk, consecutive rows) ->
// coalesced, zero in-loop conversion VALU, conflict-free chunk-major ds_reads.
// XCD-chunked swizzle: each XCD owns 34 consecutive by rows (A-panel L2 reuse).
// C = Ah*Bh + Ah*Bl + Al*Bh. Outputs: K bf16 hi/lo planes [34816][256];
// V TRANSPOSED bf16 hi/lo planes [b][256 cols][544 t].
// ---------------------------------------------------------------------------
__global__ __launch_bounds__(256) void gemm_kv_mfma(
    const unsigned short* __restrict__ Jh, const unsigned short* __restrict__ Jl,
    const unsigned short* __restrict__ Wh, const unsigned short* __restrict__ Wl,
    unsigned short* __restrict__ Kh, unsigned short* __restrict__ Kl,
    unsigned short* __restrict__ Vth, unsigned short* __restrict__ Vtl)
{
  __shared__ __align__(128) char smem[65536];  // buf: Ah|Al|Bh|Bl 8KB each, x2
  const int tid = threadIdx.x;
  const int lin = blockIdx.x + (blockIdx.y << 2);        // 0..1087
  const int virt = (lin & 7) * 136 + (lin >> 3);         // bijective (1088%8==0)
  const int bx = virt & 3, by = virt >> 2;
  const int w = __builtin_amdgcn_readfirstlane(tid >> 6);
  const int lane = tid & 63;
  const int wr = (w >> 1) << 6, wc = (w & 1) << 6;
  const int fm = lane & 15, fq = lane >> 4;

  // wave w's source plane + per-lane base (row/col block + lane)
  const unsigned short* sp = (w == 0) ? Jh : (w == 1) ? Jl : (w == 2) ? Wh : Wl;
  const size_t rstride = (w < 2) ? (size_t)NROWS : (size_t)512;
  const size_t blk = (w < 2) ? (size_t)(by * 128) : (size_t)(bx * 128);
  const char* srcb = (const char*)sp + (blk + lane) * 16;

  auto STAGE = [&](int ks, int bsel) {
    char* dst = smem + (bsel << 15) + w * 8192;
    #pragma unroll
    for (int j = 0; j < 8; ++j) {
      const int fq_ = j >> 1, half = j & 1;
      GLD16(srcb + (((size_t)(ks * 4 + fq_)) * rstride + half * 64) * 16,
            dst + fq_ * 2048 + half * 1024);
    }
  };

  f32x4 acc[4][4] = {};

  STAGE(0, 0);
  __syncthreads();

  for (int ks = 0; ks < 8; ++ks) {
    char* cur = smem + ((ks & 1) << 15);
    if (ks < 7) STAGE(ks + 1, (ks & 1) ^ 1);   // next-step loads in flight

    bf16x8 afh[4], afl[4], bfh[4], bfl[4];
    #pragma unroll
    for (int i = 0; i < 4; ++i) {
      const int ro = fq * 2048 + (wr + i * 16 + fm) * 16;
      const int co = fq * 2048 + (wc + i * 16 + fm) * 16;
      afh[i] = *(const bf16x8*)(cur + ro);
      afl[i] = *(const bf16x8*)(cur + 8192 + ro);
      bfh[i] = *(const bf16x8*)(cur + 16384 + co);
      bfl[i] = *(const bf16x8*)(cur + 24576 + co);
    }
    #pragma unroll
    for (int mi = 0; mi < 4; ++mi)
      #pragma unroll
      for (int ni = 0; ni < 4; ++ni) {
        acc[mi][ni] = __builtin_amdgcn_mfma_f32_16x16x32_bf16(afh[mi], bfl[ni], acc[mi][ni], 0, 0, 0);
        acc[mi][ni] = __builtin_amdgcn_mfma_f32_16x16x32_bf16(afl[mi], bfh[ni], acc[mi][ni], 0, 0, 0);
        acc[mi][ni] = __builtin_amdgcn_mfma_f32_16x16x32_bf16(afh[mi], bfh[ni], acc[mi][ni], 0, 0, 0);
      }

    __syncthreads();  // stage of nxt landed + reads of cur done
  }

  // ---- epilogue: RNE hi/lo bf16 planes ----
  const int cb = ((bx & 1) << 7) + wc;
  if (bx < 2) {
    // K planes, row-major [34816][256]
    #pragma unroll
    for (int mi = 0; mi < 4; ++mi) {
      #pragma unroll
      for (int r = 0; r < 4; ++r) {
        const int row = by * 128 + wr + mi * 16 + fq * 4 + r;
        const size_t rb = (size_t)row << 8;
        #pragma unroll
        for (int ni = 0; ni < 4; ++ni) {
          const int cc = cb + ni * 16 + fm;
          const float x = acc[mi][ni][r];
          const unsigned short hh = f2bf(x);
          Kh[rb + cc] = hh;
          Kl[rb + cc] = f2bf(x - bf2f(hh));
        }
      }
    }
  } else {
    // V transposed planes [b][256][544]; 4 consecutive t per frag reg quad
    #pragma unroll
    for (int mi = 0; mi < 4; ++mi) {
      const int row0 = by * 128 + wr + mi * 16 + fq * 4;   // 4-aligned, same b
      const int bb = row0 / TPAD;
      const int tt0 = row0 - bb * TPAD;
      #pragma unroll
      for (int ni = 0; ni < 4; ++ni) {
        const int cc = cb + ni * 16 + fm;
        const size_t vb = ((size_t)(bb * 256 + cc)) * TPAD + tt0;
        u16x4 vh, vl;
        #pragma unroll
        for (int r = 0; r < 4; ++r) {
          const float x = acc[mi][ni][r];
          const unsigned short hh = f2bf(x);
          vh[r] = hh;
          vl[r] = f2bf(x - bf2f(hh));
        }
        *(u16x4*)(Vth + vb) = vh;
        *(u16x4*)(Vtl + vb) = vl;
      }
    }
  }
}

// ---------------------------------------------------------------------------
// Wide tiled fp32 GEMM (Q and Wc projections): C[rows x 256] = A @ W (+bias)
// ---------------------------------------------------------------------------
template<int MODE>
__global__ __launch_bounds__(256) void gemm_wide(
    const float* __restrict__ A, const float* __restrict__ jobs,
    const float* __restrict__ skip, const float* __restrict__ W1,
    const float* __restrict__ bias, float* __restrict__ C1)
{
  __shared__ float As[16 * LDT];
  __shared__ float Bs[16 * LDB];
  const int tid = threadIdx.x;
  const int bx = blockIdx.x, by = blockIdx.y;

  const float* W = W1; float* C = C1; const int col0 = bx * 128;

  const int a_row = tid >> 2;
  const int a_k4  = (tid & 3) << 2;
  const int row = by * 64 + a_row;
  const float* arow;
  if (MODE == 0) {
    arow = A + ((size_t)row << 8);
  } else {
    const int bb = row / 513;
    const int t  = row - bb * 513;
    arow = (t == 0) ? skip : (jobs + ((size_t)(bb * 512 + t - 1) << 8));
  }

  const int b_k  = tid >> 4;
  const int b_c8 = (tid & 15) << 3;

  const int tr = tid >> 4, tc = tid & 15;
  float acc[4][8] = {};

  for (int k0 = 0; k0 < 256; k0 += 16) {
    const float4 av  = *(const float4*)(arow + k0 + a_k4);
    const float4 bv0 = *(const float4*)(W + ((size_t)(k0 + b_k) << 8) + col0 + b_c8);
    const float4 bv1 = *(const float4*)(W + ((size_t)(k0 + b_k) << 8) + col0 + b_c8 + 4);
    __syncthreads();
    As[(a_k4 + 0) * LDT + a_row] = av.x;
    As[(a_k4 + 1) * LDT + a_row] = av.y;
    As[(a_k4 + 2) * LDT + a_row] = av.z;
    As[(a_k4 + 3) * LDT + a_row] = av.w;
    *(float4*)&Bs[b_k * LDB + b_c8]     = bv0;
    *(float4*)&Bs[b_k * LDB + b_c8 + 4] = bv1;
    __syncthreads();
    #pragma unroll
    for (int k = 0; k < 16; ++k) {
      const float4 a  = *(const float4*)&As[k * LDT + (tr << 2)];
      const float4 b0 = *(const float4*)&Bs[k * LDB + (tc << 3)];
      const float4 b1 = *(const float4*)&Bs[k * LDB + (tc << 3) + 4];
      const float aa[4] = {a.x, a.y, a.z, a.w};
      #pragma unroll
      for (int i = 0; i < 4; ++i) {
        acc[i][0] = fmaf(aa[i], b0.x, acc[i][0]);
        acc[i][1] = fmaf(aa[i], b0.y, acc[i][1]);
        acc[i][2] = fmaf(aa[i], b0.z, acc[i][2]);
        acc[i][3] = fmaf(aa[i], b0.w, acc[i][3]);
        acc[i][4] = fmaf(aa[i], b1.x, acc[i][4]);
        acc[i][5] = fmaf(aa[i], b1.y, acc[i][5]);
        acc[i][6] = fmaf(aa[i], b1.z, acc[i][6]);
        acc[i][7] = fmaf(aa[i], b1.w, acc[i][7]);
      }
    }
  }

  const int oc = col0 + (tc << 3);
  float4 bsa = make_float4(0.f,0.f,0.f,0.f), bsb = make_float4(0.f,0.f,0.f,0.f);
  if (bias) { bsa = *(const float4*)(bias + oc); bsb = *(const float4*)(bias + oc + 4); }
  #pragma unroll
  for (int i = 0; i < 4; ++i) {
    float* crow = C + ((size_t)(by * 64 + (tr << 2) + i) << 8) + oc;
    float4 o0, o1;
    o0.x = acc[i][0]+bsa.x; o0.y = acc[i][1]+bsa.y; o0.z = acc[i][2]+bsa.z; o0.w = acc[i][3]+bsa.w;
    o1.x = acc[i][4]+bsb.x; o1.y = acc[i][5]+bsb.y; o1.z = acc[i][6]+bsb.z; o1.w = acc[i][7]+bsb.w;
    *(float4*)crow = o0; *(float4*)(crow + 4) = o1;
  }
}

// ---------------------------------------------------------------------------
// MFMA attention v8: one block per (h, b), 256 thr = 4 waves (m-half x t-half).
// K/V read as pre-split bf16 planes: each lane loads ONE 16B ushort8 per
// frag (hi plane for lane groups 0,1; lo plane for 2,3). V from transposed
// planes (contiguous t). P split: trunc-hi + RNE-lo via v_perm.
// Pads t=513..543 are zero -> exp=1 exactly: subtract 31 from l.
// ---------------------------------------------------------------------------
__global__ __launch_bounds__(256, 4) void attn_mfma(
    const float* __restrict__ Q,
    const unsigned short* __restrict__ Kh, const unsigned short* __restrict__ Kl,
    const unsigned short* __restrict__ Vth, const unsigned short* __restrict__ Vtl,
    float* __restrict__ OC)
{
  const int h = blockIdx.x, b = blockIdx.y;
  const int tid = threadIdx.x;
  const int lane = tid & 63;
  const int w = __builtin_amdgcn_readfirstlane(tid >> 6);
  const int g = lane >> 4, fm = lane & 15;
  const int mh = (w & 2) << 5;              // 0 or 64
  const int th = w & 1;                     // t-half
  const int send = th ? 17 : 9;             // steps [0,9) | [9,17)
  int s = th ? 9 : 0;

  __shared__ float red[2 * 64 * 21];        // 10.5 KB, stride-21 (conflict-free)

  const int col = h * 16;
  const int dbase = (g & 1) << 3;           // d 0..7 | 8..15 per group parity

  // ---- Q B-frags (persistent, RNE): Bq1 = [Qh|Qh], Bq2 = [Ql|0] ----
  bf16x8 Bq1[4], Bq2[4];
  #pragma unroll
  for (int mt = 0; mt < 4; ++mt) {
    const float* qp = Q + ((size_t)(b * 128 + mh + mt * 16 + fm) << 8) + col + dbase;
    const float4 q0 = *(const float4*)qp;
    const float4 q1 = *(const float4*)(qp + 4);
    const float qv[8] = {q0.x,q0.y,q0.z,q0.w, q1.x,q1.y,q1.z,q1.w};
    #pragma unroll
    for (int j = 0; j < 8; ++j) {
      const float x = qv[j] * 0.25f;        // fold 1/sqrt(QKV)
      const unsigned short hh = f2bf(x);
      Bq1[mt][j] = (short)hh;
      Bq2[mt][j] = (short)((g < 2) ? f2bf(x - bf2f(hh)) : (unsigned short)0);
    }
  }

  f32x4 oT[4] = {};
  float lsum[4] = {0.f, 0.f, 0.f, 0.f};

  // per-lane plane pointers (hoisted)
  const int rA = ((fm & 12) << 1) + (fm & 3);   // permuted K row within step
  const unsigned short* kpl = ((g < 2) ? Kh : Kl)
      + ((((size_t)b * TPAD) + rA) << 8) + col + dbase;
  const unsigned short* vhp = Vth + ((size_t)(b * 256 + col + fm)) * TPAD + (g << 3);
  const unsigned short* vlp = Vtl + ((size_t)(b * 256 + col + fm)) * TPAD + (g << 3);

  for (; s < send; ++s) {
    const int t0 = s << 5;
    const bf16x8 KA = *(const bf16x8*)(kpl + ((size_t)t0 << 8));
    const bf16x8 KB = *(const bf16x8*)(kpl + ((size_t)(t0 + 4) << 8));
    const bf16x8 Vh = *(const bf16x8*)(vhp + t0);
    const bf16x8 Vl = *(const bf16x8*)(vlp + t0);

    #pragma unroll
    for (int mt = 0; mt < 4; ++mt) {
      f32x4 sA = {}, sB = {};
      sA = __builtin_amdgcn_mfma_f32_16x16x32_bf16(KA, Bq1[mt], sA, 0, 0, 0);
      sA = __builtin_amdgcn_mfma_f32_16x16x32_bf16(KA, Bq2[mt], sA, 0, 0, 0);
      sB = __builtin_amdgcn_mfma_f32_16x16x32_bf16(KB, Bq1[mt], sB, 0, 0, 0);
      sB = __builtin_amdgcn_mfma_f32_16x16x32_bf16(KB, Bq2[mt], sB, 0, 0, 0);
      // lane holds P[t0+8g+r][m] (tileA r=0..3) and P[t0+8g+4+r][m] (tileB)
      float p[8];
      p[0] = __expf(sA[0]); p[1] = __expf(sA[1]); p[2] = __expf(sA[2]); p[3] = __expf(sA[3]);
      p[4] = __expf(sB[0]); p[5] = __expf(sB[1]); p[6] = __expf(sB[2]); p[7] = __expf(sB[3]);
      lsum[mt] += ((p[0] + p[1]) + (p[2] + p[3])) + ((p[4] + p[5]) + (p[6] + p[7]));
      bf16x8 Ph, Pl;
      #pragma unroll
      for (int jp = 0; jp < 4; ++jp) {
        const unsigned u0 = __float_as_uint(p[2*jp]);
        const unsigned u1 = __float_as_uint(p[2*jp+1]);
        ((unsigned*)&Ph)[jp] = __builtin_amdgcn_perm(u1, u0, 0x07060302u);
        const float r0 = p[2*jp]   - __uint_as_float(u0 & 0xffff0000u);
        const float r1 = p[2*jp+1] - __uint_as_float(u1 & 0xffff0000u);
        unsigned t0_ = __float_as_uint(r0); t0_ += 0x7fffu + ((t0_ >> 16) & 1u);
        unsigned t1_ = __float_as_uint(r1); t1_ += 0x7fffu + ((t1_ >> 16) & 1u);
        ((unsigned*)&Pl)[jp] = __builtin_amdgcn_perm(t1_, t0_, 0x07060302u);
      }
      oT[mt] = __builtin_amdgcn_mfma_f32_16x16x32_bf16(Vh, Ph, oT[mt], 0, 0, 0);
      oT[mt] = __builtin_amdgcn_mfma_f32_16x16x32_bf16(Vh, Pl, oT[mt], 0, 0, 0);
      oT[mt] = __builtin_amdgcn_mfma_f32_16x16x32_bf16(Vl, Ph, oT[mt], 0, 0, 0);
    }
  }

  // ---- pair reduce (t-half 1 -> t-half 0), then normalize + write ----
  float* slot = red + ((w >> 1) * 1344);
  const int base = lane * 21;
  if (th) {
    #pragma unroll
    for (int mt = 0; mt < 4; ++mt) {
      slot[base + 4 * mt + 0] = oT[mt][0];
      slot[base + 4 * mt + 1] = oT[mt][1];
      slot[base + 4 * mt + 2] = oT[mt][2];
      slot[base + 4 * mt + 3] = oT[mt][3];
      slot[base + 16 + mt]    = lsum[mt];
    }
  }
  __syncthreads();
  if (!th) {
    #pragma unroll
    for (int mt = 0; mt < 4; ++mt) {
      oT[mt][0] += slot[base + 4 * mt + 0];
      oT[mt][1] += slot[base + 4 * mt + 1];
      oT[mt][2] += slot[base + 4 * mt + 2];
      oT[mt][3] += slot[base + 4 * mt + 3];
      float v = lsum[mt] + slot[base + 16 + mt];
      v += __shfl_xor(v, 16);
      v += __shfl_xor(v, 32);
      const float inv = 1.f / (v - 31.f);     // remove 31 pad rows (exp(0)=1)
      float4 o;
      o.x = oT[mt][0] * inv; o.y = oT[mt][1] * inv;
      o.z = oT[mt][2] * inv; o.w = oT[mt][3] * inv;
      // oT reg r = out[m][d = 4g + r]
      *(float4*)(OC + ((size_t)(b * 128 + mh + mt * 16 + fm) << 8) + col + (g << 2)) = o;
    }
  }
}

// ---------------------------------------------------------------------------
// Logits via split-bf16 MFMA: C(128 x 513) per b = MH(128 x 256) @ vjobs(b)^T.
// LDS stride padded to 40 shorts (80 B) -> write/read bank conflicts gone.
// Fused epilogue: e = exp(10*tanh(x/16)+mask-10), write out, deterministic
// per-block partial -> partials[b*5 + bx]. grid (5 t-tiles, 64 b).
// ---------------------------------------------------------------------------
__global__ __launch_bounds__(256) void logits_mfma(
    const float* __restrict__ MH, const float* __restrict__ jobs,
    const float* __restrict__ skip, const float* __restrict__ mask,
    float* __restrict__ out, float* __restrict__ partials)
{
  __shared__ short Ah[128 * LDL], Al[128 * LDL];   // MH  [m][k] bf16 hi/lo
  __shared__ short Bh[128 * LDL], Bl[128 * LDL];   // jobs[t][k] bf16 hi/lo
  __shared__ float red[4];
  const int tid = threadIdx.x;
  const int bx = blockIdx.x;       // t-tile 0..4
  const int b  = blockIdx.y;

  const int r16 = tid >> 1;
  const int h16 = (tid & 1) << 4;
  const float* arow = MH + ((size_t)(b * 128 + r16) << 8);
  int tg = bx * 128 + r16; if (tg > 512) tg = 512;
  const float* brow = (tg == 0) ? skip : (jobs + ((size_t)(b * 512 + tg - 1) << 8));

  const int w = tid >> 6, lane = tid & 63;
  const int wr = (w >> 1) << 6, wc = (w & 1) << 6;
  const int fm = lane & 15, fq = lane >> 4;

  f32x4 acc[4][4] = {};

  for (int kk = 0; kk < 256; kk += 32) {
    const float4 a0 = *(const float4*)(arow + kk + h16);
    const float4 a1 = *(const float4*)(arow + kk + h16 + 4);
    const float4 a2 = *(const float4*)(arow + kk + h16 + 8);
    const float4 a3 = *(const float4*)(arow + kk + h16 + 12);
    const float4 b0 = *(const float4*)(brow + kk + h16);
    const float4 b1 = *(const float4*)(brow + kk + h16 + 4);
    const float4 b2 = *(const float4*)(brow + kk + h16 + 8);
    const float4 b3 = *(const float4*)(brow + kk + h16 + 12);

    unsigned short ha[16], la[16], hb[16], lb[16];
    const float av[16] = {a0.x,a0.y,a0.z,a0.w, a1.x,a1.y,a1.z,a1.w,
                          a2.x,a2.y,a2.z,a2.w, a3.x,a3.y,a3.z,a3.w};
    const float bv[16] = {b0.x,b0.y,b0.z,b0.w, b1.x,b1.y,b1.z,b1.w,
                          b2.x,b2.y,b2.z,b2.w, b3.x,b3.y,b3.z,b3.w};
    #pragma unroll
    for (int i = 0; i < 16; ++i) {
      ha[i] = f2bf(av[i]); la[i] = f2bf(av[i] - bf2f(ha[i]));
      hb[i] = f2bf(bv[i]); lb[i] = f2bf(bv[i] - bf2f(hb[i]));
    }

    __syncthreads();
    const int so = r16 * LDL + h16;
    ((int4*)&Ah[so])[0] = make_int4(pk(ha[0],ha[1]), pk(ha[2],ha[3]), pk(ha[4],ha[5]), pk(ha[6],ha[7]));
    ((int4*)&Ah[so])[1] = make_int4(pk(ha[8],ha[9]), pk(ha[10],ha[11]), pk(ha[12],ha[13]), pk(ha[14],ha[15]));
    ((int4*)&Al[so])[0] = make_int4(pk(la[0],la[1]), pk(la[2],la[3]), pk(la[4],la[5]), pk(la[6],la[7]));
    ((int4*)&Al[so])[1] = make_int4(pk(la[8],la[9]), pk(la[10],la[11]), pk(la[12],la[13]), pk(la[14],la[15]));
    ((int4*)&Bh[so])[0] = make_int4(pk(hb[0],hb[1]), pk(hb[2],hb[3]), pk(hb[4],hb[5]), pk(hb[6],hb[7]));
    ((int4*)&Bh[so])[1] = make_int4(pk(hb[8],hb[9]), pk(hb[10],hb[11]), pk(hb[12],hb[13]), pk(hb[14],hb[15]));
    ((int4*)&Bl[so])[0] = make_int4(pk(lb[0],lb[1]), pk(lb[2],lb[3]), pk(lb[4],lb[5]), pk(lb[6],lb[7]));
    ((int4*)&Bl[so])[1] = make_int4(pk(lb[8],lb[9]), pk(lb[10],lb[11]), pk(lb[12],lb[13]), pk(lb[14],lb[15]));
    __syncthreads();

    bf16x8 afh[4], afl[4], bfh[4], bfl[4];
    #pragma unroll
    for (int i = 0; i < 4; ++i) {
      const int ai = (wr + i * 16 + fm) * LDL + fq * 8;
      const int bi = (wc + i * 16 + fm) * LDL + fq * 8;
      afh[i] = *(const bf16x8*)&Ah[ai];
      afl[i] = *(const bf16x8*)&Al[ai];
      bfh[i] = *(const bf16x8*)&Bh[bi];
      bfl[i] = *(const bf16x8*)&Bl[bi];
    }
    #pragma unroll
    for (int mi = 0; mi < 4; ++mi)
      #pragma unroll
      for (int ni = 0; ni < 4; ++ni) {
        acc[mi][ni] = __builtin_amdgcn_mfma_f32_16x16x32_bf16(afh[mi], bfl[ni], acc[mi][ni], 0, 0, 0);
        acc[mi][ni] = __builtin_amdgcn_mfma_f32_16x16x32_bf16(afl[mi], bfh[ni], acc[mi][ni], 0, 0, 0);
        acc[mi][ni] = __builtin_amdgcn_mfma_f32_16x16x32_bf16(afh[mi], bfh[ni], acc[mi][ni], 0, 0, 0);
      }
  }

  // epilogue: lg = 10*tanh(acc/16) + mask; e = exp(lg-10); sum
  float lsum = 0.f;
  #pragma unroll
  for (int mi = 0; mi < 4; ++mi) {
    #pragma unroll
    for (int r = 0; r < 4; ++r) {
      const int m = wr + mi * 16 + fq * 4 + r;
      #pragma unroll
      for (int ni = 0; ni < 4; ++ni) {
        const int t = bx * 128 + wc + ni * 16 + fm;
        if (t < 513) {
          const float lg = 10.f * tanhf(acc[mi][ni][r] * 0.0625f)
                         + mask[((size_t)(b * 128 + m)) * 513 + t];
          const float e = __expf(lg - 10.f);
          out[(size_t)b * 65664 + (size_t)m * 513 + t] = e;
          lsum += e;
        }
      }
    }
  }
  #pragma unroll
  for (int off = 32; off; off >>= 1) lsum += __shfl_xor(lsum, off);
  if (lane == 0) red[w] = lsum;
  __syncthreads();
  if (tid == 0)
    partials[b * 5 + bx] = (red[0] + red[1]) + (red[2] + red[3]);
}

// Reduce 5 partials per batch -> 1/sum.
__global__ void sm_inv(const float* __restrict__ partials, float* __restrict__ invb)
{
  const int b = threadIdx.x;
  if (b < 64) {
    float s = 0.f;
    #pragma unroll
    for (int i = 0; i < 5; ++i) s += partials[b * 5 + i];
    invb[b] = 1.f / s;
  }
}

__global__ __launch_bounds__(256) void sm_norm(float* __restrict__ out,
                                               const float* __restrict__ invb)
{
  const int i4 = blockIdx.x * 256 + threadIdx.x;
  if (i4 < 1050624) {
    const int b = i4 / 16416;
    float4 v = ((float4*)out)[i4];
    const float s = invb[b];
    v.x *= s; v.y *= s; v.z *= s; v.w *= s;
    ((float4*)out)[i4] = v;
  }
}

// ---------------------------------------------------------------------------
extern "C" void kernel_launch(void* const* d_in, const int* in_sizes, int n_in,
                              void* d_out, int out_size, void* d_ws, size_t ws_size,
                              hipStream_t stream)
{
  const float* machine = (const float*)d_in[0];
  const float* jobs    = (const float*)d_in[1];
  const float* mask    = (const float*)d_in[2];
  const float* Wq      = (const float*)d_in[3];
  const float* Wk      = (const float*)d_in[4];
  const float* Wv      = (const float*)d_in[5];
  const float* Wc      = (const float*)d_in[6];
  const float* bc      = (const float*)d_in[7];
  const float* skip    = (const float*)d_in[8];

  // Workspace (floats). Peak 26,869,760 f ~ 107.5 MB.
  //   [0,        8912896)  Jh|Jl chunk-major jobs planes (dead after kv gemm)
  //        overlays after kv: Qw/OC [0,2097152), MH [2097152,4194304)
  //   [8912896, 17825792)  Kh|Kl bf16 planes [34816][256]
  //        overlays after attn: partials/invb
  //   [17825792,26738688)  Vth|Vtl transposed planes [64][256][544]
  //   [26738688,26869760)  Wh|Wl chunk-major W planes
  float* ws       = (float*)d_ws;
  unsigned short* JhP = (unsigned short*)ws;
  unsigned short* JlP = JhP + 8912896;
  unsigned short* KhP = (unsigned short*)(ws + 8912896);
  unsigned short* KlP = KhP + 8912896;
  unsigned short* VthP = (unsigned short*)(ws + 17825792);
  unsigned short* VtlP = VthP + 8912896;
  unsigned short* WhP = (unsigned short*)(ws + 26738688);
  unsigned short* WlP = WhP + 131072;
  float* Qw       = ws;                 // overlays Jh (dead after kv gemm)
  float* OC       = Qw;
  float* MH       = ws + 2097152;       // overlays Jh tail
  float* partials = ws + 8912896;       // overlays Kh (dead after attn)
  float* invb     = partials + 320;
  float* out      = (float*)d_out;

  // prep: W planes + jobs planes (chunk-major pre-split bf16)
  prep_wt<<<512, 256, 0, stream>>>(Wk, Wv, WhP, WlP);
  prep_jobs<<<544, 256, 0, stream>>>(jobs, skip, JhP, JlP);
  // K|V projection: pure bf16 MFMA, coalesced global_load_lds, 2-phase dbuf
  gemm_kv_mfma<<<dim3(4, 272), 256, 0, stream>>>(
      JhP, JlP, WhP, WlP, KhP, KlP, VthP, VtlP);
  // Q = machine @ Wq3 (fp32) -- after kv gemm (Qw overlays J planes)
  gemm_wide<0><<<dim3(2, 128), 256, 0, stream>>>(
      machine, nullptr, nullptr, Wq, nullptr, Qw);
  // MFMA attention on pre-split K/V planes
  attn_mfma<<<dim3(16, 64), 256, 0, stream>>>(Qw, KhP, KlP, VthP, VtlP, OC);
  // mh = out_concat @ Wc + bc (fp32)
  gemm_wide<0><<<dim3(2, 128), 256, 0, stream>>>(
      OC, nullptr, nullptr, Wc, bc, MH);
  // logits via split-bf16 MFMA + fused exp epilogue + partials
  logits_mfma<<<dim3(5, 64), 256, 0, stream>>>(MH, jobs, skip, mask, out, partials);
  sm_inv<<<1, 64, 0, stream>>>(partials, invb);
  sm_norm<<<4104, 256, 0, stream>>>(out, invb);
}

// Round 5
// 303.878 us; speedup vs baseline: 1.0977x; 1.0439x over previous
//
#include <hip/hip_runtime.h>
#include <math.h>

// B=64, M=128, J=512, T=513 (padded to TPAD=544), E=256, H=16, D=16; out (64, 65664) fp32.

#define LDT 68    // 64-row A-tile LDS leading dim (fp32 gemms)
#define LDB 132   // 128-col B-tile LDS leading dim (fp32 gemms)
#define TPAD 544  // 17 * 32; rows 513..543 are zero pads (exp(0)=1 -> subtract 31 from l)
#define NROWS 34816  // 64 * TPAD

typedef __attribute__((ext_vector_type(8))) short bf16x8;   // 8 bf16 = 4 VGPR
typedef __attribute__((ext_vector_type(8))) unsigned short u16x8;
typedef __attribute__((ext_vector_type(4))) float f32x4;    // MFMA acc
typedef __attribute__((ext_vector_type(4))) unsigned short u16x4;

static __device__ inline unsigned short f2bf(float x) {     // RNE fp32->bf16
  unsigned u = __float_as_uint(x);
  return (unsigned short)((u + 0x7fffu + ((u >> 16) & 1u)) >> 16);
}
static __device__ inline float bf2f(unsigned short h) {
  return __uint_as_float(((unsigned)h) << 16);
}

// global -> LDS direct DMA, 16B per lane; ldst wave-uniform (HW adds lane*16),
// gsrc is per-lane (contiguous runs: base + lane*16).
#define GLD16(gsrc, ldst) \
  __builtin_amdgcn_global_load_lds((const __attribute__((address_space(1))) void*)(gsrc), \
                                   (__attribute__((address_space(3))) void*)(ldst), 16, 0, 0)

// ---------------------------------------------------------------------------
// W split+transpose -> CHUNK-MAJOR planes: Wh/Wl[chunk 0..31][512 cols][8 bf16].
// col 0..255 = Wk cols, 256..511 = Wv cols. One block per col.
// ---------------------------------------------------------------------------
__global__ void prep_wt(const float* __restrict__ Wk, const float* __restrict__ Wv,
                        unsigned short* __restrict__ Wh, unsigned short* __restrict__ Wl)
{
  __shared__ unsigned short sh[256], sl[256];
  const int c = blockIdx.x, k = threadIdx.x;
  const float x = (c < 256) ? Wk[k * 256 + c] : Wv[k * 256 + (c - 256)];
  const unsigned short h = f2bf(x);
  sh[k] = h; sl[k] = f2bf(x - bf2f(h));
  __syncthreads();
  if (k < 32)
    *(u16x8*)(Wh + ((size_t)k * 512 + c) * 8) = *(const u16x8*)&sh[k * 8];
  else if (k < 64)
    *(u16x8*)(Wl + ((size_t)(k - 32) * 512 + c) * 8) = *(const u16x8*)&sl[(k - 32) * 8];
}

// ---------------------------------------------------------------------------
// jobs_padded split -> CHUNK-MAJOR planes: Jh/Jl[chunk 0..31][34816 rows][8 bf16].
// Row r = (b, t): t=0 skip, 1..512 jobs, >=513 zero pads. Writes are
// lane-contiguous 1KB runs. grid 544 x 256 (wave w owns chunks w*8..w*8+8).
// ---------------------------------------------------------------------------
__global__ __launch_bounds__(256) void prep_jobs(
    const float* __restrict__ jobs, const float* __restrict__ skip,
    unsigned short* __restrict__ Jh, unsigned short* __restrict__ Jl)
{
  const int w = threadIdx.x >> 6, lane = threadIdx.x & 63;
  const int r = blockIdx.x * 64 + lane;          // 0..34815
  const int bb = r / TPAD, tt = r - bb * TPAD;
  const bool padr = (tt >= 513);
  const float* src = (tt == 0) ? skip : (jobs + ((size_t)(bb * 512 + tt - 1) << 8));
  #pragma unroll
  for (int i = 0; i < 8; ++i) {
    const int cc = w * 8 + i;                    // chunk 0..31
    u16x8 h8 = {}, l8 = {};
    if (!padr) {
      const float4 a = *(const float4*)(src + cc * 8);
      const float4 b = *(const float4*)(src + cc * 8 + 4);
      const float v[8] = {a.x,a.y,a.z,a.w, b.x,b.y,b.z,b.w};
      #pragma unroll
      for (int j = 0; j < 8; ++j) {
        const unsigned short hh = f2bf(v[j]);
        h8[j] = hh;
        l8[j] = f2bf(v[j] - bf2f(hh));
      }
    }
    const size_t o = ((size_t)cc * NROWS + r) * 8;
    *(u16x8*)(Jh + o) = h8;
    *(u16x8*)(Jl + o) = l8;
  }
}

// ---------------------------------------------------------------------------
// KV projection: C(34816 x 512) = vjobs_padded @ [Wk|Wv], pure pre-split bf16.
// 128x128 tile, 4 waves (2x2 of 64x64). 2-phase double-buffered LDS (2x32KB).
// Per K-step: wave w stages its plane {Ah,Al,Bh,Bl} with 8 global_load_lds,
// each a CONTIGUOUS 1KB run -> coalesced, zero in-loop conversion VALU,
// conflict-free chunk-major ds_reads. XCD-chunked swizzle for A-panel L2 reuse.
// C = Ah*Bh + Ah*Bl + Al*Bh. Outputs: K bf16 hi/lo planes [34816][256];
// V TRANSPOSED bf16 hi/lo planes [b][256 cols][544 t].
// ---------------------------------------------------------------------------
__global__ __launch_bounds__(256) void gemm_kv_mfma(
    const unsigned short* __restrict__ Jh, const unsigned short* __restrict__ Jl,
    const unsigned short* __restrict__ Wh, const unsigned short* __restrict__ Wl,
    unsigned short* __restrict__ Kh, unsigned short* __restrict__ Kl,
    unsigned short* __restrict__ Vth, unsigned short* __restrict__ Vtl)
{
  __shared__ __align__(128) char smem[65536];  // buf: Ah|Al|Bh|Bl 8KB each, x2
  const int tid = threadIdx.x;
  const int lin = blockIdx.x + (blockIdx.y << 2);        // 0..1087
  const int virt = (lin & 7) * 136 + (lin >> 3);         // bijective (1088%8==0)
  const int bx = virt & 3, by = virt >> 2;
  const int w = __builtin_amdgcn_readfirstlane(tid >> 6);
  const int lane = tid & 63;
  const int wr = (w >> 1) << 6, wc = (w & 1) << 6;
  const int fm = lane & 15, fq = lane >> 4;

  // wave w's source plane + per-lane base (row/col block + lane)
  const unsigned short* sp = (w == 0) ? Jh : (w == 1) ? Jl : (w == 2) ? Wh : Wl;
  const size_t rstride = (w < 2) ? (size_t)NROWS : (size_t)512;
  const size_t blk = (w < 2) ? (size_t)(by * 128) : (size_t)(bx * 128);
  const char* srcb = (const char*)sp + (blk + lane) * 16;

  auto STAGE = [&](int ks, int bsel) {
    char* dst = smem + (bsel << 15) + w * 8192;
    #pragma unroll
    for (int j = 0; j < 8; ++j) {
      const int fq_ = j >> 1, half = j & 1;
      GLD16(srcb + (((size_t)(ks * 4 + fq_)) * rstride + half * 64) * 16,
            dst + fq_ * 2048 + half * 1024);
    }
  };

  f32x4 acc[4][4] = {};

  STAGE(0, 0);
  __syncthreads();

  for (int ks = 0; ks < 8; ++ks) {
    char* cur = smem + ((ks & 1) << 15);
    if (ks < 7) STAGE(ks + 1, (ks & 1) ^ 1);   // next-step loads in flight

    bf16x8 afh[4], afl[4], bfh[4], bfl[4];
    #pragma unroll
    for (int i = 0; i < 4; ++i) {
      const int ro = fq * 2048 + (wr + i * 16 + fm) * 16;
      const int co = fq * 2048 + (wc + i * 16 + fm) * 16;
      afh[i] = *(const bf16x8*)(cur + ro);
      afl[i] = *(const bf16x8*)(cur + 8192 + ro);
      bfh[i] = *(const bf16x8*)(cur + 16384 + co);
      bfl[i] = *(const bf16x8*)(cur + 24576 + co);
    }
    #pragma unroll
    for (int mi = 0; mi < 4; ++mi)
      #pragma unroll
      for (int ni = 0; ni < 4; ++ni) {
        acc[mi][ni] = __builtin_amdgcn_mfma_f32_16x16x32_bf16(afh[mi], bfl[ni], acc[mi][ni], 0, 0, 0);
        acc[mi][ni] = __builtin_amdgcn_mfma_f32_16x16x32_bf16(afl[mi], bfh[ni], acc[mi][ni], 0, 0, 0);
        acc[mi][ni] = __builtin_amdgcn_mfma_f32_16x16x32_bf16(afh[mi], bfh[ni], acc[mi][ni], 0, 0, 0);
      }

    __syncthreads();  // stage of nxt landed + reads of cur done
  }

  // ---- epilogue: RNE hi/lo bf16 planes ----
  const int cb = ((bx & 1) << 7) + wc;
  if (bx < 2) {
    // K planes, row-major [34816][256]
    #pragma unroll
    for (int mi = 0; mi < 4; ++mi) {
      #pragma unroll
      for (int r = 0; r < 4; ++r) {
        const int row = by * 128 + wr + mi * 16 + fq * 4 + r;
        const size_t rb = (size_t)row << 8;
        #pragma unroll
        for (int ni = 0; ni < 4; ++ni) {
          const int cc = cb + ni * 16 + fm;
          const float x = acc[mi][ni][r];
          const unsigned short hh = f2bf(x);
          Kh[rb + cc] = hh;
          Kl[rb + cc] = f2bf(x - bf2f(hh));
        }
      }
    }
  } else {
    // V transposed planes [b][256][544]; 4 consecutive t per frag reg quad
    #pragma unroll
    for (int mi = 0; mi < 4; ++mi) {
      const int row0 = by * 128 + wr + mi * 16 + fq * 4;   // 4-aligned, same b
      const int bb = row0 / TPAD;
      const int tt0 = row0 - bb * TPAD;
      #pragma unroll
      for (int ni = 0; ni < 4; ++ni) {
        const int cc = cb + ni * 16 + fm;
        const size_t vb = ((size_t)(bb * 256 + cc)) * TPAD + tt0;
        u16x4 vh, vl;
        #pragma unroll
        for (int r = 0; r < 4; ++r) {
          const float x = acc[mi][ni][r];
          const unsigned short hh = f2bf(x);
          vh[r] = hh;
          vl[r] = f2bf(x - bf2f(hh));
        }
        *(u16x4*)(Vth + vb) = vh;
        *(u16x4*)(Vtl + vb) = vl;
      }
    }
  }
}

// ---------------------------------------------------------------------------
// Wide tiled fp32 GEMM (Q and Wc projections): C[rows x 256] = A @ W (+bias).
// MODE 0: fp32 output C1. MODE 1: output split bf16 hi/lo CHUNK-MAJOR planes
// Ch/Cl[chunk 0..31][8192 rows][8 bf16] (feeds logits_mfma staging).
// ---------------------------------------------------------------------------
template<int MODE>
__global__ __launch_bounds__(256) void gemm_wide(
    const float* __restrict__ A, const float* __restrict__ W,
    const float* __restrict__ bias, float* __restrict__ C1,
    unsigned short* __restrict__ Ch, unsigned short* __restrict__ Cl)
{
  __shared__ float As[16 * LDT];
  __shared__ float Bs[16 * LDB];
  const int tid = threadIdx.x;
  const int bx = blockIdx.x, by = blockIdx.y;
  const int col0 = bx * 128;

  const int a_row = tid >> 2;
  const int a_k4  = (tid & 3) << 2;
  const float* arow = A + ((size_t)(by * 64 + a_row) << 8);

  const int b_k  = tid >> 4;
  const int b_c8 = (tid & 15) << 3;

  const int tr = tid >> 4, tc = tid & 15;
  float acc[4][8] = {};

  for (int k0 = 0; k0 < 256; k0 += 16) {
    const float4 av  = *(const float4*)(arow + k0 + a_k4);
    const float4 bv0 = *(const float4*)(W + ((size_t)(k0 + b_k) << 8) + col0 + b_c8);
    const float4 bv1 = *(const float4*)(W + ((size_t)(k0 + b_k) << 8) + col0 + b_c8 + 4);
    __syncthreads();
    As[(a_k4 + 0) * LDT + a_row] = av.x;
    As[(a_k4 + 1) * LDT + a_row] = av.y;
    As[(a_k4 + 2) * LDT + a_row] = av.z;
    As[(a_k4 + 3) * LDT + a_row] = av.w;
    *(float4*)&Bs[b_k * LDB + b_c8]     = bv0;
    *(float4*)&Bs[b_k * LDB + b_c8 + 4] = bv1;
    __syncthreads();
    #pragma unroll
    for (int k = 0; k < 16; ++k) {
      const float4 a  = *(const float4*)&As[k * LDT + (tr << 2)];
      const float4 b0 = *(const float4*)&Bs[k * LDB + (tc << 3)];
      const float4 b1 = *(const float4*)&Bs[k * LDB + (tc << 3) + 4];
      const float aa[4] = {a.x, a.y, a.z, a.w};
      #pragma unroll
      for (int i = 0; i < 4; ++i) {
        acc[i][0] = fmaf(aa[i], b0.x, acc[i][0]);
        acc[i][1] = fmaf(aa[i], b0.y, acc[i][1]);
        acc[i][2] = fmaf(aa[i], b0.z, acc[i][2]);
        acc[i][3] = fmaf(aa[i], b0.w, acc[i][3]);
        acc[i][4] = fmaf(aa[i], b1.x, acc[i][4]);
        acc[i][5] = fmaf(aa[i], b1.y, acc[i][5]);
        acc[i][6] = fmaf(aa[i], b1.z, acc[i][6]);
        acc[i][7] = fmaf(aa[i], b1.w, acc[i][7]);
      }
    }
  }

  const int oc = col0 + (tc << 3);
  float4 bsa = make_float4(0.f,0.f,0.f,0.f), bsb = make_float4(0.f,0.f,0.f,0.f);
  if (bias) { bsa = *(const float4*)(bias + oc); bsb = *(const float4*)(bias + oc + 4); }
  const float bb[8] = {bsa.x,bsa.y,bsa.z,bsa.w, bsb.x,bsb.y,bsb.z,bsb.w};
  #pragma unroll
  for (int i = 0; i < 4; ++i) {
    const int row = by * 64 + (tr << 2) + i;
    if (MODE == 0) {
      float* crow = C1 + ((size_t)row << 8) + oc;
      float4 o0, o1;
      o0.x = acc[i][0]+bb[0]; o0.y = acc[i][1]+bb[1]; o0.z = acc[i][2]+bb[2]; o0.w = acc[i][3]+bb[3];
      o1.x = acc[i][4]+bb[4]; o1.y = acc[i][5]+bb[5]; o1.z = acc[i][6]+bb[6]; o1.w = acc[i][7]+bb[7];
      *(float4*)crow = o0; *(float4*)(crow + 4) = o1;
    } else {
      // chunk-major split planes: chunk = oc>>3, 8 cols per chunk
      u16x8 h8, l8;
      #pragma unroll
      for (int j = 0; j < 8; ++j) {
        const float x = acc[i][j] + bb[j];
        const unsigned short hh = f2bf(x);
        h8[j] = hh;
        l8[j] = f2bf(x - bf2f(hh));
      }
      const size_t o = ((size_t)(oc >> 3) * 8192 + row) * 8;
      *(u16x8*)(Ch + o) = h8;
      *(u16x8*)(Cl + o) = l8;
    }
  }
}

// ---------------------------------------------------------------------------
// MFMA attention v8: one block per (h, b), 256 thr = 4 waves (m-half x t-half).
// K/V read as pre-split bf16 planes: each lane loads ONE 16B ushort8 per
// frag (hi plane for lane groups 0,1; lo plane for 2,3). V from transposed
// planes (contiguous t). P split: trunc-hi + RNE-lo via v_perm.
// Pads t=513..543 are zero -> exp=1 exactly: subtract 31 from l.
// ---------------------------------------------------------------------------
__global__ __launch_bounds__(256, 4) void attn_mfma(
    const float* __restrict__ Q,
    const unsigned short* __restrict__ Kh, const unsigned short* __restrict__ Kl,
    const unsigned short* __restrict__ Vth, const unsigned short* __restrict__ Vtl,
    float* __restrict__ OC)
{
  const int h = blockIdx.x, b = blockIdx.y;
  const int tid = threadIdx.x;
  const int lane = tid & 63;
  const int w = __builtin_amdgcn_readfirstlane(tid >> 6);
  const int g = lane >> 4, fm = lane & 15;
  const int mh = (w & 2) << 5;              // 0 or 64
  const int th = w & 1;                     // t-half
  const int send = th ? 17 : 9;             // steps [0,9) | [9,17)
  int s = th ? 9 : 0;

  __shared__ float red[2 * 64 * 21];        // 10.5 KB, stride-21 (conflict-free)

  const int col = h * 16;
  const int dbase = (g & 1) << 3;           // d 0..7 | 8..15 per group parity

  // ---- Q B-frags (persistent, RNE): Bq1 = [Qh|Qh], Bq2 = [Ql|0] ----
  bf16x8 Bq1[4], Bq2[4];
  #pragma unroll
  for (int mt = 0; mt < 4; ++mt) {
    const float* qp = Q + ((size_t)(b * 128 + mh + mt * 16 + fm) << 8) + col + dbase;
    const float4 q0 = *(const float4*)qp;
    const float4 q1 = *(const float4*)(qp + 4);
    const float qv[8] = {q0.x,q0.y,q0.z,q0.w, q1.x,q1.y,q1.z,q1.w};
    #pragma unroll
    for (int j = 0; j < 8; ++j) {
      const float x = qv[j] * 0.25f;        // fold 1/sqrt(QKV)
      const unsigned short hh = f2bf(x);
      Bq1[mt][j] = (short)hh;
      Bq2[mt][j] = (short)((g < 2) ? f2bf(x - bf2f(hh)) : (unsigned short)0);
    }
  }

  f32x4 oT[4] = {};
  float lsum[4] = {0.f, 0.f, 0.f, 0.f};

  // per-lane plane pointers (hoisted)
  const int rA = ((fm & 12) << 1) + (fm & 3);   // permuted K row within step
  const unsigned short* kpl = ((g < 2) ? Kh : Kl)
      + ((((size_t)b * TPAD) + rA) << 8) + col + dbase;
  const unsigned short* vhp = Vth + ((size_t)(b * 256 + col + fm)) * TPAD + (g << 3);
  const unsigned short* vlp = Vtl + ((size_t)(b * 256 + col + fm)) * TPAD + (g << 3);

  for (; s < send; ++s) {
    const int t0 = s << 5;
    const bf16x8 KA = *(const bf16x8*)(kpl + ((size_t)t0 << 8));
    const bf16x8 KB = *(const bf16x8*)(kpl + ((size_t)(t0 + 4) << 8));
    const bf16x8 Vh = *(const bf16x8*)(vhp + t0);
    const bf16x8 Vl = *(const bf16x8*)(vlp + t0);

    #pragma unroll
    for (int mt = 0; mt < 4; ++mt) {
      f32x4 sA = {}, sB = {};
      sA = __builtin_amdgcn_mfma_f32_16x16x32_bf16(KA, Bq1[mt], sA, 0, 0, 0);
      sA = __builtin_amdgcn_mfma_f32_16x16x32_bf16(KA, Bq2[mt], sA, 0, 0, 0);
      sB = __builtin_amdgcn_mfma_f32_16x16x32_bf16(KB, Bq1[mt], sB, 0, 0, 0);
      sB = __builtin_amdgcn_mfma_f32_16x16x32_bf16(KB, Bq2[mt], sB, 0, 0, 0);
      // lane holds P[t0+8g+r][m] (tileA r=0..3) and P[t0+8g+4+r][m] (tileB)
      float p[8];
      p[0] = __expf(sA[0]); p[1] = __expf(sA[1]); p[2] = __expf(sA[2]); p[3] = __expf(sA[3]);
      p[4] = __expf(sB[0]); p[5] = __expf(sB[1]); p[6] = __expf(sB[2]); p[7] = __expf(sB[3]);
      lsum[mt] += ((p[0] + p[1]) + (p[2] + p[3])) + ((p[4] + p[5]) + (p[6] + p[7]));
      bf16x8 Ph, Pl;
      #pragma unroll
      for (int jp = 0; jp < 4; ++jp) {
        const unsigned u0 = __float_as_uint(p[2*jp]);
        const unsigned u1 = __float_as_uint(p[2*jp+1]);
        ((unsigned*)&Ph)[jp] = __builtin_amdgcn_perm(u1, u0, 0x07060302u);
        const float r0 = p[2*jp]   - __uint_as_float(u0 & 0xffff0000u);
        const float r1 = p[2*jp+1] - __uint_as_float(u1 & 0xffff0000u);
        unsigned t0_ = __float_as_uint(r0); t0_ += 0x7fffu + ((t0_ >> 16) & 1u);
        unsigned t1_ = __float_as_uint(r1); t1_ += 0x7fffu + ((t1_ >> 16) & 1u);
        ((unsigned*)&Pl)[jp] = __builtin_amdgcn_perm(t1_, t0_, 0x07060302u);
      }
      oT[mt] = __builtin_amdgcn_mfma_f32_16x16x32_bf16(Vh, Ph, oT[mt], 0, 0, 0);
      oT[mt] = __builtin_amdgcn_mfma_f32_16x16x32_bf16(Vh, Pl, oT[mt], 0, 0, 0);
      oT[mt] = __builtin_amdgcn_mfma_f32_16x16x32_bf16(Vl, Ph, oT[mt], 0, 0, 0);
    }
  }

  // ---- pair reduce (t-half 1 -> t-half 0), then normalize + write ----
  float* slot = red + ((w >> 1) * 1344);
  const int base = lane * 21;
  if (th) {
    #pragma unroll
    for (int mt = 0; mt < 4; ++mt) {
      slot[base + 4 * mt + 0] = oT[mt][0];
      slot[base + 4 * mt + 1] = oT[mt][1];
      slot[base + 4 * mt + 2] = oT[mt][2];
      slot[base + 4 * mt + 3] = oT[mt][3];
      slot[base + 16 + mt]    = lsum[mt];
    }
  }
  __syncthreads();
  if (!th) {
    #pragma unroll
    for (int mt = 0; mt < 4; ++mt) {
      oT[mt][0] += slot[base + 4 * mt + 0];
      oT[mt][1] += slot[base + 4 * mt + 1];
      oT[mt][2] += slot[base + 4 * mt + 2];
      oT[mt][3] += slot[base + 4 * mt + 3];
      float v = lsum[mt] + slot[base + 16 + mt];
      v += __shfl_xor(v, 16);
      v += __shfl_xor(v, 32);
      const float inv = 1.f / (v - 31.f);     // remove 31 pad rows (exp(0)=1)
      float4 o;
      o.x = oT[mt][0] * inv; o.y = oT[mt][1] * inv;
      o.z = oT[mt][2] * inv; o.w = oT[mt][3] * inv;
      // oT reg r = out[m][d = 4g + r]
      *(float4*)(OC + ((size_t)(b * 128 + mh + mt * 16 + fm) << 8) + col + (g << 2)) = o;
    }
  }
}

// ---------------------------------------------------------------------------
// Logits v2 = gemm_kv skeleton: C(128 x 513) per b = MH(128 x 256) @ vjobs^T.
// A = MH chunk-major split planes (from gemm_wide<1>), B = Jh/Jl planes
// (kept alive from prep_jobs). Per K-step each wave stages its plane with
// 8 contiguous-1KB global_load_lds; 2-phase dbuf; zero in-loop split VALU.
// XCD swizzle groups the 5 t-tiles of each b -> MH panel L2 reuse.
// bx=4 window covers t=512..639: t>=513 are pads/cross-batch garbage, fully
// guarded at the epilogue (no write, no lsum). Fused epilogue:
// e = exp(10*tanh(x/16)+mask-10), deterministic partials[b*5+bx].
// ---------------------------------------------------------------------------
__global__ __launch_bounds__(256) void logits_mfma(
    const unsigned short* __restrict__ Mh, const unsigned short* __restrict__ Ml,
    const unsigned short* __restrict__ Jh, const unsigned short* __restrict__ Jl,
    const float* __restrict__ mask,
    float* __restrict__ out, float* __restrict__ partials)
{
  __shared__ __align__(128) char smem[65536];  // buf: Ah|Al|Bh|Bl 8KB each, x2
  __shared__ float red[4];
  const int tid = threadIdx.x;
  const int lin = blockIdx.x + blockIdx.y * 5;           // 0..319
  const int virt = (lin & 7) * 40 + (lin >> 3);          // bijective (320%8==0)
  const int bx = virt % 5;                               // t-tile
  const int b  = virt / 5;
  const int w = __builtin_amdgcn_readfirstlane(tid >> 6);
  const int lane = tid & 63;
  const int wr = (w >> 1) << 6, wc = (w & 1) << 6;
  const int fm = lane & 15, fq = lane >> 4;

  const unsigned short* sp = (w == 0) ? Mh : (w == 1) ? Ml : (w == 2) ? Jh : Jl;
  const size_t rstride = (w < 2) ? (size_t)8192 : (size_t)NROWS;
  const size_t base = (w < 2) ? (size_t)(b * 128) : ((size_t)b * TPAD + bx * 128);
  const char* srcb = (const char*)sp + (base + lane) * 16;

  auto STAGE = [&](int ks, int bsel) {
    char* dst = smem + (bsel << 15) + w * 8192;
    #pragma unroll
    for (int j = 0; j < 8; ++j) {
      const int fq_ = j >> 1, half = j & 1;
      GLD16(srcb + (((size_t)(ks * 4 + fq_)) * rstride + half * 64) * 16,
            dst + fq_ * 2048 + half * 1024);
    }
  };

  f32x4 acc[4][4] = {};

  STAGE(0, 0);
  __syncthreads();

  for (int ks = 0; ks < 8; ++ks) {
    char* cur = smem + ((ks & 1) << 15);
    if (ks < 7) STAGE(ks + 1, (ks & 1) ^ 1);

    bf16x8 afh[4], afl[4], bfh[4], bfl[4];
    #pragma unroll
    for (int i = 0; i < 4; ++i) {
      const int ro = fq * 2048 + (wr + i * 16 + fm) * 16;
      const int co = fq * 2048 + (wc + i * 16 + fm) * 16;
      afh[i] = *(const bf16x8*)(cur + ro);
      afl[i] = *(const bf16x8*)(cur + 8192 + ro);
      bfh[i] = *(const bf16x8*)(cur + 16384 + co);
      bfl[i] = *(const bf16x8*)(cur + 24576 + co);
    }
    #pragma unroll
    for (int mi = 0; mi < 4; ++mi)
      #pragma unroll
      for (int ni = 0; ni < 4; ++ni) {
        acc[mi][ni] = __builtin_amdgcn_mfma_f32_16x16x32_bf16(afh[mi], bfl[ni], acc[mi][ni], 0, 0, 0);
        acc[mi][ni] = __builtin_amdgcn_mfma_f32_16x16x32_bf16(afl[mi], bfh[ni], acc[mi][ni], 0, 0, 0);
        acc[mi][ni] = __builtin_amdgcn_mfma_f32_16x16x32_bf16(afh[mi], bfh[ni], acc[mi][ni], 0, 0, 0);
      }

    __syncthreads();
  }

  // epilogue: lg = 10*tanh(acc/16) + mask; e = exp(lg-10); sum (guard t<513)
  float lsum = 0.f;
  #pragma unroll
  for (int mi = 0; mi < 4; ++mi) {
    #pragma unroll
    for (int r = 0; r < 4; ++r) {
      const int m = wr + mi * 16 + fq * 4 + r;
      #pragma unroll
      for (int ni = 0; ni < 4; ++ni) {
        const int t = bx * 128 + wc + ni * 16 + fm;
        if (t < 513) {
          const float lg = 10.f * tanhf(acc[mi][ni][r] * 0.0625f)
                         + mask[((size_t)(b * 128 + m)) * 513 + t];
          const float e = __expf(lg - 10.f);
          out[(size_t)b * 65664 + (size_t)m * 513 + t] = e;
          lsum += e;
        }
      }
    }
  }
  #pragma unroll
  for (int off = 32; off; off >>= 1) lsum += __shfl_xor(lsum, off);
  if (lane == 0) red[w] = lsum;
  __syncthreads();
  if (tid == 0)
    partials[b * 5 + bx] = (red[0] + red[1]) + (red[2] + red[3]);
}

// Reduce 5 partials per batch -> 1/sum.
__global__ void sm_inv(const float* __restrict__ partials, float* __restrict__ invb)
{
  const int b = threadIdx.x;
  if (b < 64) {
    float s = 0.f;
    #pragma unroll
    for (int i = 0; i < 5; ++i) s += partials[b * 5 + i];
    invb[b] = 1.f / s;
  }
}

__global__ __launch_bounds__(256) void sm_norm(float* __restrict__ out,
                                               const float* __restrict__ invb)
{
  const int i4 = blockIdx.x * 256 + threadIdx.x;
  if (i4 < 1050624) {
    const int b = i4 / 16416;
    float4 v = ((float4*)out)[i4];
    const float s = invb[b];
    v.x *= s; v.y *= s; v.z *= s; v.w *= s;
    ((float4*)out)[i4] = v;
  }
}

// ---------------------------------------------------------------------------
extern "C" void kernel_launch(void* const* d_in, const int* in_sizes, int n_in,
                              void* d_out, int out_size, void* d_ws, size_t ws_size,
                              hipStream_t stream)
{
  const float* machine = (const float*)d_in[0];
  const float* jobs    = (const float*)d_in[1];
  const float* mask    = (const float*)d_in[2];
  const float* Wq      = (const float*)d_in[3];
  const float* Wk      = (const float*)d_in[4];
  const float* Wv      = (const float*)d_in[5];
  const float* Wc      = (const float*)d_in[6];
  const float* bc      = (const float*)d_in[7];
  const float* skip    = (const float*)d_in[8];

  // Workspace (floats). Peak ~26,870,144 f ~ 107.5 MB.
  //   [0,        8912896)  Jh|Jl chunk-major jobs planes (LIVE until logits)
  //   [8912896, 17825792)  Kh|Kl bf16 planes [34816][256] (dead after attn)
  //        overlays after attn: Mh|Ml chunk-major MH planes (2M floats)
  //   [17825792,26738688)  Vth|Vtl transposed planes [64][256][544]
  //   [26738688,26869760)  Wh|Wl chunk-major W planes
  //   [26869760,26870144)  partials/invb
  // d_out (4,202,496 f) used as scratch pre-logits: Qw [0,2M), OC [2M,4M).
  float* ws       = (float*)d_ws;
  unsigned short* JhP = (unsigned short*)ws;
  unsigned short* JlP = JhP + 8912896;
  unsigned short* KhP = (unsigned short*)(ws + 8912896);
  unsigned short* KlP = KhP + 8912896;
  unsigned short* VthP = (unsigned short*)(ws + 17825792);
  unsigned short* VtlP = VthP + 8912896;
  unsigned short* WhP = (unsigned short*)(ws + 26738688);
  unsigned short* WlP = WhP + 131072;
  unsigned short* MhP = (unsigned short*)(ws + 8912896);   // overlays Kh (dead after attn)
  unsigned short* MlP = MhP + 2097152;
  float* partials = ws + 26869760;
  float* invb     = partials + 320;
  float* out      = (float*)d_out;
  float* Qw       = out;                 // d_out scratch (dead before logits writes)
  float* OC       = out + 2097152;

  // prep: W planes + jobs planes (chunk-major pre-split bf16)
  prep_wt<<<512, 256, 0, stream>>>(Wk, Wv, WhP, WlP);
  prep_jobs<<<544, 256, 0, stream>>>(jobs, skip, JhP, JlP);
  // K|V projection: pure bf16 MFMA, coalesced global_load_lds, 2-phase dbuf
  gemm_kv_mfma<<<dim3(4, 272), 256, 0, stream>>>(
      JhP, JlP, WhP, WlP, KhP, KlP, VthP, VtlP);
  // Q = machine @ Wq3 (fp32) -> d_out scratch
  gemm_wide<0><<<dim3(2, 128), 256, 0, stream>>>(
      machine, Wq, nullptr, Qw, nullptr, nullptr);
  // MFMA attention on pre-split K/V planes -> OC (d_out scratch)
  attn_mfma<<<dim3(16, 64), 256, 0, stream>>>(Qw, KhP, KlP, VthP, VtlP, OC);
  // mh = out_concat @ Wc + bc -> chunk-major split planes (overlay K region)
  gemm_wide<1><<<dim3(2, 128), 256, 0, stream>>>(
      OC, Wc, bc, nullptr, MhP, MlP);
  // logits: coalesced-staged split-bf16 MFMA + fused exp epilogue + partials
  logits_mfma<<<dim3(5, 64), 256, 0, stream>>>(
      MhP, MlP, JhP, JlP, mask, out, partials);
  sm_inv<<<1, 64, 0, stream>>>(partials, invb);
  sm_norm<<<4104, 256, 0, stream>>>(out, invb);
}

// Round 6
// 301.819 us; speedup vs baseline: 1.1051x; 1.0068x over previous
//
#include <hip/hip_runtime.h>
#include <math.h>

// B=64, M=128, J=512, T=513 (padded to TPAD=544), E=256, H=16, D=16; out (64, 65664) fp32.

#define LDT 68    // 64-row A-tile LDS leading dim (fp32 gemms)
#define LDB 132   // 128-col B-tile LDS leading dim (fp32 gemms)
#define TPAD 544  // 17 * 32; rows 513..543 are zero pads (exp(0)=1 -> subtract 31 from l)
#define NROWS 34816  // 64 * TPAD

typedef __attribute__((ext_vector_type(8))) short bf16x8;   // 8 bf16 = 4 VGPR
typedef __attribute__((ext_vector_type(8))) unsigned short u16x8;
typedef __attribute__((ext_vector_type(4))) float f32x4;    // MFMA acc
typedef __attribute__((ext_vector_type(4))) unsigned short u16x4;

static __device__ inline unsigned short f2bf(float x) {     // RNE fp32->bf16
  unsigned u = __float_as_uint(x);
  return (unsigned short)((u + 0x7fffu + ((u >> 16) & 1u)) >> 16);
}
static __device__ inline float bf2f(unsigned short h) {
  return __uint_as_float(((unsigned)h) << 16);
}

// global -> LDS direct DMA, 16B per lane; ldst wave-uniform (HW adds lane*16),
// gsrc is per-lane (contiguous runs: base + lane*16).
#define GLD16(gsrc, ldst) \
  __builtin_amdgcn_global_load_lds((const __attribute__((address_space(1))) void*)(gsrc), \
                                   (__attribute__((address_space(3))) void*)(ldst), 16, 0, 0)

// ---------------------------------------------------------------------------
// W split+transpose -> CHUNK-MAJOR planes: Wh/Wl[chunk 0..31][512 cols][8 bf16].
// col 0..255 = Wk cols, 256..511 = Wv cols. One block per col.
// ---------------------------------------------------------------------------
__global__ void prep_wt(const float* __restrict__ Wk, const float* __restrict__ Wv,
                        unsigned short* __restrict__ Wh, unsigned short* __restrict__ Wl)
{
  __shared__ unsigned short sh[256], sl[256];
  const int c = blockIdx.x, k = threadIdx.x;
  const float x = (c < 256) ? Wk[k * 256 + c] : Wv[k * 256 + (c - 256)];
  const unsigned short h = f2bf(x);
  sh[k] = h; sl[k] = f2bf(x - bf2f(h));
  __syncthreads();
  if (k < 32)
    *(u16x8*)(Wh + ((size_t)k * 512 + c) * 8) = *(const u16x8*)&sh[k * 8];
  else if (k < 64)
    *(u16x8*)(Wl + ((size_t)(k - 32) * 512 + c) * 8) = *(const u16x8*)&sl[(k - 32) * 8];
}

// ---------------------------------------------------------------------------
// jobs_padded split -> CHUNK-MAJOR planes: Jh/Jl[chunk 0..31][34816 rows][8 bf16].
// Row r = (b, t): t=0 skip, 1..512 jobs, >=513 zero pads. Writes are
// lane-contiguous 1KB runs. grid 544 x 256 (wave w owns chunks w*8..w*8+8).
// ---------------------------------------------------------------------------
__global__ __launch_bounds__(256) void prep_jobs(
    const float* __restrict__ jobs, const float* __restrict__ skip,
    unsigned short* __restrict__ Jh, unsigned short* __restrict__ Jl)
{
  const int w = threadIdx.x >> 6, lane = threadIdx.x & 63;
  const int r = blockIdx.x * 64 + lane;          // 0..34815
  const int bb = r / TPAD, tt = r - bb * TPAD;
  const bool padr = (tt >= 513);
  const float* src = (tt == 0) ? skip : (jobs + ((size_t)(bb * 512 + tt - 1) << 8));
  #pragma unroll
  for (int i = 0; i < 8; ++i) {
    const int cc = w * 8 + i;                    // chunk 0..31
    u16x8 h8 = {}, l8 = {};
    if (!padr) {
      const float4 a = *(const float4*)(src + cc * 8);
      const float4 b = *(const float4*)(src + cc * 8 + 4);
      const float v[8] = {a.x,a.y,a.z,a.w, b.x,b.y,b.z,b.w};
      #pragma unroll
      for (int j = 0; j < 8; ++j) {
        const unsigned short hh = f2bf(v[j]);
        h8[j] = hh;
        l8[j] = f2bf(v[j] - bf2f(hh));
      }
    }
    const size_t o = ((size_t)cc * NROWS + r) * 8;
    *(u16x8*)(Jh + o) = h8;
    *(u16x8*)(Jl + o) = l8;
  }
}

// ---------------------------------------------------------------------------
// KV projection: C(34816 x 512) = vjobs_padded @ [Wk|Wv], pure pre-split bf16.
// 128x128 tile, 4 waves (2x2 of 64x64). T4 counted-vmcnt pipeline (depth 2):
//   prologue: STAGE(0,b0), STAGE(1,b1)
//   step ks:  s_waitcnt vmcnt(8)  <- own stage(ks) landed, stage(ks+1) IN FLIGHT
//             s_barrier           <- all waves' planes landed
//             ds_read + MFMA on buf(ks&1)
//             s_barrier           <- reads done, buf reusable
//             STAGE(ks+2, buf(ks&1))
// (NOT __syncthreads: that emits vmcnt(0) and drains the pipeline - R2/R4 bug.)
// Staging: 8 contiguous-1KB global_load_lds per wave, conflict-free chunk-major.
// C = Ah*Bh + Ah*Bl + Al*Bh. Outputs: K bf16 hi/lo planes [34816][256];
// V TRANSPOSED bf16 hi/lo planes [b][256 cols][544 t].
// ---------------------------------------------------------------------------
__global__ __launch_bounds__(256) void gemm_kv_mfma(
    const unsigned short* __restrict__ Jh, const unsigned short* __restrict__ Jl,
    const unsigned short* __restrict__ Wh, const unsigned short* __restrict__ Wl,
    unsigned short* __restrict__ Kh, unsigned short* __restrict__ Kl,
    unsigned short* __restrict__ Vth, unsigned short* __restrict__ Vtl)
{
  __shared__ __align__(128) char smem[65536];  // buf: Ah|Al|Bh|Bl 8KB each, x2
  const int tid = threadIdx.x;
  const int lin = blockIdx.x + (blockIdx.y << 2);        // 0..1087
  const int virt = (lin & 7) * 136 + (lin >> 3);         // bijective (1088%8==0)
  const int bx = virt & 3, by = virt >> 2;
  const int w = __builtin_amdgcn_readfirstlane(tid >> 6);
  const int lane = tid & 63;
  const int wr = (w >> 1) << 6, wc = (w & 1) << 6;
  const int fm = lane & 15, fq = lane >> 4;

  // wave w's source plane + per-lane base (row/col block + lane)
  const unsigned short* sp = (w == 0) ? Jh : (w == 1) ? Jl : (w == 2) ? Wh : Wl;
  const size_t rstride = (w < 2) ? (size_t)NROWS : (size_t)512;
  const size_t blk = (w < 2) ? (size_t)(by * 128) : (size_t)(bx * 128);
  const char* srcb = (const char*)sp + (blk + lane) * 16;

  auto STAGE = [&](int ks, int bsel) {
    char* dst = smem + (bsel << 15) + w * 8192;
    #pragma unroll
    for (int j = 0; j < 8; ++j) {
      const int fq_ = j >> 1, half = j & 1;
      GLD16(srcb + (((size_t)(ks * 4 + fq_)) * rstride + half * 64) * 16,
            dst + fq_ * 2048 + half * 1024);
    }
  };

  f32x4 acc[4][4] = {};

  STAGE(0, 0);
  STAGE(1, 1);

  #pragma unroll
  for (int ks = 0; ks < 8; ++ks) {
    // own stage(ks) landed; keep stage(ks+1)'s 8 loads in flight
    if (ks < 7) asm volatile("s_waitcnt vmcnt(8)" ::: "memory");
    else        asm volatile("s_waitcnt vmcnt(0)" ::: "memory");
    __builtin_amdgcn_s_barrier();          // all waves' planes landed
    __builtin_amdgcn_sched_barrier(0);     // pin: no LDS reads hoisted above

    char* cur = smem + ((ks & 1) << 15);
    bf16x8 afh[4], afl[4], bfh[4], bfl[4];
    #pragma unroll
    for (int i = 0; i < 4; ++i) {
      const int ro = fq * 2048 + (wr + i * 16 + fm) * 16;
      const int co = fq * 2048 + (wc + i * 16 + fm) * 16;
      afh[i] = *(const bf16x8*)(cur + ro);
      afl[i] = *(const bf16x8*)(cur + 8192 + ro);
      bfh[i] = *(const bf16x8*)(cur + 16384 + co);
      bfl[i] = *(const bf16x8*)(cur + 24576 + co);
    }
    #pragma unroll
    for (int mi = 0; mi < 4; ++mi)
      #pragma unroll
      for (int ni = 0; ni < 4; ++ni) {
        acc[mi][ni] = __builtin_amdgcn_mfma_f32_16x16x32_bf16(afh[mi], bfl[ni], acc[mi][ni], 0, 0, 0);
        acc[mi][ni] = __builtin_amdgcn_mfma_f32_16x16x32_bf16(afl[mi], bfh[ni], acc[mi][ni], 0, 0, 0);
        acc[mi][ni] = __builtin_amdgcn_mfma_f32_16x16x32_bf16(afh[mi], bfh[ni], acc[mi][ni], 0, 0, 0);
      }

    __builtin_amdgcn_s_barrier();          // all reads of cur done -> reusable
    if (ks + 2 < 8) STAGE(ks + 2, ks & 1); // issue 2-ahead, stays in flight
  }

  // ---- epilogue: RNE hi/lo bf16 planes ----
  const int cb = ((bx & 1) << 7) + wc;
  if (bx < 2) {
    // K planes, row-major [34816][256]
    #pragma unroll
    for (int mi = 0; mi < 4; ++mi) {
      #pragma unroll
      for (int r = 0; r < 4; ++r) {
        const int row = by * 128 + wr + mi * 16 + fq * 4 + r;
        const size_t rb = (size_t)row << 8;
        #pragma unroll
        for (int ni = 0; ni < 4; ++ni) {
          const int cc = cb + ni * 16 + fm;
          const float x = acc[mi][ni][r];
          const unsigned short hh = f2bf(x);
          Kh[rb + cc] = hh;
          Kl[rb + cc] = f2bf(x - bf2f(hh));
        }
      }
    }
  } else {
    // V transposed planes [b][256][544]; 4 consecutive t per frag reg quad
    #pragma unroll
    for (int mi = 0; mi < 4; ++mi) {
      const int row0 = by * 128 + wr + mi * 16 + fq * 4;   // 4-aligned, same b
      const int bb = row0 / TPAD;
      const int tt0 = row0 - bb * TPAD;
      #pragma unroll
      for (int ni = 0; ni < 4; ++ni) {
        const int cc = cb + ni * 16 + fm;
        const size_t vb = ((size_t)(bb * 256 + cc)) * TPAD + tt0;
        u16x4 vh, vl;
        #pragma unroll
        for (int r = 0; r < 4; ++r) {
          const float x = acc[mi][ni][r];
          const unsigned short hh = f2bf(x);
          vh[r] = hh;
          vl[r] = f2bf(x - bf2f(hh));
        }
        *(u16x4*)(Vth + vb) = vh;
        *(u16x4*)(Vtl + vb) = vl;
      }
    }
  }
}

// ---------------------------------------------------------------------------
// Wide tiled fp32 GEMM (Q and Wc projections): C[rows x 256] = A @ W (+bias).
// MODE 0: fp32 output C1. MODE 1: output split bf16 hi/lo CHUNK-MAJOR planes
// Ch/Cl[chunk 0..31][8192 rows][8 bf16] (feeds logits_mfma staging).
// ---------------------------------------------------------------------------
template<int MODE>
__global__ __launch_bounds__(256) void gemm_wide(
    const float* __restrict__ A, const float* __restrict__ W,
    const float* __restrict__ bias, float* __restrict__ C1,
    unsigned short* __restrict__ Ch, unsigned short* __restrict__ Cl)
{
  __shared__ float As[16 * LDT];
  __shared__ float Bs[16 * LDB];
  const int tid = threadIdx.x;
  const int bx = blockIdx.x, by = blockIdx.y;
  const int col0 = bx * 128;

  const int a_row = tid >> 2;
  const int a_k4  = (tid & 3) << 2;
  const float* arow = A + ((size_t)(by * 64 + a_row) << 8);

  const int b_k  = tid >> 4;
  const int b_c8 = (tid & 15) << 3;

  const int tr = tid >> 4, tc = tid & 15;
  float acc[4][8] = {};

  for (int k0 = 0; k0 < 256; k0 += 16) {
    const float4 av  = *(const float4*)(arow + k0 + a_k4);
    const float4 bv0 = *(const float4*)(W + ((size_t)(k0 + b_k) << 8) + col0 + b_c8);
    const float4 bv1 = *(const float4*)(W + ((size_t)(k0 + b_k) << 8) + col0 + b_c8 + 4);
    __syncthreads();
    As[(a_k4 + 0) * LDT + a_row] = av.x;
    As[(a_k4 + 1) * LDT + a_row] = av.y;
    As[(a_k4 + 2) * LDT + a_row] = av.z;
    As[(a_k4 + 3) * LDT + a_row] = av.w;
    *(float4*)&Bs[b_k * LDB + b_c8]     = bv0;
    *(float4*)&Bs[b_k * LDB + b_c8 + 4] = bv1;
    __syncthreads();
    #pragma unroll
    for (int k = 0; k < 16; ++k) {
      const float4 a  = *(const float4*)&As[k * LDT + (tr << 2)];
      const float4 b0 = *(const float4*)&Bs[k * LDB + (tc << 3)];
      const float4 b1 = *(const float4*)&Bs[k * LDB + (tc << 3) + 4];
      const float aa[4] = {a.x, a.y, a.z, a.w};
      #pragma unroll
      for (int i = 0; i < 4; ++i) {
        acc[i][0] = fmaf(aa[i], b0.x, acc[i][0]);
        acc[i][1] = fmaf(aa[i], b0.y, acc[i][1]);
        acc[i][2] = fmaf(aa[i], b0.z, acc[i][2]);
        acc[i][3] = fmaf(aa[i], b0.w, acc[i][3]);
        acc[i][4] = fmaf(aa[i], b1.x, acc[i][4]);
        acc[i][5] = fmaf(aa[i], b1.y, acc[i][5]);
        acc[i][6] = fmaf(aa[i], b1.z, acc[i][6]);
        acc[i][7] = fmaf(aa[i], b1.w, acc[i][7]);
      }
    }
  }

  const int oc = col0 + (tc << 3);
  float4 bsa = make_float4(0.f,0.f,0.f,0.f), bsb = make_float4(0.f,0.f,0.f,0.f);
  if (bias) { bsa = *(const float4*)(bias + oc); bsb = *(const float4*)(bias + oc + 4); }
  const float bb[8] = {bsa.x,bsa.y,bsa.z,bsa.w, bsb.x,bsb.y,bsb.z,bsb.w};
  #pragma unroll
  for (int i = 0; i < 4; ++i) {
    const int row = by * 64 + (tr << 2) + i;
    if (MODE == 0) {
      float* crow = C1 + ((size_t)row << 8) + oc;
      float4 o0, o1;
      o0.x = acc[i][0]+bb[0]; o0.y = acc[i][1]+bb[1]; o0.z = acc[i][2]+bb[2]; o0.w = acc[i][3]+bb[3];
      o1.x = acc[i][4]+bb[4]; o1.y = acc[i][5]+bb[5]; o1.z = acc[i][6]+bb[6]; o1.w = acc[i][7]+bb[7];
      *(float4*)crow = o0; *(float4*)(crow + 4) = o1;
    } else {
      // chunk-major split planes: chunk = oc>>3, 8 cols per chunk
      u16x8 h8, l8;
      #pragma unroll
      for (int j = 0; j < 8; ++j) {
        const float x = acc[i][j] + bb[j];
        const unsigned short hh = f2bf(x);
        h8[j] = hh;
        l8[j] = f2bf(x - bf2f(hh));
      }
      const size_t o = ((size_t)(oc >> 3) * 8192 + row) * 8;
      *(u16x8*)(Ch + o) = h8;
      *(u16x8*)(Cl + o) = l8;
    }
  }
}

// ---------------------------------------------------------------------------
// MFMA attention v8: one block per (h, b), 256 thr = 4 waves (m-half x t-half).
// K/V read as pre-split bf16 planes: each lane loads ONE 16B ushort8 per
// frag (hi plane for lane groups 0,1; lo plane for 2,3). V from transposed
// planes (contiguous t). P split: trunc-hi + RNE-lo via v_perm.
// Pads t=513..543 are zero -> exp=1 exactly: subtract 31 from l.
// ---------------------------------------------------------------------------
__global__ __launch_bounds__(256, 4) void attn_mfma(
    const float* __restrict__ Q,
    const unsigned short* __restrict__ Kh, const unsigned short* __restrict__ Kl,
    const unsigned short* __restrict__ Vth, const unsigned short* __restrict__ Vtl,
    float* __restrict__ OC)
{
  const int h = blockIdx.x, b = blockIdx.y;
  const int tid = threadIdx.x;
  const int lane = tid & 63;
  const int w = __builtin_amdgcn_readfirstlane(tid >> 6);
  const int g = lane >> 4, fm = lane & 15;
  const int mh = (w & 2) << 5;              // 0 or 64
  const int th = w & 1;                     // t-half
  const int send = th ? 17 : 9;             // steps [0,9) | [9,17)
  int s = th ? 9 : 0;

  __shared__ float red[2 * 64 * 21];        // 10.5 KB, stride-21 (conflict-free)

  const int col = h * 16;
  const int dbase = (g & 1) << 3;           // d 0..7 | 8..15 per group parity

  // ---- Q B-frags (persistent, RNE): Bq1 = [Qh|Qh], Bq2 = [Ql|0] ----
  bf16x8 Bq1[4], Bq2[4];
  #pragma unroll
  for (int mt = 0; mt < 4; ++mt) {
    const float* qp = Q + ((size_t)(b * 128 + mh + mt * 16 + fm) << 8) + col + dbase;
    const float4 q0 = *(const float4*)qp;
    const float4 q1 = *(const float4*)(qp + 4);
    const float qv[8] = {q0.x,q0.y,q0.z,q0.w, q1.x,q1.y,q1.z,q1.w};
    #pragma unroll
    for (int j = 0; j < 8; ++j) {
      const float x = qv[j] * 0.25f;        // fold 1/sqrt(QKV)
      const unsigned short hh = f2bf(x);
      Bq1[mt][j] = (short)hh;
      Bq2[mt][j] = (short)((g < 2) ? f2bf(x - bf2f(hh)) : (unsigned short)0);
    }
  }

  f32x4 oT[4] = {};
  float lsum[4] = {0.f, 0.f, 0.f, 0.f};

  // per-lane plane pointers (hoisted)
  const int rA = ((fm & 12) << 1) + (fm & 3);   // permuted K row within step
  const unsigned short* kpl = ((g < 2) ? Kh : Kl)
      + ((((size_t)b * TPAD) + rA) << 8) + col + dbase;
  const unsigned short* vhp = Vth + ((size_t)(b * 256 + col + fm)) * TPAD + (g << 3);
  const unsigned short* vlp = Vtl + ((size_t)(b * 256 + col + fm)) * TPAD + (g << 3);

  for (; s < send; ++s) {
    const int t0 = s << 5;
    const bf16x8 KA = *(const bf16x8*)(kpl + ((size_t)t0 << 8));
    const bf16x8 KB = *(const bf16x8*)(kpl + ((size_t)(t0 + 4) << 8));
    const bf16x8 Vh = *(const bf16x8*)(vhp + t0);
    const bf16x8 Vl = *(const bf16x8*)(vlp + t0);

    #pragma unroll
    for (int mt = 0; mt < 4; ++mt) {
      f32x4 sA = {}, sB = {};
      sA = __builtin_amdgcn_mfma_f32_16x16x32_bf16(KA, Bq1[mt], sA, 0, 0, 0);
      sA = __builtin_amdgcn_mfma_f32_16x16x32_bf16(KA, Bq2[mt], sA, 0, 0, 0);
      sB = __builtin_amdgcn_mfma_f32_16x16x32_bf16(KB, Bq1[mt], sB, 0, 0, 0);
      sB = __builtin_amdgcn_mfma_f32_16x16x32_bf16(KB, Bq2[mt], sB, 0, 0, 0);
      // lane holds P[t0+8g+r][m] (tileA r=0..3) and P[t0+8g+4+r][m] (tileB)
      float p[8];
      p[0] = __expf(sA[0]); p[1] = __expf(sA[1]); p[2] = __expf(sA[2]); p[3] = __expf(sA[3]);
      p[4] = __expf(sB[0]); p[5] = __expf(sB[1]); p[6] = __expf(sB[2]); p[7] = __expf(sB[3]);
      lsum[mt] += ((p[0] + p[1]) + (p[2] + p[3])) + ((p[4] + p[5]) + (p[6] + p[7]));
      bf16x8 Ph, Pl;
      #pragma unroll
      for (int jp = 0; jp < 4; ++jp) {
        const unsigned u0 = __float_as_uint(p[2*jp]);
        const unsigned u1 = __float_as_uint(p[2*jp+1]);
        ((unsigned*)&Ph)[jp] = __builtin_amdgcn_perm(u1, u0, 0x07060302u);
        const float r0 = p[2*jp]   - __uint_as_float(u0 & 0xffff0000u);
        const float r1 = p[2*jp+1] - __uint_as_float(u1 & 0xffff0000u);
        unsigned t0_ = __float_as_uint(r0); t0_ += 0x7fffu + ((t0_ >> 16) & 1u);
        unsigned t1_ = __float_as_uint(r1); t1_ += 0x7fffu + ((t1_ >> 16) & 1u);
        ((unsigned*)&Pl)[jp] = __builtin_amdgcn_perm(t1_, t0_, 0x07060302u);
      }
      oT[mt] = __builtin_amdgcn_mfma_f32_16x16x32_bf16(Vh, Ph, oT[mt], 0, 0, 0);
      oT[mt] = __builtin_amdgcn_mfma_f32_16x16x32_bf16(Vh, Pl, oT[mt], 0, 0, 0);
      oT[mt] = __builtin_amdgcn_mfma_f32_16x16x32_bf16(Vl, Ph, oT[mt], 0, 0, 0);
    }
  }

  // ---- pair reduce (t-half 1 -> t-half 0), then normalize + write ----
  float* slot = red + ((w >> 1) * 1344);
  const int base = lane * 21;
  if (th) {
    #pragma unroll
    for (int mt = 0; mt < 4; ++mt) {
      slot[base + 4 * mt + 0] = oT[mt][0];
      slot[base + 4 * mt + 1] = oT[mt][1];
      slot[base + 4 * mt + 2] = oT[mt][2];
      slot[base + 4 * mt + 3] = oT[mt][3];
      slot[base + 16 + mt]    = lsum[mt];
    }
  }
  __syncthreads();
  if (!th) {
    #pragma unroll
    for (int mt = 0; mt < 4; ++mt) {
      oT[mt][0] += slot[base + 4 * mt + 0];
      oT[mt][1] += slot[base + 4 * mt + 1];
      oT[mt][2] += slot[base + 4 * mt + 2];
      oT[mt][3] += slot[base + 4 * mt + 3];
      float v = lsum[mt] + slot[base + 16 + mt];
      v += __shfl_xor(v, 16);
      v += __shfl_xor(v, 32);
      const float inv = 1.f / (v - 31.f);     // remove 31 pad rows (exp(0)=1)
      float4 o;
      o.x = oT[mt][0] * inv; o.y = oT[mt][1] * inv;
      o.z = oT[mt][2] * inv; o.w = oT[mt][3] * inv;
      // oT reg r = out[m][d = 4g + r]
      *(float4*)(OC + ((size_t)(b * 128 + mh + mt * 16 + fm) << 8) + col + (g << 2)) = o;
    }
  }
}

// ---------------------------------------------------------------------------
// Logits v2 + T4 pipeline: C(128 x 513) per b = MH(128 x 256) @ vjobs^T.
// A = MH chunk-major split planes (gemm_wide<1>), B = Jh/Jl planes. Same
// counted-vmcnt raw-barrier loop as gemm_kv_mfma (see comment there).
// bx=4 window t>=513 guarded at epilogue. Fused epilogue:
// e = exp(10*tanh(x/16)+mask-10), deterministic partials[b*5+bx].
// ---------------------------------------------------------------------------
__global__ __launch_bounds__(256) void logits_mfma(
    const unsigned short* __restrict__ Mh, const unsigned short* __restrict__ Ml,
    const unsigned short* __restrict__ Jh, const unsigned short* __restrict__ Jl,
    const float* __restrict__ mask,
    float* __restrict__ out, float* __restrict__ partials)
{
  __shared__ __align__(128) char smem[65536];  // buf: Ah|Al|Bh|Bl 8KB each, x2
  __shared__ float red[4];
  const int tid = threadIdx.x;
  const int lin = blockIdx.x + blockIdx.y * 5;           // 0..319
  const int virt = (lin & 7) * 40 + (lin >> 3);          // bijective (320%8==0)
  const int bx = virt % 5;                               // t-tile
  const int b  = virt / 5;
  const int w = __builtin_amdgcn_readfirstlane(tid >> 6);
  const int lane = tid & 63;
  const int wr = (w >> 1) << 6, wc = (w & 1) << 6;
  const int fm = lane & 15, fq = lane >> 4;

  const unsigned short* sp = (w == 0) ? Mh : (w == 1) ? Ml : (w == 2) ? Jh : Jl;
  const size_t rstride = (w < 2) ? (size_t)8192 : (size_t)NROWS;
  const size_t base = (w < 2) ? (size_t)(b * 128) : ((size_t)b * TPAD + bx * 128);
  const char* srcb = (const char*)sp + (base + lane) * 16;

  auto STAGE = [&](int ks, int bsel) {
    char* dst = smem + (bsel << 15) + w * 8192;
    #pragma unroll
    for (int j = 0; j < 8; ++j) {
      const int fq_ = j >> 1, half = j & 1;
      GLD16(srcb + (((size_t)(ks * 4 + fq_)) * rstride + half * 64) * 16,
            dst + fq_ * 2048 + half * 1024);
    }
  };

  f32x4 acc[4][4] = {};

  STAGE(0, 0);
  STAGE(1, 1);

  #pragma unroll
  for (int ks = 0; ks < 8; ++ks) {
    if (ks < 7) asm volatile("s_waitcnt vmcnt(8)" ::: "memory");
    else        asm volatile("s_waitcnt vmcnt(0)" ::: "memory");
    __builtin_amdgcn_s_barrier();
    __builtin_amdgcn_sched_barrier(0);

    char* cur = smem + ((ks & 1) << 15);
    bf16x8 afh[4], afl[4], bfh[4], bfl[4];
    #pragma unroll
    for (int i = 0; i < 4; ++i) {
      const int ro = fq * 2048 + (wr + i * 16 + fm) * 16;
      const int co = fq * 2048 + (wc + i * 16 + fm) * 16;
      afh[i] = *(const bf16x8*)(cur + ro);
      afl[i] = *(const bf16x8*)(cur + 8192 + ro);
      bfh[i] = *(const bf16x8*)(cur + 16384 + co);
      bfl[i] = *(const bf16x8*)(cur + 24576 + co);
    }
    #pragma unroll
    for (int mi = 0; mi < 4; ++mi)
      #pragma unroll
      for (int ni = 0; ni < 4; ++ni) {
        acc[mi][ni] = __builtin_amdgcn_mfma_f32_16x16x32_bf16(afh[mi], bfl[ni], acc[mi][ni], 0, 0, 0);
        acc[mi][ni] = __builtin_amdgcn_mfma_f32_16x16x32_bf16(afl[mi], bfh[ni], acc[mi][ni], 0, 0, 0);
        acc[mi][ni] = __builtin_amdgcn_mfma_f32_16x16x32_bf16(afh[mi], bfh[ni], acc[mi][ni], 0, 0, 0);
      }

    __builtin_amdgcn_s_barrier();
    if (ks + 2 < 8) STAGE(ks + 2, ks & 1);
  }

  // epilogue: lg = 10*tanh(acc/16) + mask; e = exp(lg-10); sum (guard t<513)
  float lsum = 0.f;
  #pragma unroll
  for (int mi = 0; mi < 4; ++mi) {
    #pragma unroll
    for (int r = 0; r < 4; ++r) {
      const int m = wr + mi * 16 + fq * 4 + r;
      #pragma unroll
      for (int ni = 0; ni < 4; ++ni) {
        const int t = bx * 128 + wc + ni * 16 + fm;
        if (t < 513) {
          const float lg = 10.f * tanhf(acc[mi][ni][r] * 0.0625f)
                         + mask[((size_t)(b * 128 + m)) * 513 + t];
          const float e = __expf(lg - 10.f);
          out[(size_t)b * 65664 + (size_t)m * 513 + t] = e;
          lsum += e;
        }
      }
    }
  }
  #pragma unroll
  for (int off = 32; off; off >>= 1) lsum += __shfl_xor(lsum, off);
  if (lane == 0) red[w] = lsum;
  __syncthreads();
  if (tid == 0)
    partials[b * 5 + bx] = (red[0] + red[1]) + (red[2] + red[3]);
}

// Reduce 5 partials per batch -> 1/sum.
__global__ void sm_inv(const float* __restrict__ partials, float* __restrict__ invb)
{
  const int b = threadIdx.x;
  if (b < 64) {
    float s = 0.f;
    #pragma unroll
    for (int i = 0; i < 5; ++i) s += partials[b * 5 + i];
    invb[b] = 1.f / s;
  }
}

__global__ __launch_bounds__(256) void sm_norm(float* __restrict__ out,
                                               const float* __restrict__ invb)
{
  const int i4 = blockIdx.x * 256 + threadIdx.x;
  if (i4 < 1050624) {
    const int b = i4 / 16416;
    float4 v = ((float4*)out)[i4];
    const float s = invb[b];
    v.x *= s; v.y *= s; v.z *= s; v.w *= s;
    ((float4*)out)[i4] = v;
  }
}

// ---------------------------------------------------------------------------
extern "C" void kernel_launch(void* const* d_in, const int* in_sizes, int n_in,
                              void* d_out, int out_size, void* d_ws, size_t ws_size,
                              hipStream_t stream)
{
  const float* machine = (const float*)d_in[0];
  const float* jobs    = (const float*)d_in[1];
  const float* mask    = (const float*)d_in[2];
  const float* Wq      = (const float*)d_in[3];
  const float* Wk      = (const float*)d_in[4];
  const float* Wv      = (const float*)d_in[5];
  const float* Wc      = (const float*)d_in[6];
  const float* bc      = (const float*)d_in[7];
  const float* skip    = (const float*)d_in[8];

  // Workspace (floats). Peak ~26,870,144 f ~ 107.5 MB.
  //   [0,        8912896)  Jh|Jl chunk-major jobs planes (LIVE until logits)
  //   [8912896, 17825792)  Kh|Kl bf16 planes [34816][256] (dead after attn)
  //        overlays after attn: Mh|Ml chunk-major MH planes (2M floats)
  //   [17825792,26738688)  Vth|Vtl transposed planes [64][256][544]
  //   [26738688,26869760)  Wh|Wl chunk-major W planes
  //   [26869760,26870144)  partials/invb
  // d_out (4,202,496 f) used as scratch pre-logits: Qw [0,2M), OC [2M,4M).
  float* ws       = (float*)d_ws;
  unsigned short* JhP = (unsigned short*)ws;
  unsigned short* JlP = JhP + 8912896;
  unsigned short* KhP = (unsigned short*)(ws + 8912896);
  unsigned short* KlP = KhP + 8912896;
  unsigned short* VthP = (unsigned short*)(ws + 17825792);
  unsigned short* VtlP = VthP + 8912896;
  unsigned short* WhP = (unsigned short*)(ws + 26738688);
  unsigned short* WlP = WhP + 131072;
  unsigned short* MhP = (unsigned short*)(ws + 8912896);   // overlays Kh (dead after attn)
  unsigned short* MlP = MhP + 2097152;
  float* partials = ws + 26869760;
  float* invb     = partials + 320;
  float* out      = (float*)d_out;
  float* Qw       = out;                 // d_out scratch (dead before logits writes)
  float* OC       = out + 2097152;

  // prep: W planes + jobs planes (chunk-major pre-split bf16)
  prep_wt<<<512, 256, 0, stream>>>(Wk, Wv, WhP, WlP);
  prep_jobs<<<544, 256, 0, stream>>>(jobs, skip, JhP, JlP);
  // K|V projection: pure bf16 MFMA, counted-vmcnt pipelined staging
  gemm_kv_mfma<<<dim3(4, 272), 256, 0, stream>>>(
      JhP, JlP, WhP, WlP, KhP, KlP, VthP, VtlP);
  // Q = machine @ Wq3 (fp32) -> d_out scratch
  gemm_wide<0><<<dim3(2, 128), 256, 0, stream>>>(
      machine, Wq, nullptr, Qw, nullptr, nullptr);
  // MFMA attention on pre-split K/V planes -> OC (d_out scratch)
  attn_mfma<<<dim3(16, 64), 256, 0, stream>>>(Qw, KhP, KlP, VthP, VtlP, OC);
  // mh = out_concat @ Wc + bc -> chunk-major split planes (overlay K region)
  gemm_wide<1><<<dim3(2, 128), 256, 0, stream>>>(
      OC, Wc, bc, nullptr, MhP, MlP);
  // logits: counted-vmcnt pipelined split-bf16 MFMA + fused exp epilogue
  logits_mfma<<<dim3(5, 64), 256, 0, stream>>>(
      MhP, MlP, JhP, JlP, mask, out, partials);
  sm_inv<<<1, 64, 0, stream>>>(partials, invb);
  sm_norm<<<4104, 256, 0, stream>>>(out, invb);
}

// Round 8
// 294.893 us; speedup vs baseline: 1.1311x; 1.0235x over previous
//
#include <hip/hip_runtime.h>
#include <math.h>

// B=64, M=128, J=512, T=513 (padded to TPAD=544), E=256, H=16, D=16; out (64, 65664) fp32.

#define LDT 68    // 64-row A-tile LDS leading dim (fp32 gemms)
#define LDB 132   // 128-col B-tile LDS leading dim (fp32 gemms)
#define TPAD 544  // 17 * 32; rows 513..543 are zero pads (exp(0)=1 -> subtract 31 from l)
#define NROWS 34816  // 64 * TPAD

typedef __attribute__((ext_vector_type(8))) short bf16x8;   // 8 bf16 = 4 VGPR
typedef __attribute__((ext_vector_type(8))) unsigned short u16x8;
typedef __attribute__((ext_vector_type(4))) float f32x4;    // MFMA acc
typedef __attribute__((ext_vector_type(4))) unsigned short u16x4;

static __device__ inline unsigned short f2bf(float x) {     // RNE fp32->bf16
  unsigned u = __float_as_uint(x);
  return (unsigned short)((u + 0x7fffu + ((u >> 16) & 1u)) >> 16);
}
static __device__ inline float bf2f(unsigned short h) {
  return __uint_as_float(((unsigned)h) << 16);
}

// global -> LDS direct DMA, 16B per lane; ldst wave-uniform (HW adds lane*16),
// gsrc is per-lane (contiguous runs: base + lane*16).
#define GLD16(gsrc, ldst) \
  __builtin_amdgcn_global_load_lds((const __attribute__((address_space(1))) void*)(gsrc), \
                                   (__attribute__((address_space(3))) void*)(ldst), 16, 0, 0)

// ---------------------------------------------------------------------------
// W split+transpose -> CHUNK-MAJOR planes: Wh/Wl[chunk 0..31][512 cols][8 bf16].
// col 0..255 = Wk cols, 256..511 = Wv cols. One block per col.
// ---------------------------------------------------------------------------
__global__ void prep_wt(const float* __restrict__ Wk, const float* __restrict__ Wv,
                        unsigned short* __restrict__ Wh, unsigned short* __restrict__ Wl)
{
  __shared__ unsigned short sh[256], sl[256];
  const int c = blockIdx.x, k = threadIdx.x;
  const float x = (c < 256) ? Wk[k * 256 + c] : Wv[k * 256 + (c - 256)];
  const unsigned short h = f2bf(x);
  sh[k] = h; sl[k] = f2bf(x - bf2f(h));
  __syncthreads();
  if (k < 32)
    *(u16x8*)(Wh + ((size_t)k * 512 + c) * 8) = *(const u16x8*)&sh[k * 8];
  else if (k < 64)
    *(u16x8*)(Wl + ((size_t)(k - 32) * 512 + c) * 8) = *(const u16x8*)&sl[(k - 32) * 8];
}

// ---------------------------------------------------------------------------
// jobs_padded split -> CHUNK-MAJOR planes: Jh/Jl[chunk 0..31][34816 rows][8 bf16].
// Row r = (b, t): t=0 skip, 1..512 jobs, >=513 zero pads. Writes are
// lane-contiguous 1KB runs. grid 544 x 256 (wave w owns chunks w*8..w*8+8).
// ---------------------------------------------------------------------------
__global__ __launch_bounds__(256) void prep_jobs(
    const float* __restrict__ jobs, const float* __restrict__ skip,
    unsigned short* __restrict__ Jh, unsigned short* __restrict__ Jl)
{
  const int w = threadIdx.x >> 6, lane = threadIdx.x & 63;
  const int r = blockIdx.x * 64 + lane;          // 0..34815
  const int bb = r / TPAD, tt = r - bb * TPAD;
  const bool padr = (tt >= 513);
  const float* src = (tt == 0) ? skip : (jobs + ((size_t)(bb * 512 + tt - 1) << 8));
  #pragma unroll
  for (int i = 0; i < 8; ++i) {
    const int cc = w * 8 + i;                    // chunk 0..31
    u16x8 h8 = {}, l8 = {};
    if (!padr) {
      const float4 a = *(const float4*)(src + cc * 8);
      const float4 b = *(const float4*)(src + cc * 8 + 4);
      const float v[8] = {a.x,a.y,a.z,a.w, b.x,b.y,b.z,b.w};
      #pragma unroll
      for (int j = 0; j < 8; ++j) {
        const unsigned short hh = f2bf(v[j]);
        h8[j] = hh;
        l8[j] = f2bf(v[j] - bf2f(hh));
      }
    }
    const size_t o = ((size_t)cc * NROWS + r) * 8;
    *(u16x8*)(Jh + o) = h8;
    *(u16x8*)(Jl + o) = l8;
  }
}

// ---------------------------------------------------------------------------
// KV projection: C(34816 x 512) = vjobs_padded @ [Wk|Wv], pure pre-split bf16.
// 128x128 tile, 4 waves (2x2 of 64x64). T4 counted-vmcnt pipeline (depth 2).
// Staging: 8 contiguous-1KB global_load_lds per wave, conflict-free chunk-major.
// C = Ah*Bh + Ah*Bl + Al*Bh. Outputs: K bf16 hi/lo planes [34816][256];
// V TRANSPOSED bf16 hi/lo planes [b][256 cols][544 t].
// ---------------------------------------------------------------------------
__global__ __launch_bounds__(256) void gemm_kv_mfma(
    const unsigned short* __restrict__ Jh, const unsigned short* __restrict__ Jl,
    const unsigned short* __restrict__ Wh, const unsigned short* __restrict__ Wl,
    unsigned short* __restrict__ Kh, unsigned short* __restrict__ Kl,
    unsigned short* __restrict__ Vth, unsigned short* __restrict__ Vtl)
{
  __shared__ __align__(128) char smem[65536];  // buf: Ah|Al|Bh|Bl 8KB each, x2
  const int tid = threadIdx.x;
  const int lin = blockIdx.x + (blockIdx.y << 2);        // 0..1087
  const int virt = (lin & 7) * 136 + (lin >> 3);         // bijective (1088%8==0)
  const int bx = virt & 3, by = virt >> 2;
  const int w = __builtin_amdgcn_readfirstlane(tid >> 6);
  const int lane = tid & 63;
  const int wr = (w >> 1) << 6, wc = (w & 1) << 6;
  const int fm = lane & 15, fq = lane >> 4;

  // wave w's source plane + per-lane base (row/col block + lane)
  const unsigned short* sp = (w == 0) ? Jh : (w == 1) ? Jl : (w == 2) ? Wh : Wl;
  const size_t rstride = (w < 2) ? (size_t)NROWS : (size_t)512;
  const size_t blk = (w < 2) ? (size_t)(by * 128) : (size_t)(bx * 128);
  const char* srcb = (const char*)sp + (blk + lane) * 16;

  auto STAGE = [&](int ks, int bsel) {
    char* dst = smem + (bsel << 15) + w * 8192;
    #pragma unroll
    for (int j = 0; j < 8; ++j) {
      const int fq_ = j >> 1, half = j & 1;
      GLD16(srcb + (((size_t)(ks * 4 + fq_)) * rstride + half * 64) * 16,
            dst + fq_ * 2048 + half * 1024);
    }
  };

  f32x4 acc[4][4] = {};

  STAGE(0, 0);
  STAGE(1, 1);

  #pragma unroll
  for (int ks = 0; ks < 8; ++ks) {
    // own stage(ks) landed; keep stage(ks+1)'s 8 loads in flight
    if (ks < 7) asm volatile("s_waitcnt vmcnt(8)" ::: "memory");
    else        asm volatile("s_waitcnt vmcnt(0)" ::: "memory");
    __builtin_amdgcn_s_barrier();          // all waves' planes landed
    __builtin_amdgcn_sched_barrier(0);     // pin: no LDS reads hoisted above

    char* cur = smem + ((ks & 1) << 15);
    bf16x8 afh[4], afl[4], bfh[4], bfl[4];
    #pragma unroll
    for (int i = 0; i < 4; ++i) {
      const int ro = fq * 2048 + (wr + i * 16 + fm) * 16;
      const int co = fq * 2048 + (wc + i * 16 + fm) * 16;
      afh[i] = *(const bf16x8*)(cur + ro);
      afl[i] = *(const bf16x8*)(cur + 8192 + ro);
      bfh[i] = *(const bf16x8*)(cur + 16384 + co);
      bfl[i] = *(const bf16x8*)(cur + 24576 + co);
    }
    #pragma unroll
    for (int mi = 0; mi < 4; ++mi)
      #pragma unroll
      for (int ni = 0; ni < 4; ++ni) {
        acc[mi][ni] = __builtin_amdgcn_mfma_f32_16x16x32_bf16(afh[mi], bfl[ni], acc[mi][ni], 0, 0, 0);
        acc[mi][ni] = __builtin_amdgcn_mfma_f32_16x16x32_bf16(afl[mi], bfh[ni], acc[mi][ni], 0, 0, 0);
        acc[mi][ni] = __builtin_amdgcn_mfma_f32_16x16x32_bf16(afh[mi], bfh[ni], acc[mi][ni], 0, 0, 0);
      }

    __builtin_amdgcn_s_barrier();          // all reads of cur done -> reusable
    if (ks + 2 < 8) STAGE(ks + 2, ks & 1); // issue 2-ahead, stays in flight
  }

  // ---- epilogue: RNE hi/lo bf16 planes ----
  const int cb = ((bx & 1) << 7) + wc;
  if (bx < 2) {
    // K planes, row-major [34816][256]
    #pragma unroll
    for (int mi = 0; mi < 4; ++mi) {
      #pragma unroll
      for (int r = 0; r < 4; ++r) {
        const int row = by * 128 + wr + mi * 16 + fq * 4 + r;
        const size_t rb = (size_t)row << 8;
        #pragma unroll
        for (int ni = 0; ni < 4; ++ni) {
          const int cc = cb + ni * 16 + fm;
          const float x = acc[mi][ni][r];
          const unsigned short hh = f2bf(x);
          Kh[rb + cc] = hh;
          Kl[rb + cc] = f2bf(x - bf2f(hh));
        }
      }
    }
  } else {
    // V transposed planes [b][256][544]; 4 consecutive t per frag reg quad
    #pragma unroll
    for (int mi = 0; mi < 4; ++mi) {
      const int row0 = by * 128 + wr + mi * 16 + fq * 4;   // 4-aligned, same b
      const int bb = row0 / TPAD;
      const int tt0 = row0 - bb * TPAD;
      #pragma unroll
      for (int ni = 0; ni < 4; ++ni) {
        const int cc = cb + ni * 16 + fm;
        const size_t vb = ((size_t)(bb * 256 + cc)) * TPAD + tt0;
        u16x4 vh, vl;
        #pragma unroll
        for (int r = 0; r < 4; ++r) {
          const float x = acc[mi][ni][r];
          const unsigned short hh = f2bf(x);
          vh[r] = hh;
          vl[r] = f2bf(x - bf2f(hh));
        }
        *(u16x4*)(Vth + vb) = vh;
        *(u16x4*)(Vtl + vb) = vl;
      }
    }
  }
}

// ---------------------------------------------------------------------------
// Wide tiled fp32 GEMM (Q and Wc projections): C[rows x 256] = A @ W (+bias).
// MODE 0: fp32 output C1. MODE 1: output split bf16 hi/lo CHUNK-MAJOR planes
// Ch/Cl[chunk 0..31][8192 rows][8 bf16] (feeds logits_mfma staging).
// ---------------------------------------------------------------------------
template<int MODE>
__global__ __launch_bounds__(256) void gemm_wide(
    const float* __restrict__ A, const float* __restrict__ W,
    const float* __restrict__ bias, float* __restrict__ C1,
    unsigned short* __restrict__ Ch, unsigned short* __restrict__ Cl)
{
  __shared__ float As[16 * LDT];
  __shared__ float Bs[16 * LDB];
  const int tid = threadIdx.x;
  const int bx = blockIdx.x, by = blockIdx.y;
  const int col0 = bx * 128;

  const int a_row = tid >> 2;
  const int a_k4  = (tid & 3) << 2;
  const float* arow = A + ((size_t)(by * 64 + a_row) << 8);

  const int b_k  = tid >> 4;
  const int b_c8 = (tid & 15) << 3;

  const int tr = tid >> 4, tc = tid & 15;
  float acc[4][8] = {};

  for (int k0 = 0; k0 < 256; k0 += 16) {
    const float4 av  = *(const float4*)(arow + k0 + a_k4);
    const float4 bv0 = *(const float4*)(W + ((size_t)(k0 + b_k) << 8) + col0 + b_c8);
    const float4 bv1 = *(const float4*)(W + ((size_t)(k0 + b_k) << 8) + col0 + b_c8 + 4);
    __syncthreads();
    As[(a_k4 + 0) * LDT + a_row] = av.x;
    As[(a_k4 + 1) * LDT + a_row] = av.y;
    As[(a_k4 + 2) * LDT + a_row] = av.z;
    As[(a_k4 + 3) * LDT + a_row] = av.w;
    *(float4*)&Bs[b_k * LDB + b_c8]     = bv0;
    *(float4*)&Bs[b_k * LDB + b_c8 + 4] = bv1;
    __syncthreads();
    #pragma unroll
    for (int k = 0; k < 16; ++k) {
      const float4 a  = *(const float4*)&As[k * LDT + (tr << 2)];
      const float4 b0 = *(const float4*)&Bs[k * LDB + (tc << 3)];
      const float4 b1 = *(const float4*)&Bs[k * LDB + (tc << 3) + 4];
      const float aa[4] = {a.x, a.y, a.z, a.w};
      #pragma unroll
      for (int i = 0; i < 4; ++i) {
        acc[i][0] = fmaf(aa[i], b0.x, acc[i][0]);
        acc[i][1] = fmaf(aa[i], b0.y, acc[i][1]);
        acc[i][2] = fmaf(aa[i], b0.z, acc[i][2]);
        acc[i][3] = fmaf(aa[i], b0.w, acc[i][3]);
        acc[i][4] = fmaf(aa[i], b1.x, acc[i][4]);
        acc[i][5] = fmaf(aa[i], b1.y, acc[i][5]);
        acc[i][6] = fmaf(aa[i], b1.z, acc[i][6]);
        acc[i][7] = fmaf(aa[i], b1.w, acc[i][7]);
      }
    }
  }

  const int oc = col0 + (tc << 3);
  float4 bsa = make_float4(0.f,0.f,0.f,0.f), bsb = make_float4(0.f,0.f,0.f,0.f);
  if (bias) { bsa = *(const float4*)(bias + oc); bsb = *(const float4*)(bias + oc + 4); }
  const float bb[8] = {bsa.x,bsa.y,bsa.z,bsa.w, bsb.x,bsb.y,bsb.z,bsb.w};
  #pragma unroll
  for (int i = 0; i < 4; ++i) {
    const int row = by * 64 + (tr << 2) + i;
    if (MODE == 0) {
      float* crow = C1 + ((size_t)row << 8) + oc;
      float4 o0, o1;
      o0.x = acc[i][0]+bb[0]; o0.y = acc[i][1]+bb[1]; o0.z = acc[i][2]+bb[2]; o0.w = acc[i][3]+bb[3];
      o1.x = acc[i][4]+bb[4]; o1.y = acc[i][5]+bb[5]; o1.z = acc[i][6]+bb[6]; o1.w = acc[i][7]+bb[7];
      *(float4*)crow = o0; *(float4*)(crow + 4) = o1;
    } else {
      // chunk-major split planes: chunk = oc>>3, 8 cols per chunk
      u16x8 h8, l8;
      #pragma unroll
      for (int j = 0; j < 8; ++j) {
        const float x = acc[i][j] + bb[j];
        const unsigned short hh = f2bf(x);
        h8[j] = hh;
        l8[j] = f2bf(x - bf2f(hh));
      }
      const size_t o = ((size_t)(oc >> 3) * 8192 + row) * 8;
      *(u16x8*)(Ch + o) = h8;
      *(u16x8*)(Cl + o) = l8;
    }
  }
}

// ---------------------------------------------------------------------------
// MFMA attention v8: one block per (h, b), 256 thr = 4 waves (m-half x t-half).
// K/V read as pre-split bf16 planes: each lane loads ONE 16B ushort8 per
// frag (hi plane for lane groups 0,1; lo plane for 2,3). V from transposed
// planes (contiguous t). P split: trunc-hi + RNE-lo via v_perm.
// Pads t=513..543 are zero -> exp=1 exactly: subtract 31 from l.
// ---------------------------------------------------------------------------
__global__ __launch_bounds__(256, 4) void attn_mfma(
    const float* __restrict__ Q,
    const unsigned short* __restrict__ Kh, const unsigned short* __restrict__ Kl,
    const unsigned short* __restrict__ Vth, const unsigned short* __restrict__ Vtl,
    float* __restrict__ OC)
{
  const int h = blockIdx.x, b = blockIdx.y;
  const int tid = threadIdx.x;
  const int lane = tid & 63;
  const int w = __builtin_amdgcn_readfirstlane(tid >> 6);
  const int g = lane >> 4, fm = lane & 15;
  const int mh = (w & 2) << 5;              // 0 or 64
  const int th = w & 1;                     // t-half
  const int send = th ? 17 : 9;             // steps [0,9) | [9,17)
  int s = th ? 9 : 0;

  __shared__ float red[2 * 64 * 21];        // 10.5 KB, stride-21 (conflict-free)

  const int col = h * 16;
  const int dbase = (g & 1) << 3;           // d 0..7 | 8..15 per group parity

  // ---- Q B-frags (persistent, RNE): Bq1 = [Qh|Qh], Bq2 = [Ql|0] ----
  bf16x8 Bq1[4], Bq2[4];
  #pragma unroll
  for (int mt = 0; mt < 4; ++mt) {
    const float* qp = Q + ((size_t)(b * 128 + mh + mt * 16 + fm) << 8) + col + dbase;
    const float4 q0 = *(const float4*)qp;
    const float4 q1 = *(const float4*)(qp + 4);
    const float qv[8] = {q0.x,q0.y,q0.z,q0.w, q1.x,q1.y,q1.z,q1.w};
    #pragma unroll
    for (int j = 0; j < 8; ++j) {
      const float x = qv[j] * 0.25f;        // fold 1/sqrt(QKV)
      const unsigned short hh = f2bf(x);
      Bq1[mt][j] = (short)hh;
      Bq2[mt][j] = (short)((g < 2) ? f2bf(x - bf2f(hh)) : (unsigned short)0);
    }
  }

  f32x4 oT[4] = {};
  float lsum[4] = {0.f, 0.f, 0.f, 0.f};

  // per-lane plane pointers (hoisted)
  const int rA = ((fm & 12) << 1) + (fm & 3);   // permuted K row within step
  const unsigned short* kpl = ((g < 2) ? Kh : Kl)
      + ((((size_t)b * TPAD) + rA) << 8) + col + dbase;
  const unsigned short* vhp = Vth + ((size_t)(b * 256 + col + fm)) * TPAD + (g << 3);
  const unsigned short* vlp = Vtl + ((size_t)(b * 256 + col + fm)) * TPAD + (g << 3);

  for (; s < send; ++s) {
    const int t0 = s << 5;
    const bf16x8 KA = *(const bf16x8*)(kpl + ((size_t)t0 << 8));
    const bf16x8 KB = *(const bf16x8*)(kpl + ((size_t)(t0 + 4) << 8));
    const bf16x8 Vh = *(const bf16x8*)(vhp + t0);
    const bf16x8 Vl = *(const bf16x8*)(vlp + t0);

    #pragma unroll
    for (int mt = 0; mt < 4; ++mt) {
      f32x4 sA = {}, sB = {};
      sA = __builtin_amdgcn_mfma_f32_16x16x32_bf16(KA, Bq1[mt], sA, 0, 0, 0);
      sA = __builtin_amdgcn_mfma_f32_16x16x32_bf16(KA, Bq2[mt], sA, 0, 0, 0);
      sB = __builtin_amdgcn_mfma_f32_16x16x32_bf16(KB, Bq1[mt], sB, 0, 0, 0);
      sB = __builtin_amdgcn_mfma_f32_16x16x32_bf16(KB, Bq2[mt], sB, 0, 0, 0);
      // lane holds P[t0+8g+r][m] (tileA r=0..3) and P[t0+8g+4+r][m] (tileB)
      float p[8];
      p[0] = __expf(sA[0]); p[1] = __expf(sA[1]); p[2] = __expf(sA[2]); p[3] = __expf(sA[3]);
      p[4] = __expf(sB[0]); p[5] = __expf(sB[1]); p[6] = __expf(sB[2]); p[7] = __expf(sB[3]);
      lsum[mt] += ((p[0] + p[1]) + (p[2] + p[3])) + ((p[4] + p[5]) + (p[6] + p[7]));
      bf16x8 Ph, Pl;
      #pragma unroll
      for (int jp = 0; jp < 4; ++jp) {
        const unsigned u0 = __float_as_uint(p[2*jp]);
        const unsigned u1 = __float_as_uint(p[2*jp+1]);
        ((unsigned*)&Ph)[jp] = __builtin_amdgcn_perm(u1, u0, 0x07060302u);
        const float r0 = p[2*jp]   - __uint_as_float(u0 & 0xffff0000u);
        const float r1 = p[2*jp+1] - __uint_as_float(u1 & 0xffff0000u);
        unsigned t0_ = __float_as_uint(r0); t0_ += 0x7fffu + ((t0_ >> 16) & 1u);
        unsigned t1_ = __float_as_uint(r1); t1_ += 0x7fffu + ((t1_ >> 16) & 1u);
        ((unsigned*)&Pl)[jp] = __builtin_amdgcn_perm(t1_, t0_, 0x07060302u);
      }
      oT[mt] = __builtin_amdgcn_mfma_f32_16x16x32_bf16(Vh, Ph, oT[mt], 0, 0, 0);
      oT[mt] = __builtin_amdgcn_mfma_f32_16x16x32_bf16(Vh, Pl, oT[mt], 0, 0, 0);
      oT[mt] = __builtin_amdgcn_mfma_f32_16x16x32_bf16(Vl, Ph, oT[mt], 0, 0, 0);
    }
  }

  // ---- pair reduce (t-half 1 -> t-half 0), then normalize + write ----
  float* slot = red + ((w >> 1) * 1344);
  const int base = lane * 21;
  if (th) {
    #pragma unroll
    for (int mt = 0; mt < 4; ++mt) {
      slot[base + 4 * mt + 0] = oT[mt][0];
      slot[base + 4 * mt + 1] = oT[mt][1];
      slot[base + 4 * mt + 2] = oT[mt][2];
      slot[base + 4 * mt + 3] = oT[mt][3];
      slot[base + 16 + mt]    = lsum[mt];
    }
  }
  __syncthreads();
  if (!th) {
    #pragma unroll
    for (int mt = 0; mt < 4; ++mt) {
      oT[mt][0] += slot[base + 4 * mt + 0];
      oT[mt][1] += slot[base + 4 * mt + 1];
      oT[mt][2] += slot[base + 4 * mt + 2];
      oT[mt][3] += slot[base + 4 * mt + 3];
      float v = lsum[mt] + slot[base + 16 + mt];
      v += __shfl_xor(v, 16);
      v += __shfl_xor(v, 32);
      const float inv = 1.f / (v - 31.f);     // remove 31 pad rows (exp(0)=1)
      float4 o;
      o.x = oT[mt][0] * inv; o.y = oT[mt][1] * inv;
      o.z = oT[mt][2] * inv; o.w = oT[mt][3] * inv;
      // oT reg r = out[m][d = 4g + r]
      *(float4*)(OC + ((size_t)(b * 128 + mh + mt * 16 + fm) << 8) + col + (g << 2)) = o;
    }
  }
}

// ---------------------------------------------------------------------------
// Logits v3: occupancy-first. Tile 128m x 64t, grid 9 t-tiles x 64 b = 576
// blocks; LDS 48KB (2 x 24KB dbuf) -> 3 blocks/CU -> ALL 576 resident
// (2.25/CU), ~9 waves/CU vs v2's ~3. 4 waves = 2x2 (m-half 64, t-half 32),
// acc[4][2]. Staging contiguous-1KB: waves 0/1 = Mh/Ml (8 loads), waves
// 2/3 = Jh/Jl (4 loads); per-wave counted vmcnt. Cheap tanh:
// 10*tanh(y)-10 = -20/(exp(2y)+1) -> e = exp(mask - 20/(e2+1)),
// e2 = exp(acc/8). tx=8 covers t 512..575: t>=513 epilogue-guarded; J-row
// reads clamped to NROWS-1 (lane 0 / t=512 unaffected).
// Deterministic partials[b*9+tx]; sm_inv folded into sm_norm.
// ---------------------------------------------------------------------------
__global__ __launch_bounds__(256) void logits_mfma(
    const unsigned short* __restrict__ Mh, const unsigned short* __restrict__ Ml,
    const unsigned short* __restrict__ Jh, const unsigned short* __restrict__ Jl,
    const float* __restrict__ mask,
    float* __restrict__ out, float* __restrict__ partials)
{
  __shared__ __align__(128) char smem[49152];  // 2 x {Ah 8K|Al 8K|Bh 4K|Bl 4K}
  __shared__ float red[4];
  const int tid = threadIdx.x;
  const int lin = blockIdx.x + blockIdx.y * 9;           // 0..575
  const int virt = (lin & 7) * 72 + (lin >> 3);          // bijective (576%8==0)
  const int tx = virt % 9;                               // t-tile 0..8
  const int b  = virt / 9;
  const int w = __builtin_amdgcn_readfirstlane(tid >> 6);
  const int lane = tid & 63;
  const int wr = (w >> 1) << 6;              // m-half: 0 | 64
  const int wtc = (w & 1) << 5;              // t-half: 0 | 32
  const int fm = lane & 15, fq = lane >> 4;

  const unsigned short* sp = (w == 0) ? Mh : (w == 1) ? Ml : (w == 2) ? Jh : Jl;
  int jrow = b * TPAD + tx * 64 + lane;      // clamp tx=8 tail (guarded cols only)
  if (jrow > NROWS - 1) jrow = NROWS - 1;
  const char* srcb = (w < 2)
      ? (const char*)sp + ((size_t)(b * 128) + lane) * 16
      : (const char*)sp + (size_t)jrow * 16;

  auto STAGE = [&](int ks, int bsel) {
    char* buf = smem + bsel * 24576;
    if (w < 2) {                             // M planes: 128 rows, 8 loads
      char* dst = buf + (w ? 8192 : 0);
      #pragma unroll
      for (int j = 0; j < 8; ++j) {
        const int fq_ = j >> 1, half = j & 1;
        GLD16(srcb + (((size_t)(ks * 4 + fq_)) * 8192 + half * 64) * 16,
              dst + fq_ * 2048 + half * 1024);
      }
    } else {                                 // J planes: 64 rows, 4 loads
      char* dst = buf + 16384 + ((w == 3) ? 4096 : 0);
      #pragma unroll
      for (int j = 0; j < 4; ++j)
        GLD16(srcb + ((size_t)(ks * 4 + j)) * ((size_t)NROWS * 16),
              dst + j * 1024);
    }
  };

  f32x4 acc[4][2] = {};

  STAGE(0, 0);
  STAGE(1, 1);

  #pragma unroll
  for (int ks = 0; ks < 8; ++ks) {
    if (ks < 7) {
      if (w < 2) asm volatile("s_waitcnt vmcnt(8)" ::: "memory");
      else       asm volatile("s_waitcnt vmcnt(4)" ::: "memory");
    } else {
      asm volatile("s_waitcnt vmcnt(0)" ::: "memory");
    }
    __builtin_amdgcn_s_barrier();
    __builtin_amdgcn_sched_barrier(0);

    char* cur = smem + (ks & 1) * 24576;
    bf16x8 afh[4], afl[4], bfh[2], bfl[2];
    #pragma unroll
    for (int i = 0; i < 4; ++i) {
      const int ro = fq * 2048 + (wr + i * 16 + fm) * 16;
      afh[i] = *(const bf16x8*)(cur + ro);
      afl[i] = *(const bf16x8*)(cur + 8192 + ro);
    }
    #pragma unroll
    for (int n = 0; n < 2; ++n) {
      const int co = fq * 1024 + (wtc + n * 16 + fm) * 16;
      bfh[n] = *(const bf16x8*)(cur + 16384 + co);
      bfl[n] = *(const bf16x8*)(cur + 20480 + co);
    }
    #pragma unroll
    for (int mi = 0; mi < 4; ++mi)
      #pragma unroll
      for (int ni = 0; ni < 2; ++ni) {
        acc[mi][ni] = __builtin_amdgcn_mfma_f32_16x16x32_bf16(afh[mi], bfl[ni], acc[mi][ni], 0, 0, 0);
        acc[mi][ni] = __builtin_amdgcn_mfma_f32_16x16x32_bf16(afl[mi], bfh[ni], acc[mi][ni], 0, 0, 0);
        acc[mi][ni] = __builtin_amdgcn_mfma_f32_16x16x32_bf16(afh[mi], bfh[ni], acc[mi][ni], 0, 0, 0);
      }

    __builtin_amdgcn_s_barrier();
    if (ks + 2 < 8) STAGE(ks + 2, ks & 1);
  }

  // epilogue: e = exp(mask - 20/(exp(acc/8)+1)); write; deterministic partial
  float lsum = 0.f;
  #pragma unroll
  for (int mi = 0; mi < 4; ++mi) {
    #pragma unroll
    for (int r = 0; r < 4; ++r) {
      const int m = wr + mi * 16 + fq * 4 + r;
      #pragma unroll
      for (int ni = 0; ni < 2; ++ni) {
        const int t = tx * 64 + wtc + ni * 16 + fm;
        if (t < 513) {
          const float e2 = __expf(acc[mi][ni][r] * 0.125f);
          const float e  = __expf(mask[((size_t)(b * 128 + m)) * 513 + t]
                                  - 20.f / (e2 + 1.f));
          out[(size_t)b * 65664 + (size_t)m * 513 + t] = e;
          lsum += e;
        }
      }
    }
  }
  #pragma unroll
  for (int off = 32; off; off >>= 1) lsum += __shfl_xor(lsum, off);
  if (lane == 0) red[w] = lsum;
  __syncthreads();
  if (tid == 0)
    partials[b * 9 + tx] = (red[0] + red[1]) + (red[2] + red[3]);
}

// Normalize: inv computed inline from 9 deterministic partials (L1-hot).
__global__ __launch_bounds__(256) void sm_norm(float* __restrict__ out,
                                               const float* __restrict__ partials)
{
  const int i4 = blockIdx.x * 256 + threadIdx.x;
  if (i4 < 1050624) {
    const int b = i4 / 16416;
    float s = 0.f;
    #pragma unroll
    for (int i = 0; i < 9; ++i) s += partials[b * 9 + i];
    const float inv = 1.f / s;
    float4 v = ((float4*)out)[i4];
    v.x *= inv; v.y *= inv; v.z *= inv; v.w *= inv;
    ((float4*)out)[i4] = v;
  }
}

// ---------------------------------------------------------------------------
extern "C" void kernel_launch(void* const* d_in, const int* in_sizes, int n_in,
                              void* d_out, int out_size, void* d_ws, size_t ws_size,
                              hipStream_t stream)
{
  const float* machine = (const float*)d_in[0];
  const float* jobs    = (const float*)d_in[1];
  const float* mask    = (const float*)d_in[2];
  const float* Wq      = (const float*)d_in[3];
  const float* Wk      = (const float*)d_in[4];
  const float* Wv      = (const float*)d_in[5];
  const float* Wc      = (const float*)d_in[6];
  const float* bc      = (const float*)d_in[7];
  const float* skip    = (const float*)d_in[8];

  // Workspace (floats). Peak ~26,869,760 f ~ 107.5 MB.
  //   [0,        8912896)  Jh|Jl chunk-major jobs planes (LIVE until logits)
  //   [8912896, 17825792)  Kh|Kl bf16 planes [34816][256] (dead after attn)
  //        overlays after attn: Mh|Ml chunk-major MH planes (2M floats)
  //   [17825792,26738688)  Vth|Vtl transposed planes [64][256][544]
  //   [26738688,26869760)  Wh|Wl chunk-major W planes (dead after kv gemm)
  //        overlays after kv: partials (576 f)
  // d_out (4,202,496 f) used as scratch pre-logits: Qw [0,2M), OC [2M,4M).
  float* ws       = (float*)d_ws;
  unsigned short* JhP = (unsigned short*)ws;
  unsigned short* JlP = JhP + 8912896;
  unsigned short* KhP = (unsigned short*)(ws + 8912896);
  unsigned short* KlP = KhP + 8912896;
  unsigned short* VthP = (unsigned short*)(ws + 17825792);
  unsigned short* VtlP = VthP + 8912896;
  unsigned short* WhP = (unsigned short*)(ws + 26738688);
  unsigned short* WlP = WhP + 131072;
  unsigned short* MhP = (unsigned short*)(ws + 8912896);   // overlays Kh (dead after attn)
  unsigned short* MlP = MhP + 2097152;
  float* partials = ws + 26738688;       // overlays W planes (dead after kv gemm)
  float* out      = (float*)d_out;
  float* Qw       = out;                 // d_out scratch (dead before logits writes)
  float* OC       = out + 2097152;

  // prep: W planes + jobs planes (chunk-major pre-split bf16)
  prep_wt<<<512, 256, 0, stream>>>(Wk, Wv, WhP, WlP);
  prep_jobs<<<544, 256, 0, stream>>>(jobs, skip, JhP, JlP);
  // K|V projection: pure bf16 MFMA, counted-vmcnt pipelined staging
  gemm_kv_mfma<<<dim3(4, 272), 256, 0, stream>>>(
      JhP, JlP, WhP, WlP, KhP, KlP, VthP, VtlP);
  // Q = machine @ Wq3 (fp32) -> d_out scratch
  gemm_wide<0><<<dim3(2, 128), 256, 0, stream>>>(
      machine, Wq, nullptr, Qw, nullptr, nullptr);
  // MFMA attention on pre-split K/V planes -> OC (d_out scratch)
  attn_mfma<<<dim3(16, 64), 256, 0, stream>>>(Qw, KhP, KlP, VthP, VtlP, OC);
  // mh = out_concat @ Wc + bc -> chunk-major split planes (overlay K region)
  gemm_wide<1><<<dim3(2, 128), 256, 0, stream>>>(
      OC, Wc, bc, nullptr, MhP, MlP);
  // logits v3: 576 fully-resident blocks, cheap tanh, fused exp epilogue
  logits_mfma<<<dim3(9, 64), 256, 0, stream>>>(
      MhP, MlP, JhP, JlP, mask, out, partials);
  sm_norm<<<4104, 256, 0, stream>>>(out, partials);
}

// Round 9
// 290.222 us; speedup vs baseline: 1.1493x; 1.0161x over previous
//
#include <hip/hip_runtime.h>
#include <math.h>

// B=64, M=128, J=512, T=513 (padded to TPAD=544), E=256, H=16, D=16; out (64, 65664) fp32.

#define LDT 68    // 64-row A-tile LDS leading dim (fp32 gemms)
#define LDB 132   // 128-col B-tile LDS leading dim (fp32 gemms)
#define TPAD 544  // 17 * 32; rows 513..543 are zero pads (exp(0)=1 -> subtract 31 from l)
#define NROWS 34816  // 64 * TPAD

typedef __attribute__((ext_vector_type(8))) short bf16x8;   // 8 bf16 = 4 VGPR
typedef __attribute__((ext_vector_type(8))) unsigned short u16x8;
typedef __attribute__((ext_vector_type(4))) float f32x4;    // MFMA acc
typedef __attribute__((ext_vector_type(4))) unsigned short u16x4;

static __device__ inline unsigned short f2bf(float x) {     // RNE fp32->bf16
  unsigned u = __float_as_uint(x);
  return (unsigned short)((u + 0x7fffu + ((u >> 16) & 1u)) >> 16);
}
static __device__ inline float bf2f(unsigned short h) {
  return __uint_as_float(((unsigned)h) << 16);
}

// global -> LDS direct DMA, 16B per lane; ldst wave-uniform (HW adds lane*16),
// gsrc is per-lane (contiguous runs: base + lane*16).
#define GLD16(gsrc, ldst) \
  __builtin_amdgcn_global_load_lds((const __attribute__((address_space(1))) void*)(gsrc), \
                                   (__attribute__((address_space(3))) void*)(ldst), 16, 0, 0)

// ---------------------------------------------------------------------------
// W split+transpose -> CHUNK-MAJOR planes: Wh/Wl[chunk 0..31][512 cols][8 bf16].
// col 0..255 = Wk cols, 256..511 = Wv cols. One block per col.
// ---------------------------------------------------------------------------
__global__ void prep_wt(const float* __restrict__ Wk, const float* __restrict__ Wv,
                        unsigned short* __restrict__ Wh, unsigned short* __restrict__ Wl)
{
  __shared__ unsigned short sh[256], sl[256];
  const int c = blockIdx.x, k = threadIdx.x;
  const float x = (c < 256) ? Wk[k * 256 + c] : Wv[k * 256 + (c - 256)];
  const unsigned short h = f2bf(x);
  sh[k] = h; sl[k] = f2bf(x - bf2f(h));
  __syncthreads();
  if (k < 32)
    *(u16x8*)(Wh + ((size_t)k * 512 + c) * 8) = *(const u16x8*)&sh[k * 8];
  else if (k < 64)
    *(u16x8*)(Wl + ((size_t)(k - 32) * 512 + c) * 8) = *(const u16x8*)&sl[(k - 32) * 8];
}

// ---------------------------------------------------------------------------
// jobs_padded split -> CHUNK-MAJOR planes: Jh/Jl[chunk 0..31][34816 rows][8 bf16].
// Row r = (b, t): t=0 skip, 1..512 jobs, >=513 zero pads. Writes are
// lane-contiguous 1KB runs. grid 544 x 256 (wave w owns chunks w*8..w*8+8).
// ---------------------------------------------------------------------------
__global__ __launch_bounds__(256) void prep_jobs(
    const float* __restrict__ jobs, const float* __restrict__ skip,
    unsigned short* __restrict__ Jh, unsigned short* __restrict__ Jl)
{
  const int w = threadIdx.x >> 6, lane = threadIdx.x & 63;
  const int r = blockIdx.x * 64 + lane;          // 0..34815
  const int bb = r / TPAD, tt = r - bb * TPAD;
  const bool padr = (tt >= 513);
  const float* src = (tt == 0) ? skip : (jobs + ((size_t)(bb * 512 + tt - 1) << 8));
  #pragma unroll
  for (int i = 0; i < 8; ++i) {
    const int cc = w * 8 + i;                    // chunk 0..31
    u16x8 h8 = {}, l8 = {};
    if (!padr) {
      const float4 a = *(const float4*)(src + cc * 8);
      const float4 b = *(const float4*)(src + cc * 8 + 4);
      const float v[8] = {a.x,a.y,a.z,a.w, b.x,b.y,b.z,b.w};
      #pragma unroll
      for (int j = 0; j < 8; ++j) {
        const unsigned short hh = f2bf(v[j]);
        h8[j] = hh;
        l8[j] = f2bf(v[j] - bf2f(hh));
      }
    }
    const size_t o = ((size_t)cc * NROWS + r) * 8;
    *(u16x8*)(Jh + o) = h8;
    *(u16x8*)(Jl + o) = l8;
  }
}

// ---------------------------------------------------------------------------
// KV projection v2, occupancy-first: C(34816 x 512) = vjobs_padded @ [Wk|Wv].
// Tile 64m x 128c, grid 4 x 544 = 2176 blocks; LDS 48KB (2 x 24KB dbuf) ->
// 3 blocks/CU resident (vs 128-tile's 2), ~12 waves/CU. 4 waves = 2x2 over
// (32 rows x 64 cols), acc[2][4]. T4 counted-vmcnt pipeline (depth 2):
// waves 0/1 stage Jh/Jl (4 x 1KB loads), waves 2/3 stage Wh/Wl (8 x 1KB);
// per-wave vmcnt(4)/(8). C = Ah*Bh + Ah*Bl + Al*Bh.
// Outputs: K bf16 hi/lo planes [34816][256]; V TRANSPOSED planes [b][256][544].
// ---------------------------------------------------------------------------
__global__ __launch_bounds__(256) void gemm_kv_mfma(
    const unsigned short* __restrict__ Jh, const unsigned short* __restrict__ Jl,
    const unsigned short* __restrict__ Wh, const unsigned short* __restrict__ Wl,
    unsigned short* __restrict__ Kh, unsigned short* __restrict__ Kl,
    unsigned short* __restrict__ Vth, unsigned short* __restrict__ Vtl)
{
  __shared__ __align__(128) char smem[49152];  // 2 x {Ah 4K|Al 4K|Bh 8K|Bl 8K}
  const int tid = threadIdx.x;
  const int lin = blockIdx.x + (blockIdx.y << 2);        // 0..2175
  const int virt = (lin & 7) * 272 + (lin >> 3);         // bijective (2176%8==0)
  const int bx = virt & 3, by = virt >> 2;               // col-tile, row-tile
  const int w = __builtin_amdgcn_readfirstlane(tid >> 6);
  const int lane = tid & 63;
  const int wr = (w >> 1) << 5;              // row-half: 0 | 32
  const int wc = (w & 1) << 6;               // col-half: 0 | 64
  const int fm = lane & 15, fq = lane >> 4;

  // wave w's source plane + per-lane base
  const unsigned short* sp = (w == 0) ? Jh : (w == 1) ? Jl : (w == 2) ? Wh : Wl;
  const char* srcb = (w < 2)
      ? (const char*)sp + ((size_t)(by * 64) + lane) * 16
      : (const char*)sp + ((size_t)(bx * 128) + lane) * 16;

  auto STAGE = [&](int ks, int bsel) {
    char* buf = smem + bsel * 24576;
    if (w < 2) {                             // J planes: 64 rows, 4 loads
      char* dst = buf + (w ? 4096 : 0);
      #pragma unroll
      for (int j = 0; j < 4; ++j)
        GLD16(srcb + ((size_t)(ks * 4 + j)) * ((size_t)NROWS * 16),
              dst + j * 1024);
    } else {                                 // W planes: 128 cols, 8 loads
      char* dst = buf + 8192 + ((w == 3) ? 8192 : 0);
      #pragma unroll
      for (int j = 0; j < 8; ++j) {
        const int fq_ = j >> 1, half = j & 1;
        GLD16(srcb + (((size_t)(ks * 4 + fq_)) * 512 + half * 64) * 16,
              dst + fq_ * 2048 + half * 1024);
      }
    }
  };

  f32x4 acc[2][4] = {};

  STAGE(0, 0);
  STAGE(1, 1);

  #pragma unroll
  for (int ks = 0; ks < 8; ++ks) {
    // own stage(ks) landed; keep stage(ks+1)'s loads in flight
    if (ks < 7) {
      if (w < 2) asm volatile("s_waitcnt vmcnt(4)" ::: "memory");
      else       asm volatile("s_waitcnt vmcnt(8)" ::: "memory");
    } else {
      asm volatile("s_waitcnt vmcnt(0)" ::: "memory");
    }
    __builtin_amdgcn_s_barrier();          // all waves' planes landed
    __builtin_amdgcn_sched_barrier(0);     // pin: no LDS reads hoisted above

    char* cur = smem + (ks & 1) * 24576;
    bf16x8 afh[2], afl[2], bfh[4], bfl[4];
    #pragma unroll
    for (int i = 0; i < 2; ++i) {
      const int ro = fq * 1024 + (wr + i * 16 + fm) * 16;
      afh[i] = *(const bf16x8*)(cur + ro);
      afl[i] = *(const bf16x8*)(cur + 4096 + ro);
    }
    #pragma unroll
    for (int n = 0; n < 4; ++n) {
      const int co = fq * 2048 + (wc + n * 16 + fm) * 16;
      bfh[n] = *(const bf16x8*)(cur + 8192 + co);
      bfl[n] = *(const bf16x8*)(cur + 16384 + co);
    }
    #pragma unroll
    for (int mi = 0; mi < 2; ++mi)
      #pragma unroll
      for (int ni = 0; ni < 4; ++ni) {
        acc[mi][ni] = __builtin_amdgcn_mfma_f32_16x16x32_bf16(afh[mi], bfl[ni], acc[mi][ni], 0, 0, 0);
        acc[mi][ni] = __builtin_amdgcn_mfma_f32_16x16x32_bf16(afl[mi], bfh[ni], acc[mi][ni], 0, 0, 0);
        acc[mi][ni] = __builtin_amdgcn_mfma_f32_16x16x32_bf16(afh[mi], bfh[ni], acc[mi][ni], 0, 0, 0);
      }

    __builtin_amdgcn_s_barrier();          // all reads of cur done -> reusable
    if (ks + 2 < 8) STAGE(ks + 2, ks & 1); // issue 2-ahead, stays in flight
  }

  // ---- epilogue: RNE hi/lo bf16 planes ----
  const int cb = ((bx & 1) << 7) + wc;
  if (bx < 2) {
    // K planes, row-major [34816][256]
    #pragma unroll
    for (int mi = 0; mi < 2; ++mi) {
      #pragma unroll
      for (int r = 0; r < 4; ++r) {
        const int row = by * 64 + wr + mi * 16 + fq * 4 + r;
        const size_t rb = (size_t)row << 8;
        #pragma unroll
        for (int ni = 0; ni < 4; ++ni) {
          const int cc = cb + ni * 16 + fm;
          const float x = acc[mi][ni][r];
          const unsigned short hh = f2bf(x);
          Kh[rb + cc] = hh;
          Kl[rb + cc] = f2bf(x - bf2f(hh));
        }
      }
    }
  } else {
    // V transposed planes [b][256][544]; 4 consecutive t per frag reg quad
    // (quad never spans a b boundary: 544 % 4 == 0)
    #pragma unroll
    for (int mi = 0; mi < 2; ++mi) {
      const int row0 = by * 64 + wr + mi * 16 + fq * 4;   // 4-aligned
      const int bb = row0 / TPAD;
      const int tt0 = row0 - bb * TPAD;
      #pragma unroll
      for (int ni = 0; ni < 4; ++ni) {
        const int cc = cb + ni * 16 + fm;
        const size_t vb = ((size_t)(bb * 256 + cc)) * TPAD + tt0;
        u16x4 vh, vl;
        #pragma unroll
        for (int r = 0; r < 4; ++r) {
          const float x = acc[mi][ni][r];
          const unsigned short hh = f2bf(x);
          vh[r] = hh;
          vl[r] = f2bf(x - bf2f(hh));
        }
        *(u16x4*)(Vth + vb) = vh;
        *(u16x4*)(Vtl + vb) = vl;
      }
    }
  }
}

// ---------------------------------------------------------------------------
// Wide tiled fp32 GEMM (Q and Wc projections): C[rows x 256] = A @ W (+bias).
// MODE 0: fp32 output C1. MODE 1: output split bf16 hi/lo CHUNK-MAJOR planes
// Ch/Cl[chunk 0..31][8192 rows][8 bf16] (feeds logits_mfma staging).
// ---------------------------------------------------------------------------
template<int MODE>
__global__ __launch_bounds__(256) void gemm_wide(
    const float* __restrict__ A, const float* __restrict__ W,
    const float* __restrict__ bias, float* __restrict__ C1,
    unsigned short* __restrict__ Ch, unsigned short* __restrict__ Cl)
{
  __shared__ float As[16 * LDT];
  __shared__ float Bs[16 * LDB];
  const int tid = threadIdx.x;
  const int bx = blockIdx.x, by = blockIdx.y;
  const int col0 = bx * 128;

  const int a_row = tid >> 2;
  const int a_k4  = (tid & 3) << 2;
  const float* arow = A + ((size_t)(by * 64 + a_row) << 8);

  const int b_k  = tid >> 4;
  const int b_c8 = (tid & 15) << 3;

  const int tr = tid >> 4, tc = tid & 15;
  float acc[4][8] = {};

  for (int k0 = 0; k0 < 256; k0 += 16) {
    const float4 av  = *(const float4*)(arow + k0 + a_k4);
    const float4 bv0 = *(const float4*)(W + ((size_t)(k0 + b_k) << 8) + col0 + b_c8);
    const float4 bv1 = *(const float4*)(W + ((size_t)(k0 + b_k) << 8) + col0 + b_c8 + 4);
    __syncthreads();
    As[(a_k4 + 0) * LDT + a_row] = av.x;
    As[(a_k4 + 1) * LDT + a_row] = av.y;
    As[(a_k4 + 2) * LDT + a_row] = av.z;
    As[(a_k4 + 3) * LDT + a_row] = av.w;
    *(float4*)&Bs[b_k * LDB + b_c8]     = bv0;
    *(float4*)&Bs[b_k * LDB + b_c8 + 4] = bv1;
    __syncthreads();
    #pragma unroll
    for (int k = 0; k < 16; ++k) {
      const float4 a  = *(const float4*)&As[k * LDT + (tr << 2)];
      const float4 b0 = *(const float4*)&Bs[k * LDB + (tc << 3)];
      const float4 b1 = *(const float4*)&Bs[k * LDB + (tc << 3) + 4];
      const float aa[4] = {a.x, a.y, a.z, a.w};
      #pragma unroll
      for (int i = 0; i < 4; ++i) {
        acc[i][0] = fmaf(aa[i], b0.x, acc[i][0]);
        acc[i][1] = fmaf(aa[i], b0.y, acc[i][1]);
        acc[i][2] = fmaf(aa[i], b0.z, acc[i][2]);
        acc[i][3] = fmaf(aa[i], b0.w, acc[i][3]);
        acc[i][4] = fmaf(aa[i], b1.x, acc[i][4]);
        acc[i][5] = fmaf(aa[i], b1.y, acc[i][5]);
        acc[i][6] = fmaf(aa[i], b1.z, acc[i][6]);
        acc[i][7] = fmaf(aa[i], b1.w, acc[i][7]);
      }
    }
  }

  const int oc = col0 + (tc << 3);
  float4 bsa = make_float4(0.f,0.f,0.f,0.f), bsb = make_float4(0.f,0.f,0.f,0.f);
  if (bias) { bsa = *(const float4*)(bias + oc); bsb = *(const float4*)(bias + oc + 4); }
  const float bb[8] = {bsa.x,bsa.y,bsa.z,bsa.w, bsb.x,bsb.y,bsb.z,bsb.w};
  #pragma unroll
  for (int i = 0; i < 4; ++i) {
    const int row = by * 64 + (tr << 2) + i;
    if (MODE == 0) {
      float* crow = C1 + ((size_t)row << 8) + oc;
      float4 o0, o1;
      o0.x = acc[i][0]+bb[0]; o0.y = acc[i][1]+bb[1]; o0.z = acc[i][2]+bb[2]; o0.w = acc[i][3]+bb[3];
      o1.x = acc[i][4]+bb[4]; o1.y = acc[i][5]+bb[5]; o1.z = acc[i][6]+bb[6]; o1.w = acc[i][7]+bb[7];
      *(float4*)crow = o0; *(float4*)(crow + 4) = o1;
    } else {
      // chunk-major split planes: chunk = oc>>3, 8 cols per chunk
      u16x8 h8, l8;
      #pragma unroll
      for (int j = 0; j < 8; ++j) {
        const float x = acc[i][j] + bb[j];
        const unsigned short hh = f2bf(x);
        h8[j] = hh;
        l8[j] = f2bf(x - bf2f(hh));
      }
      const size_t o = ((size_t)(oc >> 3) * 8192 + row) * 8;
      *(u16x8*)(Ch + o) = h8;
      *(u16x8*)(Cl + o) = l8;
    }
  }
}

// ---------------------------------------------------------------------------
// MFMA attention v8: one block per (h, b), 256 thr = 4 waves (m-half x t-half).
// K/V read as pre-split bf16 planes: each lane loads ONE 16B ushort8 per
// frag (hi plane for lane groups 0,1; lo plane for 2,3). V from transposed
// planes (contiguous t). P split: trunc-hi + RNE-lo via v_perm.
// Pads t=513..543 are zero -> exp=1 exactly: subtract 31 from l.
// ---------------------------------------------------------------------------
__global__ __launch_bounds__(256, 4) void attn_mfma(
    const float* __restrict__ Q,
    const unsigned short* __restrict__ Kh, const unsigned short* __restrict__ Kl,
    const unsigned short* __restrict__ Vth, const unsigned short* __restrict__ Vtl,
    float* __restrict__ OC)
{
  const int h = blockIdx.x, b = blockIdx.y;
  const int tid = threadIdx.x;
  const int lane = tid & 63;
  const int w = __builtin_amdgcn_readfirstlane(tid >> 6);
  const int g = lane >> 4, fm = lane & 15;
  const int mh = (w & 2) << 5;              // 0 or 64
  const int th = w & 1;                     // t-half
  const int send = th ? 17 : 9;             // steps [0,9) | [9,17)
  int s = th ? 9 : 0;

  __shared__ float red[2 * 64 * 21];        // 10.5 KB, stride-21 (conflict-free)

  const int col = h * 16;
  const int dbase = (g & 1) << 3;           // d 0..7 | 8..15 per group parity

  // ---- Q B-frags (persistent, RNE): Bq1 = [Qh|Qh], Bq2 = [Ql|0] ----
  bf16x8 Bq1[4], Bq2[4];
  #pragma unroll
  for (int mt = 0; mt < 4; ++mt) {
    const float* qp = Q + ((size_t)(b * 128 + mh + mt * 16 + fm) << 8) + col + dbase;
    const float4 q0 = *(const float4*)qp;
    const float4 q1 = *(const float4*)(qp + 4);
    const float qv[8] = {q0.x,q0.y,q0.z,q0.w, q1.x,q1.y,q1.z,q1.w};
    #pragma unroll
    for (int j = 0; j < 8; ++j) {
      const float x = qv[j] * 0.25f;        // fold 1/sqrt(QKV)
      const unsigned short hh = f2bf(x);
      Bq1[mt][j] = (short)hh;
      Bq2[mt][j] = (short)((g < 2) ? f2bf(x - bf2f(hh)) : (unsigned short)0);
    }
  }

  f32x4 oT[4] = {};
  float lsum[4] = {0.f, 0.f, 0.f, 0.f};

  // per-lane plane pointers (hoisted)
  const int rA = ((fm & 12) << 1) + (fm & 3);   // permuted K row within step
  const unsigned short* kpl = ((g < 2) ? Kh : Kl)
      + ((((size_t)b * TPAD) + rA) << 8) + col + dbase;
  const unsigned short* vhp = Vth + ((size_t)(b * 256 + col + fm)) * TPAD + (g << 3);
  const unsigned short* vlp = Vtl + ((size_t)(b * 256 + col + fm)) * TPAD + (g << 3);

  for (; s < send; ++s) {
    const int t0 = s << 5;
    const bf16x8 KA = *(const bf16x8*)(kpl + ((size_t)t0 << 8));
    const bf16x8 KB = *(const bf16x8*)(kpl + ((size_t)(t0 + 4) << 8));
    const bf16x8 Vh = *(const bf16x8*)(vhp + t0);
    const bf16x8 Vl = *(const bf16x8*)(vlp + t0);

    #pragma unroll
    for (int mt = 0; mt < 4; ++mt) {
      f32x4 sA = {}, sB = {};
      sA = __builtin_amdgcn_mfma_f32_16x16x32_bf16(KA, Bq1[mt], sA, 0, 0, 0);
      sA = __builtin_amdgcn_mfma_f32_16x16x32_bf16(KA, Bq2[mt], sA, 0, 0, 0);
      sB = __builtin_amdgcn_mfma_f32_16x16x32_bf16(KB, Bq1[mt], sB, 0, 0, 0);
      sB = __builtin_amdgcn_mfma_f32_16x16x32_bf16(KB, Bq2[mt], sB, 0, 0, 0);
      // lane holds P[t0+8g+r][m] (tileA r=0..3) and P[t0+8g+4+r][m] (tileB)
      float p[8];
      p[0] = __expf(sA[0]); p[1] = __expf(sA[1]); p[2] = __expf(sA[2]); p[3] = __expf(sA[3]);
      p[4] = __expf(sB[0]); p[5] = __expf(sB[1]); p[6] = __expf(sB[2]); p[7] = __expf(sB[3]);
      lsum[mt] += ((p[0] + p[1]) + (p[2] + p[3])) + ((p[4] + p[5]) + (p[6] + p[7]));
      bf16x8 Ph, Pl;
      #pragma unroll
      for (int jp = 0; jp < 4; ++jp) {
        const unsigned u0 = __float_as_uint(p[2*jp]);
        const unsigned u1 = __float_as_uint(p[2*jp+1]);
        ((unsigned*)&Ph)[jp] = __builtin_amdgcn_perm(u1, u0, 0x07060302u);
        const float r0 = p[2*jp]   - __uint_as_float(u0 & 0xffff0000u);
        const float r1 = p[2*jp+1] - __uint_as_float(u1 & 0xffff0000u);
        unsigned t0_ = __float_as_uint(r0); t0_ += 0x7fffu + ((t0_ >> 16) & 1u);
        unsigned t1_ = __float_as_uint(r1); t1_ += 0x7fffu + ((t1_ >> 16) & 1u);
        ((unsigned*)&Pl)[jp] = __builtin_amdgcn_perm(t1_, t0_, 0x07060302u);
      }
      oT[mt] = __builtin_amdgcn_mfma_f32_16x16x32_bf16(Vh, Ph, oT[mt], 0, 0, 0);
      oT[mt] = __builtin_amdgcn_mfma_f32_16x16x32_bf16(Vh, Pl, oT[mt], 0, 0, 0);
      oT[mt] = __builtin_amdgcn_mfma_f32_16x16x32_bf16(Vl, Ph, oT[mt], 0, 0, 0);
    }
  }

  // ---- pair reduce (t-half 1 -> t-half 0), then normalize + write ----
  float* slot = red + ((w >> 1) * 1344);
  const int base = lane * 21;
  if (th) {
    #pragma unroll
    for (int mt = 0; mt < 4; ++mt) {
      slot[base + 4 * mt + 0] = oT[mt][0];
      slot[base + 4 * mt + 1] = oT[mt][1];
      slot[base + 4 * mt + 2] = oT[mt][2];
      slot[base + 4 * mt + 3] = oT[mt][3];
      slot[base + 16 + mt]    = lsum[mt];
    }
  }
  __syncthreads();
  if (!th) {
    #pragma unroll
    for (int mt = 0; mt < 4; ++mt) {
      oT[mt][0] += slot[base + 4 * mt + 0];
      oT[mt][1] += slot[base + 4 * mt + 1];
      oT[mt][2] += slot[base + 4 * mt + 2];
      oT[mt][3] += slot[base + 4 * mt + 3];
      float v = lsum[mt] + slot[base + 16 + mt];
      v += __shfl_xor(v, 16);
      v += __shfl_xor(v, 32);
      const float inv = 1.f / (v - 31.f);     // remove 31 pad rows (exp(0)=1)
      float4 o;
      o.x = oT[mt][0] * inv; o.y = oT[mt][1] * inv;
      o.z = oT[mt][2] * inv; o.w = oT[mt][3] * inv;
      // oT reg r = out[m][d = 4g + r]
      *(float4*)(OC + ((size_t)(b * 128 + mh + mt * 16 + fm) << 8) + col + (g << 2)) = o;
    }
  }
}

// ---------------------------------------------------------------------------
// Logits v3: occupancy-first. Tile 128m x 64t, grid 9 t-tiles x 64 b = 576
// blocks; LDS 48KB (2 x 24KB dbuf) -> 3 blocks/CU. 4 waves = 2x2 (m-half 64,
// t-half 32), acc[4][2]. Staging contiguous-1KB: waves 0/1 = Mh/Ml (8 loads),
// waves 2/3 = Jh/Jl (4 loads); per-wave counted vmcnt. Cheap tanh:
// 10*tanh(y)-10 = -20/(exp(2y)+1) -> e = exp(mask - 20/(e2+1)), e2=exp(acc/8).
// tx=8 covers t 512..575: t>=513 epilogue-guarded; J-row reads clamped.
// Deterministic partials[b*9+tx]; sm_inv folded into sm_norm.
// ---------------------------------------------------------------------------
__global__ __launch_bounds__(256) void logits_mfma(
    const unsigned short* __restrict__ Mh, const unsigned short* __restrict__ Ml,
    const unsigned short* __restrict__ Jh, const unsigned short* __restrict__ Jl,
    const float* __restrict__ mask,
    float* __restrict__ out, float* __restrict__ partials)
{
  __shared__ __align__(128) char smem[49152];  // 2 x {Ah 8K|Al 8K|Bh 4K|Bl 4K}
  __shared__ float red[4];
  const int tid = threadIdx.x;
  const int lin = blockIdx.x + blockIdx.y * 9;           // 0..575
  const int virt = (lin & 7) * 72 + (lin >> 3);          // bijective (576%8==0)
  const int tx = virt % 9;                               // t-tile 0..8
  const int b  = virt / 9;
  const int w = __builtin_amdgcn_readfirstlane(tid >> 6);
  const int lane = tid & 63;
  const int wr = (w >> 1) << 6;              // m-half: 0 | 64
  const int wtc = (w & 1) << 5;              // t-half: 0 | 32
  const int fm = lane & 15, fq = lane >> 4;

  const unsigned short* sp = (w == 0) ? Mh : (w == 1) ? Ml : (w == 2) ? Jh : Jl;
  int jrow = b * TPAD + tx * 64 + lane;      // clamp tx=8 tail (guarded cols only)
  if (jrow > NROWS - 1) jrow = NROWS - 1;
  const char* srcb = (w < 2)
      ? (const char*)sp + ((size_t)(b * 128) + lane) * 16
      : (const char*)sp + (size_t)jrow * 16;

  auto STAGE = [&](int ks, int bsel) {
    char* buf = smem + bsel * 24576;
    if (w < 2) {                             // M planes: 128 rows, 8 loads
      char* dst = buf + (w ? 8192 : 0);
      #pragma unroll
      for (int j = 0; j < 8; ++j) {
        const int fq_ = j >> 1, half = j & 1;
        GLD16(srcb + (((size_t)(ks * 4 + fq_)) * 8192 + half * 64) * 16,
              dst + fq_ * 2048 + half * 1024);
      }
    } else {                                 // J planes: 64 rows, 4 loads
      char* dst = buf + 16384 + ((w == 3) ? 4096 : 0);
      #pragma unroll
      for (int j = 0; j < 4; ++j)
        GLD16(srcb + ((size_t)(ks * 4 + j)) * ((size_t)NROWS * 16),
              dst + j * 1024);
    }
  };

  f32x4 acc[4][2] = {};

  STAGE(0, 0);
  STAGE(1, 1);

  #pragma unroll
  for (int ks = 0; ks < 8; ++ks) {
    if (ks < 7) {
      if (w < 2) asm volatile("s_waitcnt vmcnt(8)" ::: "memory");
      else       asm volatile("s_waitcnt vmcnt(4)" ::: "memory");
    } else {
      asm volatile("s_waitcnt vmcnt(0)" ::: "memory");
    }
    __builtin_amdgcn_s_barrier();
    __builtin_amdgcn_sched_barrier(0);

    char* cur = smem + (ks & 1) * 24576;
    bf16x8 afh[4], afl[4], bfh[2], bfl[2];
    #pragma unroll
    for (int i = 0; i < 4; ++i) {
      const int ro = fq * 2048 + (wr + i * 16 + fm) * 16;
      afh[i] = *(const bf16x8*)(cur + ro);
      afl[i] = *(const bf16x8*)(cur + 8192 + ro);
    }
    #pragma unroll
    for (int n = 0; n < 2; ++n) {
      const int co = fq * 1024 + (wtc + n * 16 + fm) * 16;
      bfh[n] = *(const bf16x8*)(cur + 16384 + co);
      bfl[n] = *(const bf16x8*)(cur + 20480 + co);
    }
    #pragma unroll
    for (int mi = 0; mi < 4; ++mi)
      #pragma unroll
      for (int ni = 0; ni < 2; ++ni) {
        acc[mi][ni] = __builtin_amdgcn_mfma_f32_16x16x32_bf16(afh[mi], bfl[ni], acc[mi][ni], 0, 0, 0);
        acc[mi][ni] = __builtin_amdgcn_mfma_f32_16x16x32_bf16(afl[mi], bfh[ni], acc[mi][ni], 0, 0, 0);
        acc[mi][ni] = __builtin_amdgcn_mfma_f32_16x16x32_bf16(afh[mi], bfh[ni], acc[mi][ni], 0, 0, 0);
      }

    __builtin_amdgcn_s_barrier();
    if (ks + 2 < 8) STAGE(ks + 2, ks & 1);
  }

  // epilogue: e = exp(mask - 20/(exp(acc/8)+1)); write; deterministic partial
  float lsum = 0.f;
  #pragma unroll
  for (int mi = 0; mi < 4; ++mi) {
    #pragma unroll
    for (int r = 0; r < 4; ++r) {
      const int m = wr + mi * 16 + fq * 4 + r;
      #pragma unroll
      for (int ni = 0; ni < 2; ++ni) {
        const int t = tx * 64 + wtc + ni * 16 + fm;
        if (t < 513) {
          const float e2 = __expf(acc[mi][ni][r] * 0.125f);
          const float e  = __expf(mask[((size_t)(b * 128 + m)) * 513 + t]
                                  - 20.f / (e2 + 1.f));
          out[(size_t)b * 65664 + (size_t)m * 513 + t] = e;
          lsum += e;
        }
      }
    }
  }
  #pragma unroll
  for (int off = 32; off; off >>= 1) lsum += __shfl_xor(lsum, off);
  if (lane == 0) red[w] = lsum;
  __syncthreads();
  if (tid == 0)
    partials[b * 9 + tx] = (red[0] + red[1]) + (red[2] + red[3]);
}

// Normalize: inv computed inline from 9 deterministic partials (L1-hot).
__global__ __launch_bounds__(256) void sm_norm(float* __restrict__ out,
                                               const float* __restrict__ partials)
{
  const int i4 = blockIdx.x * 256 + threadIdx.x;
  if (i4 < 1050624) {
    const int b = i4 / 16416;
    float s = 0.f;
    #pragma unroll
    for (int i = 0; i < 9; ++i) s += partials[b * 9 + i];
    const float inv = 1.f / s;
    float4 v = ((float4*)out)[i4];
    v.x *= inv; v.y *= inv; v.z *= inv; v.w *= inv;
    ((float4*)out)[i4] = v;
  }
}

// ---------------------------------------------------------------------------
extern "C" void kernel_launch(void* const* d_in, const int* in_sizes, int n_in,
                              void* d_out, int out_size, void* d_ws, size_t ws_size,
                              hipStream_t stream)
{
  const float* machine = (const float*)d_in[0];
  const float* jobs    = (const float*)d_in[1];
  const float* mask    = (const float*)d_in[2];
  const float* Wq      = (const float*)d_in[3];
  const float* Wk      = (const float*)d_in[4];
  const float* Wv      = (const float*)d_in[5];
  const float* Wc      = (const float*)d_in[6];
  const float* bc      = (const float*)d_in[7];
  const float* skip    = (const float*)d_in[8];

  // Workspace (floats). Peak ~26,869,760 f ~ 107.5 MB.
  //   [0,        8912896)  Jh|Jl chunk-major jobs planes (LIVE until logits)
  //   [8912896, 17825792)  Kh|Kl bf16 planes [34816][256] (dead after attn)
  //        overlays after attn: Mh|Ml chunk-major MH planes (2M floats)
  //   [17825792,26738688)  Vth|Vtl transposed planes [64][256][544]
  //   [26738688,26869760)  Wh|Wl chunk-major W planes (dead after kv gemm)
  //        overlays after kv: partials (576 f)
  // d_out (4,202,496 f) used as scratch pre-logits: Qw [0,2M), OC [2M,4M).
  float* ws       = (float*)d_ws;
  unsigned short* JhP = (unsigned short*)ws;
  unsigned short* JlP = JhP + 8912896;
  unsigned short* KhP = (unsigned short*)(ws + 8912896);
  unsigned short* KlP = KhP + 8912896;
  unsigned short* VthP = (unsigned short*)(ws + 17825792);
  unsigned short* VtlP = VthP + 8912896;
  unsigned short* WhP = (unsigned short*)(ws + 26738688);
  unsigned short* WlP = WhP + 131072;
  unsigned short* MhP = (unsigned short*)(ws + 8912896);   // overlays Kh (dead after attn)
  unsigned short* MlP = MhP + 2097152;
  float* partials = ws + 26738688;       // overlays W planes (dead after kv gemm)
  float* out      = (float*)d_out;
  float* Qw       = out;                 // d_out scratch (dead before logits writes)
  float* OC       = out + 2097152;

  // prep: W planes + jobs planes (chunk-major pre-split bf16)
  prep_wt<<<512, 256, 0, stream>>>(Wk, Wv, WhP, WlP);
  prep_jobs<<<544, 256, 0, stream>>>(jobs, skip, JhP, JlP);
  // K|V projection v2: 64x128 tiles, 3 blocks/CU, counted-vmcnt staging
  gemm_kv_mfma<<<dim3(4, 544), 256, 0, stream>>>(
      JhP, JlP, WhP, WlP, KhP, KlP, VthP, VtlP);
  // Q = machine @ Wq3 (fp32) -> d_out scratch
  gemm_wide<0><<<dim3(2, 128), 256, 0, stream>>>(
      machine, Wq, nullptr, Qw, nullptr, nullptr);
  // MFMA attention on pre-split K/V planes -> OC (d_out scratch)
  attn_mfma<<<dim3(16, 64), 256, 0, stream>>>(Qw, KhP, KlP, VthP, VtlP, OC);
  // mh = out_concat @ Wc + bc -> chunk-major split planes (overlay K region)
  gemm_wide<1><<<dim3(2, 128), 256, 0, stream>>>(
      OC, Wc, bc, nullptr, MhP, MlP);
  // logits v3: 576 fully-resident blocks, cheap tanh, fused exp epilogue
  logits_mfma<<<dim3(9, 64), 256, 0, stream>>>(
      MhP, MlP, JhP, JlP, mask, out, partials);
  sm_norm<<<4104, 256, 0, stream>>>(out, partials);
}

// Round 10
// 242.879 us; speedup vs baseline: 1.3733x; 1.1949x over previous
//
#include <hip/hip_runtime.h>
#include <math.h>

// B=64, M=128, J=512, T=513 (padded to TPAD=544), E=256, H=16, D=16; out (64, 65664) fp32.

#define TPAD 544  // 17 * 32; rows 513..543 are zero pads (exp(0)=1 -> subtract 31 from l)
#define NROWS 34816  // 64 * TPAD

typedef __attribute__((ext_vector_type(8))) short bf16x8;   // 8 bf16 = 4 VGPR
typedef __attribute__((ext_vector_type(8))) unsigned short u16x8;
typedef __attribute__((ext_vector_type(4))) float f32x4;    // MFMA acc
typedef __attribute__((ext_vector_type(4))) unsigned short u16x4;

static __device__ inline unsigned short f2bf(float x) {     // RNE fp32->bf16
  unsigned u = __float_as_uint(x);
  return (unsigned short)((u + 0x7fffu + ((u >> 16) & 1u)) >> 16);
}
static __device__ inline float bf2f(unsigned short h) {
  return __uint_as_float(((unsigned)h) << 16);
}

// global -> LDS direct DMA, 16B per lane; ldst wave-uniform (HW adds lane*16),
// gsrc is per-lane (contiguous runs: base + lane*16).
#define GLD16(gsrc, ldst) \
  __builtin_amdgcn_global_load_lds((const __attribute__((address_space(1))) void*)(gsrc), \
                                   (__attribute__((address_space(3))) void*)(ldst), 16, 0, 0)

// ---------------------------------------------------------------------------
// ALL-W split+transpose -> CHUNK-MAJOR planes Wh/Wl[chunk 0..31][1024 cols][8]:
// cols 0..255 = Wq, 256..511 = Wk, 512..767 = Wv, 768..1023 = Wc.
// One block per col (grid 1024).
// ---------------------------------------------------------------------------
__global__ void prep_wt(const float* __restrict__ Wq, const float* __restrict__ Wk,
                        const float* __restrict__ Wv, const float* __restrict__ Wc,
                        unsigned short* __restrict__ Wh, unsigned short* __restrict__ Wl)
{
  __shared__ unsigned short sh[256], sl[256];
  const int c = blockIdx.x, k = threadIdx.x;     // c 0..1023
  const float* Ws = (c < 256) ? Wq : (c < 512) ? Wk : (c < 768) ? Wv : Wc;
  const float x = Ws[k * 256 + (c & 255)];
  const unsigned short h = f2bf(x);
  sh[k] = h; sl[k] = f2bf(x - bf2f(h));
  __syncthreads();
  if (k < 32)
    *(u16x8*)(Wh + ((size_t)k * 1024 + c) * 8) = *(const u16x8*)&sh[k * 8];
  else if (k < 64)
    *(u16x8*)(Wl + ((size_t)(k - 32) * 1024 + c) * 8) = *(const u16x8*)&sl[(k - 32) * 8];
}

// ---------------------------------------------------------------------------
// jobs_padded split -> CHUNK-MAJOR planes: Jh/Jl[chunk 0..31][34816 rows][8 bf16].
// Row r = (b, t): t=0 skip, 1..512 jobs, >=513 zero pads. Writes are
// lane-contiguous 1KB runs. grid 544 x 256 (wave w owns chunks w*8..w*8+8).
// ---------------------------------------------------------------------------
__global__ __launch_bounds__(256) void prep_jobs(
    const float* __restrict__ jobs, const float* __restrict__ skip,
    unsigned short* __restrict__ Jh, unsigned short* __restrict__ Jl)
{
  const int w = threadIdx.x >> 6, lane = threadIdx.x & 63;
  const int r = blockIdx.x * 64 + lane;          // 0..34815
  const int bb = r / TPAD, tt = r - bb * TPAD;
  const bool padr = (tt >= 513);
  const float* src = (tt == 0) ? skip : (jobs + ((size_t)(bb * 512 + tt - 1) << 8));
  #pragma unroll
  for (int i = 0; i < 8; ++i) {
    const int cc = w * 8 + i;                    // chunk 0..31
    u16x8 h8 = {}, l8 = {};
    if (!padr) {
      const float4 a = *(const float4*)(src + cc * 8);
      const float4 b = *(const float4*)(src + cc * 8 + 4);
      const float v[8] = {a.x,a.y,a.z,a.w, b.x,b.y,b.z,b.w};
      #pragma unroll
      for (int j = 0; j < 8; ++j) {
        const unsigned short hh = f2bf(v[j]);
        h8[j] = hh;
        l8[j] = f2bf(v[j] - bf2f(hh));
      }
    }
    const size_t o = ((size_t)cc * NROWS + r) * 8;
    *(u16x8*)(Jh + o) = h8;
    *(u16x8*)(Jl + o) = l8;
  }
}

// ---------------------------------------------------------------------------
// machine split -> CHUNK-MAJOR planes Mh/Ml[chunk 0..31][8192 rows][8 bf16].
// grid 128 x 256 (wave w owns chunks w*8..w*8+8). Dense, no pad logic.
// ---------------------------------------------------------------------------
__global__ __launch_bounds__(256) void prep_mach(
    const float* __restrict__ A,
    unsigned short* __restrict__ Mh, unsigned short* __restrict__ Ml)
{
  const int w = threadIdx.x >> 6, lane = threadIdx.x & 63;
  const int r = blockIdx.x * 64 + lane;          // 0..8191
  const float* src = A + ((size_t)r << 8);
  #pragma unroll
  for (int i = 0; i < 8; ++i) {
    const int cc = w * 8 + i;
    const float4 a = *(const float4*)(src + cc * 8);
    const float4 b = *(const float4*)(src + cc * 8 + 4);
    const float v[8] = {a.x,a.y,a.z,a.w, b.x,b.y,b.z,b.w};
    u16x8 h8, l8;
    #pragma unroll
    for (int j = 0; j < 8; ++j) {
      const unsigned short hh = f2bf(v[j]);
      h8[j] = hh;
      l8[j] = f2bf(v[j] - bf2f(hh));
    }
    const size_t o = ((size_t)cc * 8192 + r) * 8;
    *(u16x8*)(Mh + o) = h8;
    *(u16x8*)(Ml + o) = l8;
  }
}

// ---------------------------------------------------------------------------
// KV projection v2 (as R8): tile 64m x 128c, grid 4 x 544 = 2176 blocks;
// LDS 48KB dbuf -> 3 blocks/CU. Waves 0/1 stage Jh/Jl (4 x 1KB), waves 2/3
// stage W planes cols 256..767 (8 x 1KB, stride 1024). Counted-vmcnt depth 2.
// C = Ah*Bh + Ah*Bl + Al*Bh. Outputs: K planes [34816][256]; V transposed
// planes [b][256][544].
// ---------------------------------------------------------------------------
__global__ __launch_bounds__(256) void gemm_kv_mfma(
    const unsigned short* __restrict__ Jh, const unsigned short* __restrict__ Jl,
    const unsigned short* __restrict__ Wh, const unsigned short* __restrict__ Wl,
    unsigned short* __restrict__ Kh, unsigned short* __restrict__ Kl,
    unsigned short* __restrict__ Vth, unsigned short* __restrict__ Vtl)
{
  __shared__ __align__(128) char smem[49152];  // 2 x {Ah 4K|Al 4K|Bh 8K|Bl 8K}
  const int tid = threadIdx.x;
  const int lin = blockIdx.x + (blockIdx.y << 2);        // 0..2175
  const int virt = (lin & 7) * 272 + (lin >> 3);         // bijective (2176%8==0)
  const int bx = virt & 3, by = virt >> 2;               // col-tile, row-tile
  const int w = __builtin_amdgcn_readfirstlane(tid >> 6);
  const int lane = tid & 63;
  const int wr = (w >> 1) << 5;              // row-half: 0 | 32
  const int wc = (w & 1) << 6;               // col-half: 0 | 64
  const int fm = lane & 15, fq = lane >> 4;

  const unsigned short* sp = (w == 0) ? Jh : (w == 1) ? Jl : (w == 2) ? Wh : Wl;
  const char* srcb = (w < 2)
      ? (const char*)sp + ((size_t)(by * 64) + lane) * 16
      : (const char*)sp + ((size_t)(256 + bx * 128) + lane) * 16;  // Wk|Wv window

  auto STAGE = [&](int ks, int bsel) {
    char* buf = smem + bsel * 24576;
    if (w < 2) {                             // J planes: 64 rows, 4 loads
      char* dst = buf + (w ? 4096 : 0);
      #pragma unroll
      for (int j = 0; j < 4; ++j)
        GLD16(srcb + ((size_t)(ks * 4 + j)) * ((size_t)NROWS * 16),
              dst + j * 1024);
    } else {                                 // W planes: 128 cols, 8 loads
      char* dst = buf + 8192 + ((w == 3) ? 8192 : 0);
      #pragma unroll
      for (int j = 0; j < 8; ++j) {
        const int fq_ = j >> 1, half = j & 1;
        GLD16(srcb + (((size_t)(ks * 4 + fq_)) * 1024 + half * 64) * 16,
              dst + fq_ * 2048 + half * 1024);
      }
    }
  };

  f32x4 acc[2][4] = {};

  STAGE(0, 0);
  STAGE(1, 1);

  #pragma unroll
  for (int ks = 0; ks < 8; ++ks) {
    if (ks < 7) {
      if (w < 2) asm volatile("s_waitcnt vmcnt(4)" ::: "memory");
      else       asm volatile("s_waitcnt vmcnt(8)" ::: "memory");
    } else {
      asm volatile("s_waitcnt vmcnt(0)" ::: "memory");
    }
    __builtin_amdgcn_s_barrier();
    __builtin_amdgcn_sched_barrier(0);

    char* cur = smem + (ks & 1) * 24576;
    bf16x8 afh[2], afl[2], bfh[4], bfl[4];
    #pragma unroll
    for (int i = 0; i < 2; ++i) {
      const int ro = fq * 1024 + (wr + i * 16 + fm) * 16;
      afh[i] = *(const bf16x8*)(cur + ro);
      afl[i] = *(const bf16x8*)(cur + 4096 + ro);
    }
    #pragma unroll
    for (int n = 0; n < 4; ++n) {
      const int co = fq * 2048 + (wc + n * 16 + fm) * 16;
      bfh[n] = *(const bf16x8*)(cur + 8192 + co);
      bfl[n] = *(const bf16x8*)(cur + 16384 + co);
    }
    #pragma unroll
    for (int mi = 0; mi < 2; ++mi)
      #pragma unroll
      for (int ni = 0; ni < 4; ++ni) {
        acc[mi][ni] = __builtin_amdgcn_mfma_f32_16x16x32_bf16(afh[mi], bfl[ni], acc[mi][ni], 0, 0, 0);
        acc[mi][ni] = __builtin_amdgcn_mfma_f32_16x16x32_bf16(afl[mi], bfh[ni], acc[mi][ni], 0, 0, 0);
        acc[mi][ni] = __builtin_amdgcn_mfma_f32_16x16x32_bf16(afh[mi], bfh[ni], acc[mi][ni], 0, 0, 0);
      }

    __builtin_amdgcn_s_barrier();
    if (ks + 2 < 8) STAGE(ks + 2, ks & 1);
  }

  // ---- epilogue: RNE hi/lo bf16 planes ----
  const int cb = ((bx & 1) << 7) + wc;
  if (bx < 2) {
    #pragma unroll
    for (int mi = 0; mi < 2; ++mi) {
      #pragma unroll
      for (int r = 0; r < 4; ++r) {
        const int row = by * 64 + wr + mi * 16 + fq * 4 + r;
        const size_t rb = (size_t)row << 8;
        #pragma unroll
        for (int ni = 0; ni < 4; ++ni) {
          const int cc = cb + ni * 16 + fm;
          const float x = acc[mi][ni][r];
          const unsigned short hh = f2bf(x);
          Kh[rb + cc] = hh;
          Kl[rb + cc] = f2bf(x - bf2f(hh));
        }
      }
    }
  } else {
    #pragma unroll
    for (int mi = 0; mi < 2; ++mi) {
      const int row0 = by * 64 + wr + mi * 16 + fq * 4;   // 4-aligned
      const int bb = row0 / TPAD;
      const int tt0 = row0 - bb * TPAD;
      #pragma unroll
      for (int ni = 0; ni < 4; ++ni) {
        const int cc = cb + ni * 16 + fm;
        const size_t vb = ((size_t)(bb * 256 + cc)) * TPAD + tt0;
        u16x4 vh, vl;
        #pragma unroll
        for (int r = 0; r < 4; ++r) {
          const float x = acc[mi][ni][r];
          const unsigned short hh = f2bf(x);
          vh[r] = hh;
          vl[r] = f2bf(x - bf2f(hh));
        }
        *(u16x4*)(Vth + vb) = vh;
        *(u16x4*)(Vtl + vb) = vl;
      }
    }
  }
}

// ---------------------------------------------------------------------------
// proj_mfma: C(8192 x 256) = A(8192 x 256) @ W[:, cbase..cbase+256) (+bias)*scale,
// all operands pre-split chunk-major planes; output split planes [chunk][8192][8].
// Tile 64m x 64c, grid 4 x 128 = 512 blocks; LDS 32KB (2 x 16KB dbuf) ->
// 2 blocks/CU from grid, ~8 waves/CU. 4 waves = 2x2 (32 rows x 32 cols),
// acc[2][2]. Each wave stages its plane: 4 contiguous-1KB loads; vmcnt(4).
// Used for Q = machine@Wq (scale=0.25, fold 1/sqrt(QKV)) and MH = OC@Wc + bc.
// ---------------------------------------------------------------------------
__global__ __launch_bounds__(256) void proj_mfma(
    const unsigned short* __restrict__ Ah_, const unsigned short* __restrict__ Al_,
    const unsigned short* __restrict__ Wh_, const unsigned short* __restrict__ Wl_,
    const int cbase, const float scale, const float* __restrict__ bias,
    unsigned short* __restrict__ Ch, unsigned short* __restrict__ Cl)
{
  __shared__ __align__(128) char smem[32768];  // 2 x {Ah 4K|Al 4K|Bh 4K|Bl 4K}
  const int tid = threadIdx.x;
  const int lin = blockIdx.x + (blockIdx.y << 2);        // 0..511
  const int virt = (lin & 7) * 64 + (lin >> 3);          // bijective (512%8==0)
  const int bx = virt & 3, by = virt >> 2;               // col-tile(64), row-tile(64)
  const int w = __builtin_amdgcn_readfirstlane(tid >> 6);
  const int lane = tid & 63;
  const int wr = (w >> 1) << 5, wc = (w & 1) << 5;
  const int fm = lane & 15, fq = lane >> 4;

  const unsigned short* sp = (w == 0) ? Ah_ : (w == 1) ? Al_ : (w == 2) ? Wh_ : Wl_;
  const size_t rstride = (w < 2) ? (size_t)8192 : (size_t)1024;
  const size_t base = (w < 2) ? (size_t)(by * 64) : (size_t)(cbase + bx * 64);
  const char* srcb = (const char*)sp + (base + lane) * 16;

  auto STAGE = [&](int ks, int bsel) {
    char* dst = smem + bsel * 16384 + w * 4096;
    #pragma unroll
    for (int j = 0; j < 4; ++j)
      GLD16(srcb + ((size_t)(ks * 4 + j)) * rstride * 16, dst + j * 1024);
  };

  f32x4 acc[2][2] = {};

  STAGE(0, 0);
  STAGE(1, 1);

  #pragma unroll
  for (int ks = 0; ks < 8; ++ks) {
    if (ks < 7) asm volatile("s_waitcnt vmcnt(4)" ::: "memory");
    else        asm volatile("s_waitcnt vmcnt(0)" ::: "memory");
    __builtin_amdgcn_s_barrier();
    __builtin_amdgcn_sched_barrier(0);

    char* cur = smem + (ks & 1) * 16384;
    bf16x8 afh[2], afl[2], bfh[2], bfl[2];
    #pragma unroll
    for (int i = 0; i < 2; ++i) {
      const int ro = fq * 1024 + (wr + i * 16 + fm) * 16;
      const int co = fq * 1024 + (wc + i * 16 + fm) * 16;
      afh[i] = *(const bf16x8*)(cur + ro);
      afl[i] = *(const bf16x8*)(cur + 4096 + ro);
      bfh[i] = *(const bf16x8*)(cur + 8192 + co);
      bfl[i] = *(const bf16x8*)(cur + 12288 + co);
    }
    #pragma unroll
    for (int mi = 0; mi < 2; ++mi)
      #pragma unroll
      for (int ni = 0; ni < 2; ++ni) {
        acc[mi][ni] = __builtin_amdgcn_mfma_f32_16x16x32_bf16(afh[mi], bfl[ni], acc[mi][ni], 0, 0, 0);
        acc[mi][ni] = __builtin_amdgcn_mfma_f32_16x16x32_bf16(afl[mi], bfh[ni], acc[mi][ni], 0, 0, 0);
        acc[mi][ni] = __builtin_amdgcn_mfma_f32_16x16x32_bf16(afh[mi], bfh[ni], acc[mi][ni], 0, 0, 0);
      }

    __builtin_amdgcn_s_barrier();
    if (ks + 2 < 8) STAGE(ks + 2, ks & 1);
  }

  // epilogue: x = acc*scale (+bias); split RNE hi/lo into chunk-major planes
  const int colb = bx * 64 + wc;
  #pragma unroll
  for (int mi = 0; mi < 2; ++mi) {
    #pragma unroll
    for (int r = 0; r < 4; ++r) {
      const int row = by * 64 + wr + mi * 16 + fq * 4 + r;
      #pragma unroll
      for (int ni = 0; ni < 2; ++ni) {
        const int oc = colb + ni * 16 + fm;
        float x = acc[mi][ni][r] * scale;
        if (bias) x += bias[oc];
        const unsigned short hh = f2bf(x);
        const size_t o = ((size_t)(oc >> 3) * 8192 + row) * 8 + (oc & 7);
        Ch[o] = hh;
        Cl[o] = f2bf(x - bf2f(hh));
      }
    }
  }
}

// ---------------------------------------------------------------------------
// MFMA attention v9: one block per (h, b), 4 waves (m-half x t-half).
// Q now read as pre-split planes (scale 0.25 folded by proj_mfma) -> one
// u16x8 load per frag, zero convert VALU. K/V as pre-split planes (hi for
// lane groups 0,1; lo for 2,3); V transposed (contiguous t). Output written
// as split OC planes [chunk][8192][8] feeding proj_mfma directly.
// Pads t=513..543 are zero -> exp=1 exactly: subtract 31 from l.
// ---------------------------------------------------------------------------
__global__ __launch_bounds__(256, 4) void attn_mfma(
    const unsigned short* __restrict__ Qh, const unsigned short* __restrict__ Ql,
    const unsigned short* __restrict__ Kh, const unsigned short* __restrict__ Kl,
    const unsigned short* __restrict__ Vth, const unsigned short* __restrict__ Vtl,
    unsigned short* __restrict__ Och, unsigned short* __restrict__ Ocl)
{
  const int h = blockIdx.x, b = blockIdx.y;
  const int tid = threadIdx.x;
  const int lane = tid & 63;
  const int w = __builtin_amdgcn_readfirstlane(tid >> 6);
  const int g = lane >> 4, fm = lane & 15;
  const int mh = (w & 2) << 5;              // 0 or 64
  const int th = w & 1;                     // t-half
  const int send = th ? 17 : 9;             // steps [0,9) | [9,17)
  int s = th ? 9 : 0;

  __shared__ float red[2 * 64 * 21];        // 10.5 KB, stride-21 (conflict-free)

  const int col = h * 16;

  // ---- Q B-frags from pre-split planes: Bq1 = hi, Bq2 = lo (g<2) | 0 ----
  bf16x8 Bq1[4], Bq2[4];
  const bf16x8 zf = {};
  #pragma unroll
  for (int mt = 0; mt < 4; ++mt) {
    const size_t qo = ((size_t)(h * 2 + (g & 1)) * 8192
                      + (b * 128 + mh + mt * 16 + fm)) * 8;
    Bq1[mt] = *(const bf16x8*)(Qh + qo);
    Bq2[mt] = (g < 2) ? *(const bf16x8*)(Ql + qo) : zf;
  }

  f32x4 oT[4] = {};
  float lsum[4] = {0.f, 0.f, 0.f, 0.f};

  const int rA = ((fm & 12) << 1) + (fm & 3);   // permuted K row within step
  const int dbase = (g & 1) << 3;
  const unsigned short* kpl = ((g < 2) ? Kh : Kl)
      + ((((size_t)b * TPAD) + rA) << 8) + col + dbase;
  const unsigned short* vhp = Vth + ((size_t)(b * 256 + col + fm)) * TPAD + (g << 3);
  const unsigned short* vlp = Vtl + ((size_t)(b * 256 + col + fm)) * TPAD + (g << 3);

  for (; s < send; ++s) {
    const int t0 = s << 5;
    const bf16x8 KA = *(const bf16x8*)(kpl + ((size_t)t0 << 8));
    const bf16x8 KB = *(const bf16x8*)(kpl + ((size_t)(t0 + 4) << 8));
    const bf16x8 Vh = *(const bf16x8*)(vhp + t0);
    const bf16x8 Vl = *(const bf16x8*)(vlp + t0);

    #pragma unroll
    for (int mt = 0; mt < 4; ++mt) {
      f32x4 sA = {}, sB = {};
      sA = __builtin_amdgcn_mfma_f32_16x16x32_bf16(KA, Bq1[mt], sA, 0, 0, 0);
      sA = __builtin_amdgcn_mfma_f32_16x16x32_bf16(KA, Bq2[mt], sA, 0, 0, 0);
      sB = __builtin_amdgcn_mfma_f32_16x16x32_bf16(KB, Bq1[mt], sB, 0, 0, 0);
      sB = __builtin_amdgcn_mfma_f32_16x16x32_bf16(KB, Bq2[mt], sB, 0, 0, 0);
      float p[8];
      p[0] = __expf(sA[0]); p[1] = __expf(sA[1]); p[2] = __expf(sA[2]); p[3] = __expf(sA[3]);
      p[4] = __expf(sB[0]); p[5] = __expf(sB[1]); p[6] = __expf(sB[2]); p[7] = __expf(sB[3]);
      lsum[mt] += ((p[0] + p[1]) + (p[2] + p[3])) + ((p[4] + p[5]) + (p[6] + p[7]));
      bf16x8 Ph, Pl;
      #pragma unroll
      for (int jp = 0; jp < 4; ++jp) {
        const unsigned u0 = __float_as_uint(p[2*jp]);
        const unsigned u1 = __float_as_uint(p[2*jp+1]);
        ((unsigned*)&Ph)[jp] = __builtin_amdgcn_perm(u1, u0, 0x07060302u);
        const float r0 = p[2*jp]   - __uint_as_float(u0 & 0xffff0000u);
        const float r1 = p[2*jp+1] - __uint_as_float(u1 & 0xffff0000u);
        unsigned t0_ = __float_as_uint(r0); t0_ += 0x7fffu + ((t0_ >> 16) & 1u);
        unsigned t1_ = __float_as_uint(r1); t1_ += 0x7fffu + ((t1_ >> 16) & 1u);
        ((unsigned*)&Pl)[jp] = __builtin_amdgcn_perm(t1_, t0_, 0x07060302u);
      }
      oT[mt] = __builtin_amdgcn_mfma_f32_16x16x32_bf16(Vh, Ph, oT[mt], 0, 0, 0);
      oT[mt] = __builtin_amdgcn_mfma_f32_16x16x32_bf16(Vh, Pl, oT[mt], 0, 0, 0);
      oT[mt] = __builtin_amdgcn_mfma_f32_16x16x32_bf16(Vl, Ph, oT[mt], 0, 0, 0);
    }
  }

  // ---- pair reduce (t-half 1 -> t-half 0), then normalize + write planes ----
  float* slot = red + ((w >> 1) * 1344);
  const int base = lane * 21;
  if (th) {
    #pragma unroll
    for (int mt = 0; mt < 4; ++mt) {
      slot[base + 4 * mt + 0] = oT[mt][0];
      slot[base + 4 * mt + 1] = oT[mt][1];
      slot[base + 4 * mt + 2] = oT[mt][2];
      slot[base + 4 * mt + 3] = oT[mt][3];
      slot[base + 16 + mt]    = lsum[mt];
    }
  }
  __syncthreads();
  if (!th) {
    #pragma unroll
    for (int mt = 0; mt < 4; ++mt) {
      oT[mt][0] += slot[base + 4 * mt + 0];
      oT[mt][1] += slot[base + 4 * mt + 1];
      oT[mt][2] += slot[base + 4 * mt + 2];
      oT[mt][3] += slot[base + 4 * mt + 3];
      float v = lsum[mt] + slot[base + 16 + mt];
      v += __shfl_xor(v, 16);
      v += __shfl_xor(v, 32);
      const float inv = 1.f / (v - 31.f);     // remove 31 pad rows (exp(0)=1)
      // oT reg r = out[m][d = 4g + r] -> chunk h*2+(g>>1), slot (g&1)*4 + r
      const int row = b * 128 + mh + mt * 16 + fm;
      const size_t oo = ((size_t)(h * 2 + (g >> 1)) * 8192 + row) * 8 + ((g & 1) << 2);
      u16x4 oh, ol;
      #pragma unroll
      for (int r = 0; r < 4; ++r) {
        const float x = oT[mt][r] * inv;
        const unsigned short hh = f2bf(x);
        oh[r] = hh;
        ol[r] = f2bf(x - bf2f(hh));
      }
      *(u16x4*)(Och + oo) = oh;
      *(u16x4*)(Ocl + oo) = ol;
    }
  }
}

// ---------------------------------------------------------------------------
// Logits v3 (as R7): tile 128m x 64t, grid 9 x 64 = 576 blocks; 48KB dbuf ->
// 3 blocks/CU. Waves 0/1 stage Mh/Ml (8 loads), 2/3 Jh/Jl (4 loads); counted
// vmcnt. Cheap tanh: e = exp(mask - 20/(exp(acc/8)+1)). tx=8 tail guarded +
// J-row clamped. Deterministic partials[b*9+tx]; sm_inv folded into sm_norm.
// ---------------------------------------------------------------------------
__global__ __launch_bounds__(256) void logits_mfma(
    const unsigned short* __restrict__ Mh, const unsigned short* __restrict__ Ml,
    const unsigned short* __restrict__ Jh, const unsigned short* __restrict__ Jl,
    const float* __restrict__ mask,
    float* __restrict__ out, float* __restrict__ partials)
{
  __shared__ __align__(128) char smem[49152];  // 2 x {Ah 8K|Al 8K|Bh 4K|Bl 4K}
  __shared__ float red[4];
  const int tid = threadIdx.x;
  const int lin = blockIdx.x + blockIdx.y * 9;           // 0..575
  const int virt = (lin & 7) * 72 + (lin >> 3);          // bijective (576%8==0)
  const int tx = virt % 9;                               // t-tile 0..8
  const int b  = virt / 9;
  const int w = __builtin_amdgcn_readfirstlane(tid >> 6);
  const int lane = tid & 63;
  const int wr = (w >> 1) << 6;              // m-half: 0 | 64
  const int wtc = (w & 1) << 5;              // t-half: 0 | 32
  const int fm = lane & 15, fq = lane >> 4;

  const unsigned short* sp = (w == 0) ? Mh : (w == 1) ? Ml : (w == 2) ? Jh : Jl;
  int jrow = b * TPAD + tx * 64 + lane;      // clamp tx=8 tail (guarded cols only)
  if (jrow > NROWS - 1) jrow = NROWS - 1;
  const char* srcb = (w < 2)
      ? (const char*)sp + ((size_t)(b * 128) + lane) * 16
      : (const char*)sp + (size_t)jrow * 16;

  auto STAGE = [&](int ks, int bsel) {
    char* buf = smem + bsel * 24576;
    if (w < 2) {                             // M planes: 128 rows, 8 loads
      char* dst = buf + (w ? 8192 : 0);
      #pragma unroll
      for (int j = 0; j < 8; ++j) {
        const int fq_ = j >> 1, half = j & 1;
        GLD16(srcb + (((size_t)(ks * 4 + fq_)) * 8192 + half * 64) * 16,
              dst + fq_ * 2048 + half * 1024);
      }
    } else {                                 // J planes: 64 rows, 4 loads
      char* dst = buf + 16384 + ((w == 3) ? 4096 : 0);
      #pragma unroll
      for (int j = 0; j < 4; ++j)
        GLD16(srcb + ((size_t)(ks * 4 + j)) * ((size_t)NROWS * 16),
              dst + j * 1024);
    }
  };

  f32x4 acc[4][2] = {};

  STAGE(0, 0);
  STAGE(1, 1);

  #pragma unroll
  for (int ks = 0; ks < 8; ++ks) {
    if (ks < 7) {
      if (w < 2) asm volatile("s_waitcnt vmcnt(8)" ::: "memory");
      else       asm volatile("s_waitcnt vmcnt(4)" ::: "memory");
    } else {
      asm volatile("s_waitcnt vmcnt(0)" ::: "memory");
    }
    __builtin_amdgcn_s_barrier();
    __builtin_amdgcn_sched_barrier(0);

    char* cur = smem + (ks & 1) * 24576;
    bf16x8 afh[4], afl[4], bfh[2], bfl[2];
    #pragma unroll
    for (int i = 0; i < 4; ++i) {
      const int ro = fq * 2048 + (wr + i * 16 + fm) * 16;
      afh[i] = *(const bf16x8*)(cur + ro);
      afl[i] = *(const bf16x8*)(cur + 8192 + ro);
    }
    #pragma unroll
    for (int n = 0; n < 2; ++n) {
      const int co = fq * 1024 + (wtc + n * 16 + fm) * 16;
      bfh[n] = *(const bf16x8*)(cur + 16384 + co);
      bfl[n] = *(const bf16x8*)(cur + 20480 + co);
    }
    #pragma unroll
    for (int mi = 0; mi < 4; ++mi)
      #pragma unroll
      for (int ni = 0; ni < 2; ++ni) {
        acc[mi][ni] = __builtin_amdgcn_mfma_f32_16x16x32_bf16(afh[mi], bfl[ni], acc[mi][ni], 0, 0, 0);
        acc[mi][ni] = __builtin_amdgcn_mfma_f32_16x16x32_bf16(afl[mi], bfh[ni], acc[mi][ni], 0, 0, 0);
        acc[mi][ni] = __builtin_amdgcn_mfma_f32_16x16x32_bf16(afh[mi], bfh[ni], acc[mi][ni], 0, 0, 0);
      }

    __builtin_amdgcn_s_barrier();
    if (ks + 2 < 8) STAGE(ks + 2, ks & 1);
  }

  // epilogue: e = exp(mask - 20/(exp(acc/8)+1)); write; deterministic partial
  float lsum = 0.f;
  #pragma unroll
  for (int mi = 0; mi < 4; ++mi) {
    #pragma unroll
    for (int r = 0; r < 4; ++r) {
      const int m = wr + mi * 16 + fq * 4 + r;
      #pragma unroll
      for (int ni = 0; ni < 2; ++ni) {
        const int t = tx * 64 + wtc + ni * 16 + fm;
        if (t < 513) {
          const float e2 = __expf(acc[mi][ni][r] * 0.125f);
          const float e  = __expf(mask[((size_t)(b * 128 + m)) * 513 + t]
                                  - 20.f / (e2 + 1.f));
          out[(size_t)b * 65664 + (size_t)m * 513 + t] = e;
          lsum += e;
        }
      }
    }
  }
  #pragma unroll
  for (int off = 32; off; off >>= 1) lsum += __shfl_xor(lsum, off);
  if (lane == 0) red[w] = lsum;
  __syncthreads();
  if (tid == 0)
    partials[b * 9 + tx] = (red[0] + red[1]) + (red[2] + red[3]);
}

// Normalize: inv computed inline from 9 deterministic partials (L1-hot).
__global__ __launch_bounds__(256) void sm_norm(float* __restrict__ out,
                                               const float* __restrict__ partials)
{
  const int i4 = blockIdx.x * 256 + threadIdx.x;
  if (i4 < 1050624) {
    const int b = i4 / 16416;
    float s = 0.f;
    #pragma unroll
    for (int i = 0; i < 9; ++i) s += partials[b * 9 + i];
    const float inv = 1.f / s;
    float4 v = ((float4*)out)[i4];
    v.x *= inv; v.y *= inv; v.z *= inv; v.w *= inv;
    ((float4*)out)[i4] = v;
  }
}

// ---------------------------------------------------------------------------
extern "C" void kernel_launch(void* const* d_in, const int* in_sizes, int n_in,
                              void* d_out, int out_size, void* d_ws, size_t ws_size,
                              hipStream_t stream)
{
  const float* machine = (const float*)d_in[0];
  const float* jobs    = (const float*)d_in[1];
  const float* mask    = (const float*)d_in[2];
  const float* Wq      = (const float*)d_in[3];
  const float* Wk      = (const float*)d_in[4];
  const float* Wv      = (const float*)d_in[5];
  const float* Wc      = (const float*)d_in[6];
  const float* bc      = (const float*)d_in[7];
  const float* skip    = (const float*)d_in[8];

  // Workspace (floats). Peak ~29,098,560 f ~ 116.4 MB (fill shows ws >= 268MB).
  //   [0,        8912896)  Jh|Jl chunk-major jobs planes (LIVE until logits)
  //   [8912896, 17825792)  Kh|Kl planes [34816][256] (dead after attn)
  //        overlays after attn: Mh|Ml MH planes (proj2 output, 2.1M f)
  //   [17825792,26738688)  Vth|Vtl transposed planes [64][256][544]
  //   [26738688,27000832)  Wah|Wal all-W planes [32][1024][8] hi/lo
  //   [27000832,29097984)  Mch|Mcl machine planes [32][8192][8] hi/lo
  //   [29097984,29098560)  partials (576 f)
  // d_out (4,202,496 f) scratch pre-logits: Qh|Ql [0,2.1M f), Och|Ocl [2.1M,4.2M f).
  float* ws       = (float*)d_ws;
  unsigned short* JhP = (unsigned short*)ws;
  unsigned short* JlP = JhP + 8912896;
  unsigned short* KhP = (unsigned short*)(ws + 8912896);
  unsigned short* KlP = KhP + 8912896;
  unsigned short* VthP = (unsigned short*)(ws + 17825792);
  unsigned short* VtlP = VthP + 8912896;
  unsigned short* WahP = (unsigned short*)(ws + 26738688);
  unsigned short* WalP = WahP + 262144;
  unsigned short* MchP = (unsigned short*)(ws + 27000832);
  unsigned short* MclP = MchP + 2097152;
  unsigned short* MhP  = (unsigned short*)(ws + 8912896);   // overlays Kh (dead after attn)
  unsigned short* MlP  = MhP + 2097152;
  float* partials = ws + 29097984;
  float* out      = (float*)d_out;
  unsigned short* QhP  = (unsigned short*)out;              // d_out scratch
  unsigned short* QlP  = QhP + 2097152;
  unsigned short* OchP = QlP + 2097152;
  unsigned short* OclP = OchP + 2097152;

  // prep: all-W planes, jobs planes, machine planes (chunk-major pre-split)
  prep_wt<<<1024, 256, 0, stream>>>(Wq, Wk, Wv, Wc, WahP, WalP);
  prep_jobs<<<544, 256, 0, stream>>>(jobs, skip, JhP, JlP);
  prep_mach<<<128, 256, 0, stream>>>(machine, MchP, MclP);
  // K|V projection (W window cols 256..767)
  gemm_kv_mfma<<<dim3(4, 544), 256, 0, stream>>>(
      JhP, JlP, WahP, WalP, KhP, KlP, VthP, VtlP);
  // Q = machine @ Wq * 0.25 -> split planes (d_out scratch)
  proj_mfma<<<dim3(4, 128), 256, 0, stream>>>(
      MchP, MclP, WahP, WalP, 0, 0.25f, nullptr, QhP, QlP);
  // MFMA attention -> OC split planes (d_out scratch)
  attn_mfma<<<dim3(16, 64), 256, 0, stream>>>(
      QhP, QlP, KhP, KlP, VthP, VtlP, OchP, OclP);
  // MH = OC @ Wc + bc -> split planes (overlay K region)
  proj_mfma<<<dim3(4, 128), 256, 0, stream>>>(
      OchP, OclP, WahP, WalP, 768, 1.0f, bc, MhP, MlP);
  // logits v3 + fused exp epilogue + partials
  logits_mfma<<<dim3(9, 64), 256, 0, stream>>>(
      MhP, MlP, JhP, JlP, mask, out, partials);
  sm_norm<<<4104, 256, 0, stream>>>(out, partials);
}